// Round 1
// baseline (2825.737 us; speedup 1.0000x reference)
//
#include <hip/hip_runtime.h>
#include <math.h>

#define NN 65536
#define TWO_PI 6.283185307179586f

typedef float2 cplx;

__device__ __forceinline__ void cmac(cplx& acc, const cplx a, const cplx b) {
    acc.x = fmaf(a.x, b.x, fmaf(-a.y, b.y, acc.x));
    acc.y = fmaf(a.x, b.y, fmaf(a.y, b.x, acc.y));
}
__device__ __forceinline__ cplx cmul(const cplx a, const cplx b) {
    return make_float2(a.x * b.x - a.y * b.y, a.x * b.y + a.y * b.x);
}

template<int SIGN>
__device__ __forceinline__ void init_luts(cplx* w16c, cplx* w256c, int t)
{
    float ang = (float)SIGN * (TWO_PI / 256.0f) * (float)t;
    float s, c; __sincosf(ang, &s, &c);
    w256c[t] = make_float2(c, s);
    if (t < 16) {
        float ang2 = (float)SIGN * (TWO_PI / 16.0f) * (float)t;
        float s2, c2; __sincosf(ang2, &s2, &c2);
        w16c[t] = make_float2(c2, s2);
    }
}

// 256-point DFT over one group's LDS row (256 cplx), done by 16 threads (u = 0..15).
// n = a + 16*b, k = c + 16*d:
//   Y1[a][c] = (sum_b x[a+16b] W16^{s b c}) * W256^{s a c}    (thread u = a)
//   X[c+16d] = sum_a Y1[a][c] W16^{s a d}                     (thread u = c)
// If BIGTW, multiply by W_65536^{s * n1 * k} before the final store (4-step stage 1).
template<int SIGN, bool BIGTW>
__device__ __forceinline__ void small_fft256(cplx* tg, const cplx* w16c, const cplx* w256c,
                                             int u, int n1)
{
    cplx xv[16];
#pragma unroll
    for (int b = 0; b < 16; ++b) xv[b] = tg[u + (b << 4)];
    __syncthreads();
#pragma unroll
    for (int c = 0; c < 16; ++c) {
        cplx acc = make_float2(0.f, 0.f);
#pragma unroll
        for (int b = 0; b < 16; ++b) cmac(acc, xv[b], w16c[(b * c) & 15]);
        acc = cmul(acc, w256c[(u * c) & 255]);
        tg[(c << 4) + u] = acc;
    }
    __syncthreads();
#pragma unroll
    for (int a = 0; a < 16; ++a) xv[a] = tg[(u << 4) + a];
    __syncthreads();
#pragma unroll
    for (int d = 0; d < 16; ++d) {
        cplx acc = make_float2(0.f, 0.f);
#pragma unroll
        for (int a = 0; a < 16; ++a) cmac(acc, xv[a], w16c[(a * d) & 15]);
        int k = u + (d << 4);
        if (BIGTW) {
            float ang = (float)SIGN * (TWO_PI / (float)NN) * (float)(n1 * k);
            float s, c; __sincosf(ang, &s, &c);
            acc = cmul(acc, make_float2(c, s));
        }
        tg[k] = acc;
    }
    __syncthreads();
}

// -------- 4-step 64K FFT, stage 1: per n1-column FFT over n2 (+ big twiddle) ---------
// MODE 0: real input rows (row = base + r)
// MODE 1: spectrum XF[b] * psi1(lam),  q = base + r, b = q>>3, lam = j1*8 + (q&7)
// MODE 2: spectrum C[rb] * psi2(j2),   q = base + r, rb = q&63, j2 = j1+1+(q>>6)
template<int SIGN, int MODE>
__global__ __launch_bounds__(256)
void fft_stage1(const float* __restrict__ srcR, const cplx* __restrict__ srcC,
                cplx* __restrict__ D, int base, int j1)
{
    __shared__ cplx tile[16][257];
    __shared__ cplx w256c[256];
    __shared__ cplx w16c[16];
    const int t = threadIdx.x;
    const int r = blockIdx.x >> 4;
    const int n10 = (blockIdx.x & 15) << 4;
    init_luts<SIGN>(w16c, w256c, t);

    const int q = base + r;
    int srow;
    float xi = 0.f, invsig = 0.f;
    if (MODE == 0) {
        srow = q;
    } else if (MODE == 1) {
        srow = q >> 3;
        int lam = j1 * 8 + (q & 7);
        xi = 0.35f * exp2f(-(float)lam * 0.125f);
        invsig = 8.0f / xi;                       // sigma1 = xi/Q, Q=8
    } else {
        srow = q & 63;
        int j2 = j1 + 1 + (q >> 6);
        xi = 0.35f * exp2f(-(float)j2);
        invsig = 1.0f / (0.6f * xi);              // sigma2 = 0.6*xi
    }

#pragma unroll
    for (int it = 0; it < 16; ++it) {
        int flat = it * 256 + t;
        int i = flat & 15;
        int n2 = flat >> 4;
        int n = (n10 + i) + (n2 << 8);
        cplx v;
        if (MODE == 0) {
            v = make_float2(srcR[(size_t)srow * NN + n], 0.0f);
        } else {
            v = srcC[(size_t)srow * NN + n];
            int ns = (n < (NN / 2)) ? n : n - NN;
            float f = (float)ns * (1.0f / (float)NN);
            float a = (f - xi) * invsig;
            float w = __expf(-0.5f * a * a);
            v.x *= w; v.y *= w;
        }
        tile[i][n2] = v;
    }
    __syncthreads();

    const int g = t >> 4;
    const int u = t & 15;
    small_fft256<SIGN, true>(&tile[g][0], w16c, w256c, u, n10 + g);

    // D layout: D[r][k2*256 + n1]  (k2-major so stage 2 reads contiguously)
#pragma unroll
    for (int it = 0; it < 16; ++it) {
        int flat = it * 256 + t;
        int i = flat & 15;
        int k2 = flat >> 4;
        D[(size_t)r * NN + (k2 << 8) + (n10 + i)] = tile[i][k2];
    }
}

// -------- stage 2: per k2-row FFT over n1, output at natural index k2 + 256*k1 --------
// OUTMOD 0: complex output (forward FFT). OUTMOD 1: |.|/N (inverse FFT + modulus).
template<int SIGN, int OUTMOD>
__global__ __launch_bounds__(256)
void fft_stage2(const cplx* __restrict__ D, cplx* __restrict__ outC,
                float* __restrict__ outF, int obase)
{
    __shared__ cplx tile[16][257];
    __shared__ cplx w256c[256];
    __shared__ cplx w16c[16];
    const int t = threadIdx.x;
    const int r = blockIdx.x >> 4;
    const int k20 = (blockIdx.x & 15) << 4;
    init_luts<SIGN>(w16c, w256c, t);

#pragma unroll
    for (int it = 0; it < 16; ++it) {
        int flat = it * 256 + t;
        int fi = flat >> 8;
        int n1 = flat & 255;
        tile[fi][n1] = D[(size_t)r * NN + ((size_t)(k20 + fi) << 8) + n1];
    }
    __syncthreads();

    const int g = t >> 4;
    const int u = t & 15;
    small_fft256<SIGN, false>(&tile[g][0], w16c, w256c, u, 0);

    const size_t orow = (size_t)(obase + r) * NN;
#pragma unroll
    for (int it = 0; it < 16; ++it) {
        int flat = it * 256 + t;
        int fi = flat & 15;
        int k1 = flat >> 4;
        size_t idx = orow + (size_t)(k20 + fi) + ((size_t)k1 << 8);
        cplx v = tile[fi][k1];
        if (OUTMOD == 0) outC[idx] = v;
        else outF[idx] = sqrtf(v.x * v.x + v.y * v.y) * (1.0f / (float)NN);
    }
}

// ---- S0/S1: fold spectrum*phi mod 256 bins, then 256-pt ifft (real part), log-mag ----
__global__ __launch_bounds__(256)
void sfold_kernel(const cplx* __restrict__ src, float* __restrict__ out, int j1)
{
    __shared__ cplx G[256];
    const int r = blockIdx.x;
    const int t = threadIdx.x;
    const float invsigphi = 731.428571f;   // 1 / (0.35 * 2^-8)
    cplx acc = make_float2(0.f, 0.f);
#pragma unroll
    for (int qq = -4; qq <= 4; ++qq) {
        int ks = t + (qq << 8);
        int k = ks & (NN - 1);
        float f = (float)ks * (1.0f / (float)NN);
        float a = f * invsigphi;
        float w = __expf(-0.5f * a * a);
        cplx v = src[(size_t)r * NN + k];
        acc.x = fmaf(v.x, w, acc.x);
        acc.y = fmaf(v.y, w, acc.y);
    }
    G[t] = acc;
    __syncthreads();
    float s = 0.f;
    for (int kk = 0; kk < 256; ++kk) {
        float ang = (TWO_PI / 256.0f) * (float)((kk * t) & 255);
        float sn, cs; __sincosf(ang, &sn, &cs);
        s = fmaf(G[kk].x, cs, s);
        s = fmaf(-G[kk].y, sn, s);
    }
    s *= (1.0f / (float)NN);
    float mag = sqrtf(fmaf(s, s, 1e-8f));
    float val = logf(mag + 1e-8f);
    int b, chan;
    if (j1 < 0) { b = r; chan = 0; }
    else { b = r >> 3; chan = 1 + j1 * 8 + (r & 7); }
    out[((size_t)b * 289 + chan) * 256 + t] = val;
}

// ---- S2: circular time-domain Gaussian lowpass at the 256 strided outputs ----
// One wave per output sample; 1537 taps split across 64 lanes (coalesced reads).
__global__ __launch_bounds__(256)
void s2conv_kernel(const float* __restrict__ U2T, const float* __restrict__ gtab,
                   float* __restrict__ out, int j1, int qs)
{
    const int t = threadIdx.x;
    const int lane = t & 63;
    const int wid = t >> 6;
    const int bx = blockIdx.x;
    const int rho = bx >> 6;                       // chunk-local row
    const int n = ((bx & 63) << 2) + wid;          // output sample 0..255
    const int q = qs + rho;
    const int j2 = j1 + 1 + (q >> 6);
    const int rb = q & 63;
    const int b = rb >> 3;
    const int chan = 65 + 4 * j2 * (j2 - 1) + j1 * 8 + (rb & 7);
    const size_t rowoff = (size_t)rho * NN;
    const int s0 = (n << 8) - 768 + NN;
    float acc = 0.f;
#pragma unroll
    for (int jj = 0; jj < 25; ++jj) {
        int j = lane + (jj << 6);
        if (j < 1537) {
            int idx = (s0 + j) & (NN - 1);
            acc = fmaf(U2T[rowoff + idx], gtab[j], acc);
        }
    }
#pragma unroll
    for (int off = 32; off > 0; off >>= 1)
        acc += __shfl_down(acc, off, 64);
    if (lane == 0) {
        float mag = sqrtf(fmaf(acc, acc, 1e-8f));
        out[((size_t)b * 289 + chan) * 256 + n] = logf(mag + 1e-8f);
    }
}

// time-domain Gaussian: g[m] = sigphi*sqrt(2pi) * exp(-2 pi^2 sigphi^2 m^2), m = i-768
__global__ void ginit_kernel(float* g)
{
    int i = blockIdx.x * 256 + threadIdx.x;
    if (i < 1537) {
        const float sp = 0.0013671875f;            // 0.35 * 2^-8
        const float c0 = sp * 2.5066282746f;
        const float c1 = 19.739208802f * sp * sp;
        float m = (float)(i - 768);
        g[i] = c0 * expf(-c1 * m * m);
    }
}

__global__ void zero_kernel(float* p, int nElem)
{
    int i = blockIdx.x * 256 + threadIdx.x;
    if (i < nElem) p[i] = 0.f;
}

extern "C" void kernel_launch(void* const* d_in, const int* in_sizes, int n_in,
                              void* d_out, int out_size, void* d_ws, size_t ws_size,
                              hipStream_t stream)
{
    const float* x = (const float*)d_in[0];
    float* out = (float*)d_out;
    char* ws = (char*)d_ws;

    const size_t NB = (size_t)NN;
    cplx*  XF   = (cplx*)ws;                                       // 8*NN cplx
    cplx*  C    = (cplx*)(ws + 8 * NB * 8);                        // 64*NN cplx (per-octave U1f)
    float* U1T  = (float*)(ws + 8 * NB * 8 + 64 * NB * 8);         // 64*NN float
    float* gbuf = (float*)(ws + 8 * NB * 8 + 64 * NB * 8 + 64 * NB * 4);
    const size_t fixedEnd = 8 * NB * 8 + 64 * NB * 8 + 64 * NB * 4 + 8192;

    long avail = (long)ws_size - (long)fixedEnd;
    int CH = (int)(avail / (long)(NB * 12));   // per chunk-row: cplx stage buf + float U2
    if (CH > 64) CH = 64;
    if (CH < 1) CH = 1;
    cplx*  D   = (cplx*)(ws + fixedEnd);
    float* U2T = (float*)(ws + fixedEnd + (size_t)CH * NB * 8);

    // imag half of output = 0
    {
        int nz = 8 * 289 * 256;
        zero_kernel<<<(nz + 255) / 256, 256, 0, stream>>>(out + nz, nz);
    }
    ginit_kernel<<<7, 256, 0, stream>>>(gbuf);

    // XF = fft(x)
    for (int cs = 0; cs < 8; cs += CH) {
        int m = (8 - cs < CH) ? (8 - cs) : CH;
        fft_stage1<-1, 0><<<m * 16, 256, 0, stream>>>(x, nullptr, D, cs, 0);
        fft_stage2<-1, 0><<<m * 16, 256, 0, stream>>>(D, XF, nullptr, cs);
    }
    // S0
    sfold_kernel<<<8, 256, 0, stream>>>(XF, out, -1);

    for (int j1 = 0; j1 < 8; ++j1) {
        // U1 = |ifft(XF * psi1)| for this octave's 64 (b,lam) rows
        for (int cs = 0; cs < 64; cs += CH) {
            int m = (64 - cs < CH) ? (64 - cs) : CH;
            fft_stage1<1, 1><<<m * 16, 256, 0, stream>>>(nullptr, XF, D, cs, j1);
            fft_stage2<1, 1><<<m * 16, 256, 0, stream>>>(D, nullptr, U1T, cs);
        }
        // C = fft(U1)
        for (int cs = 0; cs < 64; cs += CH) {
            int m = (64 - cs < CH) ? (64 - cs) : CH;
            fft_stage1<-1, 0><<<m * 16, 256, 0, stream>>>(U1T, nullptr, D, cs, 0);
            fft_stage2<-1, 0><<<m * 16, 256, 0, stream>>>(D, C, nullptr, cs);
        }
        // S1 for this octave
        sfold_kernel<<<64, 256, 0, stream>>>(C, out, j1);
        // second order: all j2 > j1 using this octave's C rows
        int totq = 64 * (7 - j1);
        for (int qsv = 0; qsv < totq; qsv += CH) {
            int m = (totq - qsv < CH) ? (totq - qsv) : CH;
            fft_stage1<1, 2><<<m * 16, 256, 0, stream>>>(nullptr, C, D, qsv, j1);
            fft_stage2<1, 1><<<m * 16, 256, 0, stream>>>(D, nullptr, U2T, 0);
            s2conv_kernel<<<m * 64, 256, 0, stream>>>(U2T, gbuf, out, j1, qsv);
        }
    }
}

// Round 2
// 2128.252 us; speedup vs baseline: 1.3277x; 1.3277x over previous
//
#include <hip/hip_runtime.h>
#include <math.h>

#define NN 65536
#define TWO_PI 6.283185307179586f

typedef float2 cplx;

// LDS swizzle within a 256-slot row: conflict-free for stride-1 and stride-16 patterns
#define SWZ(m) ((m) ^ (((m) >> 4) & 15))

__device__ constexpr float W16R[16] = {
    1.f, 0.9238795325f, 0.7071067812f, 0.3826834324f, 0.f, -0.3826834324f,
    -0.7071067812f, -0.9238795325f, -1.f, -0.9238795325f, -0.7071067812f,
    -0.3826834324f, 0.f, 0.3826834324f, 0.7071067812f, 0.9238795325f};
__device__ constexpr float W16I[16] = {
    0.f, 0.3826834324f, 0.7071067812f, 0.9238795325f, 1.f, 0.9238795325f,
    0.7071067812f, 0.3826834324f, 0.f, -0.3826834324f, -0.7071067812f,
    -0.9238795325f, -1.f, -0.9238795325f, -0.7071067812f, -0.3826834324f};

__device__ __forceinline__ cplx cmul(const cplx a, const cplx b) {
    return make_float2(a.x * b.x - a.y * b.y, a.x * b.y + a.y * b.x);
}
__device__ __forceinline__ void lds_fence() {
    asm volatile("s_waitcnt lgkmcnt(0)" ::: "memory");
}

// 256-pt DFT on one group's LDS row (16 lanes, all within one wave).
// Layout: logical index m lives at rowc[SWZ(m)] (cplx) / rowf[SWZ(m)] (float).
// qmask: which quarters of the b-range (pass-1 inputs) are nonzero.
template<int SIGN, bool BIGTW, bool INREAL, bool MAGOUT>
__device__ __forceinline__ void fft256(cplx* rowc, float* rowf, int u, int n1, int qmask)
{
    const bool empty = (qmask == 0);
    // ---- pass 1: acc[c] = sum_b x[u+16b] W16^{s b c} ----
    cplx acc[16];
#pragma unroll
    for (int c = 0; c < 16; ++c) acc[c] = make_float2(0.f, 0.f);
#pragma unroll
    for (int q = 0; q < 4; ++q) {
        if (qmask & (1 << q)) {
            float xr[4], xi4[4];
#pragma unroll
            for (int j = 0; j < 4; ++j) {
                int m = u + ((q * 4 + j) << 4);
                if (INREAL) { xr[j] = rowf[SWZ(m)]; xi4[j] = 0.f; }
                else { cplx v = rowc[SWZ(m)]; xr[j] = v.x; xi4[j] = v.y; }
            }
#pragma unroll
            for (int c = 0; c < 16; ++c) {
#pragma unroll
                for (int j = 0; j < 4; ++j) {
                    const int idx = (((q * 4 + j) * c) & 15);
                    const float cr = W16R[idx];
                    const float ci = (SIGN > 0) ? W16I[idx] : -W16I[idx];
                    if (INREAL) {
                        acc[c].x = fmaf(xr[j], cr, acc[c].x);
                        acc[c].y = fmaf(xr[j], ci, acc[c].y);
                    } else {
                        acc[c].x = fmaf(xr[j], cr, fmaf(-xi4[j], ci, acc[c].x));
                        acc[c].y = fmaf(xr[j], ci, fmaf(xi4[j], cr, acc[c].y));
                    }
                }
            }
        }
    }
    // twiddle by W256^{s u c} (recurrence) and transpose-write
    if (!empty) {
        float sa, ca;
        __sincosf((float)SIGN * (TWO_PI / 256.0f) * (float)u, &sa, &ca);
        cplx base = make_float2(ca, sa);
        cplx tw = make_float2(1.f, 0.f);
#pragma unroll
        for (int c = 0; c < 16; ++c) {
            cplx o = cmul(acc[c], tw);
            rowc[SWZ((c << 4) + u)] = o;
            tw = cmul(tw, base);
        }
    }
    lds_fence();
    // ---- pass 2: X[u+16d] = sum_a Y[a][u] W16^{s a d} (optionally * bigtw) ----
    if (empty) {
#pragma unroll
        for (int d = 0; d < 16; ++d) {
            int k = u + (d << 4);
            if (MAGOUT) rowf[SWZ(k)] = 0.f;
            else rowc[SWZ(k)] = make_float2(0.f, 0.f);
        }
    } else {
        cplx xv[16];
#pragma unroll
        for (int a = 0; a < 16; ++a) xv[a] = rowc[SWZ((u << 4) + a)];
        cplx twb = make_float2(1.f, 0.f), step = make_float2(1.f, 0.f);
        if (BIGTW) {
            float s0, c0, s1v, c1v;
            __sincosf((float)SIGN * (TWO_PI / (float)NN) * (float)(n1 * u), &s0, &c0);
            __sincosf((float)SIGN * (TWO_PI / (float)NN) * (float)(16 * n1), &s1v, &c1v);
            twb = make_float2(c0, s0); step = make_float2(c1v, s1v);
        }
#pragma unroll
        for (int d = 0; d < 16; ++d) {
            cplx o = make_float2(0.f, 0.f);
#pragma unroll
            for (int a = 0; a < 16; ++a) {
                const int idx = ((a * d) & 15);
                const float cr = W16R[idx];
                const float ci = (SIGN > 0) ? W16I[idx] : -W16I[idx];
                o.x = fmaf(xv[a].x, cr, fmaf(-xv[a].y, ci, o.x));
                o.y = fmaf(xv[a].x, ci, fmaf(xv[a].y, cr, o.y));
            }
            if (BIGTW) { o = cmul(o, twb); twb = cmul(twb, step); }
            int k = u + (d << 4);
            if (MAGOUT) rowf[SWZ(k)] = sqrtf(fmaf(o.x, o.x, o.y * o.y)) * (1.0f / (float)NN);
            else rowc[SWZ(k)] = o;
        }
    }
    lds_fence();
}

// -------- 4-step 64K FFT, stage 1 (FFT over n2 per n1-column + big twiddle) --------
// MODE 0: real input rows. MODE 1: XF[b]*psi1. MODE 2: C[rb]*psi2. (band-truncated)
template<int SIGN, int MODE>
__global__ __launch_bounds__(256)
void fft_stage1(const float* __restrict__ srcR, const cplx* __restrict__ srcC,
                cplx* __restrict__ D, int base, int j1)
{
    __shared__ cplx tile[16][257];
    const int t = threadIdx.x;
    const int r = blockIdx.x >> 4;
    const int n10 = (blockIdx.x & 15) << 4;
    const int q = base + r;
    int srow = q;
    float kc = 0.f, Hh = 0.f, invsig = 0.f, xi = 0.f;
    if (MODE == 1) {
        srow = q >> 3;
        int lam = j1 * 8 + (q & 7);
        xi = 0.35f * exp2f(-(float)lam * 0.125f);
        invsig = 8.0f / xi;
        kc = xi * (float)NN;
        Hh = 6.10f * (xi * 0.125f) * (float)NN;
    } else if (MODE == 2) {
        srow = q & 63;
        int j2 = j1 + 1 + (q >> 6);
        xi = 0.35f * exp2f(-(float)j2);
        invsig = 1.0f / (0.6f * xi);
        kc = xi * (float)NN;
        Hh = 6.10f * (0.6f * xi) * (float)NN;
    }
    float* tf = (float*)&tile[0][0];   // float row i at tf + i*514

#pragma unroll
    for (int it = 0; it < 16; ++it) {
        int flat = it * 256 + t;
        int i = flat & 15;
        int n2 = flat >> 4;
        int n = (n10 + i) + (n2 << 8);
        if (MODE == 0) {
            tf[i * 514 + SWZ(n2)] = srcR[(size_t)srow * NN + n];
        } else {
            float nsf = (float)((n < (NN / 2)) ? n : n - NN);
            cplx v = make_float2(0.f, 0.f);
            if (fabsf(nsf - kc) <= Hh) {
                v = srcC[(size_t)srow * NN + n];
                float a = (nsf * (1.0f / (float)NN) - xi) * invsig;
                float w = __expf(-0.5f * a * a);
                v.x *= w; v.y *= w;
            }
            tile[i][SWZ(n2)] = v;
        }
    }
    __syncthreads();

    const int g = t >> 4;
    const int u = t & 15;
    const int n1 = n10 + g;
    int qmask = 15;
    if (MODE != 0) {
        int klo = (int)floorf(kc - Hh);
        int khi = (int)ceilf(kc + Hh);
        if (khi > NN - 1) khi = NN - 1;
        qmask = 0;
        if (klo >= 0) {
            int n2min = (klo - n1 + 255) >> 8;         // klo>=0, n1<256 -> numerator>=0
            int n2max = (khi - n1) >> 8;               // may go negative -> empty
            if (n2min <= n2max) {
                int b0v = n2min >> 4, b1v = n2max >> 4;
#pragma unroll
                for (int qq = 0; qq < 4; ++qq)
                    if (4 * qq + 3 >= b0v && 4 * qq <= b1v) qmask |= (1 << qq);
            }
        } else {                                        // wrapped: [0,khi] U [klo+N, N)
            int bA = ((khi - n1) >> 8) >> 4;
            int nB = (klo + NN - n1 + 255) >> 8;
            int bB = nB >> 4;
#pragma unroll
            for (int qq = 0; qq < 4; ++qq)
                if (4 * qq <= bA || (nB <= 255 && 4 * qq + 3 >= bB)) qmask |= (1 << qq);
        }
    }
    if (MODE == 0)
        fft256<SIGN, true, true, false>(&tile[g][0], tf + g * 514, u, n1, 15);
    else
        fft256<SIGN, true, false, false>(&tile[g][0], tf + g * 514, u, n1, qmask);
    __syncthreads();

#pragma unroll
    for (int it = 0; it < 16; ++it) {
        int flat = it * 256 + t;
        int i = flat & 15;
        int k2 = flat >> 4;
        D[(size_t)r * NN + (k2 << 8) + (n10 + i)] = tile[i][SWZ(k2)];
    }
}

// -------- stage 2: FFT over n1 per k2-row. OUTMOD 0: cplx. OUTMOD 1: |.|/N float. --------
template<int SIGN, int OUTMOD>
__global__ __launch_bounds__(256)
void fft_stage2(const cplx* __restrict__ Din, cplx* __restrict__ outC,
                float* __restrict__ outF, int obase)
{
    __shared__ cplx tile[16][257];
    const int t = threadIdx.x;
    const int r = blockIdx.x >> 4;
    const int k20 = (blockIdx.x & 15) << 4;
#pragma unroll
    for (int it = 0; it < 16; ++it)
        tile[it][SWZ(t)] = Din[(size_t)r * NN + ((size_t)(k20 + it) << 8) + t];
    __syncthreads();

    const int g = t >> 4;
    const int u = t & 15;
    fft256<SIGN, false, false, (OUTMOD == 1)>(&tile[g][0], (float*)&tile[g][0], u, 0, 15);
    __syncthreads();

    const size_t orow = (size_t)(obase + r) * NN;
    if (OUTMOD == 0) {
#pragma unroll
        for (int it = 0; it < 16; ++it) {
            int flat = it * 256 + t;
            int fi = flat & 15;
            int k1 = flat >> 4;
            outC[orow + (size_t)(k20 + fi) + ((size_t)k1 << 8)] = tile[fi][SWZ(k1)];
        }
    } else {
        float* tf = (float*)&tile[0][0];
#pragma unroll
        for (int it = 0; it < 16; ++it) {
            int flat = it * 256 + t;
            int fi = flat & 15;
            int k1 = flat >> 4;
            outF[orow + (size_t)(k20 + fi) + ((size_t)k1 << 8)] = tf[fi * 514 + SWZ(k1)];
        }
    }
}

// -------- fused U1 middle: ifft-stage2 + modulus + fwd-stage1(+bigtw) --------
__global__ __launch_bounds__(256)
void fft_mid(const cplx* __restrict__ Din, cplx* __restrict__ D2)
{
    __shared__ cplx tile[16][257];
    const int t = threadIdx.x;
    const int r = blockIdx.x >> 4;
    const int k20 = (blockIdx.x & 15) << 4;
#pragma unroll
    for (int it = 0; it < 16; ++it)
        tile[it][SWZ(t)] = Din[(size_t)r * NN + ((size_t)(k20 + it) << 8) + t];
    __syncthreads();

    const int g = t >> 4;
    const int u = t & 15;
    float* rowf = (float*)&tile[g][0];
    // ifft (+1) with modulus -> float row holds U1 samples at k = (k20+g) + 256*k1
    fft256<1, false, false, true>(&tile[g][0], rowf, u, 0, 15);
    // forward fft over those samples (they are exactly column n1=k20+g of the fwd 4-step)
    fft256<-1, true, true, false>(&tile[g][0], rowf, u, k20 + g, 15);
    __syncthreads();

#pragma unroll
    for (int it = 0; it < 16; ++it) {
        int flat = it * 256 + t;
        int i = flat & 15;
        int k2 = flat >> 4;
        D2[(size_t)r * NN + (k2 << 8) + (k20 + i)] = tile[i][SWZ(k2)];
    }
}

// ---- S0/S1: fold spectrum*phi mod 256 bins, 256-pt ifft (real part), log-mag ----
__global__ __launch_bounds__(256)
void sfold_kernel(const cplx* __restrict__ src, float* __restrict__ out, int j1)
{
    __shared__ cplx G[256];
    const int r = blockIdx.x;
    const int t = threadIdx.x;
    const float invsigphi = 731.428571f;   // 1 / (0.35 * 2^-8)
    cplx acc = make_float2(0.f, 0.f);
#pragma unroll
    for (int qq = -4; qq <= 4; ++qq) {
        int ks = t + (qq << 8);
        int k = ks & (NN - 1);
        float f = (float)ks * (1.0f / (float)NN);
        float a = f * invsigphi;
        float w = __expf(-0.5f * a * a);
        cplx v = src[(size_t)r * NN + k];
        acc.x = fmaf(v.x, w, acc.x);
        acc.y = fmaf(v.y, w, acc.y);
    }
    G[t] = acc;
    __syncthreads();
    float sb, cb;
    __sincosf((TWO_PI / 256.0f) * (float)t, &sb, &cb);
    cplx wstep = make_float2(cb, sb);
    cplx w = make_float2(1.f, 0.f);
    float s = 0.f;
    for (int kk = 0; kk < 256; ++kk) {
        s = fmaf(G[kk].x, w.x, s);
        s = fmaf(-G[kk].y, w.y, s);
        w = cmul(w, wstep);
    }
    s *= (1.0f / (float)NN);
    float mag = sqrtf(fmaf(s, s, 1e-8f));
    float val = logf(mag + 1e-8f);
    int b, chan;
    if (j1 < 0) { b = r; chan = 0; }
    else { b = r >> 3; chan = 1 + j1 * 8 + (r & 7); }
    out[((size_t)b * 289 + chan) * 256 + t] = val;
}

// ---- S2: circular time-domain Gaussian lowpass at the 256 strided outputs ----
__global__ __launch_bounds__(256)
void s2conv_kernel(const float* __restrict__ U2T, const float* __restrict__ gtab,
                   float* __restrict__ out, int j1, int qs)
{
    const int t = threadIdx.x;
    const int lane = t & 63;
    const int wid = t >> 6;
    const int bx = blockIdx.x;
    const int rho = bx >> 6;
    const int n = ((bx & 63) << 2) + wid;
    const int q = qs + rho;
    const int j2 = j1 + 1 + (q >> 6);
    const int rb = q & 63;
    const int b = rb >> 3;
    const int chan = 65 + 4 * j2 * (j2 - 1) + j1 * 8 + (rb & 7);
    const size_t rowoff = (size_t)rho * NN;
    const int s0 = (n << 8) - 768 + NN;
    float acc = 0.f;
#pragma unroll
    for (int jj = 0; jj < 25; ++jj) {
        int j = lane + (jj << 6);
        if (j < 1537) {
            int idx = (s0 + j) & (NN - 1);
            acc = fmaf(U2T[rowoff + idx], gtab[j], acc);
        }
    }
#pragma unroll
    for (int off = 32; off > 0; off >>= 1)
        acc += __shfl_down(acc, off, 64);
    if (lane == 0) {
        float mag = sqrtf(fmaf(acc, acc, 1e-8f));
        out[((size_t)b * 289 + chan) * 256 + n] = logf(mag + 1e-8f);
    }
}

__global__ void ginit_kernel(float* g)
{
    int i = blockIdx.x * 256 + threadIdx.x;
    if (i < 1537) {
        const float sp = 0.0013671875f;            // 0.35 * 2^-8
        const float c0 = sp * 2.5066282746f;
        const float c1 = 19.739208802f * sp * sp;
        float m = (float)(i - 768);
        g[i] = c0 * expf(-c1 * m * m);
    }
}

__global__ void zero_kernel(float* p, int nElem)
{
    int i = blockIdx.x * 256 + threadIdx.x;
    if (i < nElem) p[i] = 0.f;
}

extern "C" void kernel_launch(void* const* d_in, const int* in_sizes, int n_in,
                              void* d_out, int out_size, void* d_ws, size_t ws_size,
                              hipStream_t stream)
{
    const float* x = (const float*)d_in[0];
    float* out = (float*)d_out;
    char* ws = (char*)d_ws;

    const size_t NB = (size_t)NN;
    cplx*  XF   = (cplx*)ws;                               // 8 rows cplx
    cplx*  C    = (cplx*)(ws + 8 * NB * 8);                // 64 rows cplx
    float* gbuf = (float*)(ws + 8 * NB * 8 + 64 * NB * 8);
    const size_t fixedEnd = 8 * NB * 8 + 64 * NB * 8 + 8192;

    long avail = (long)ws_size - (long)fixedEnd;
    int CH = (int)(avail / (long)(NB * 16));   // D (8B/elem) + D2/U2T union (8B/elem)
    if (CH > 64) CH = 64;
    if (CH < 1) CH = 1;
    cplx*  D   = (cplx*)(ws + fixedEnd);
    cplx*  D2  = (cplx*)(ws + fixedEnd + (size_t)CH * NB * 8);
    float* U2T = (float*)D2;

    {
        int nz = 8 * 289 * 256;
        zero_kernel<<<(nz + 255) / 256, 256, 0, stream>>>(out + nz, nz);
    }
    ginit_kernel<<<7, 256, 0, stream>>>(gbuf);

    // XF = fft(x)
    for (int cs = 0; cs < 8; cs += CH) {
        int m = (8 - cs < CH) ? (8 - cs) : CH;
        fft_stage1<-1, 0><<<m * 16, 256, 0, stream>>>(x, nullptr, D, cs, 0);
        fft_stage2<-1, 0><<<m * 16, 256, 0, stream>>>(D, XF, nullptr, cs);
    }
    sfold_kernel<<<8, 256, 0, stream>>>(XF, out, -1);

    for (int j1 = 0; j1 < 8; ++j1) {
        // C = fft(|ifft(XF * psi1)|) for this octave's 64 (b,lam) rows
        for (int cs = 0; cs < 64; cs += CH) {
            int m = (64 - cs < CH) ? (64 - cs) : CH;
            fft_stage1<1, 1><<<m * 16, 256, 0, stream>>>(nullptr, XF, D, cs, j1);
            fft_mid<<<m * 16, 256, 0, stream>>>(D, D2);
            fft_stage2<-1, 0><<<m * 16, 256, 0, stream>>>(D2, C, nullptr, cs);
        }
        sfold_kernel<<<64, 256, 0, stream>>>(C, out, j1);
        // second order: all j2 > j1 from this octave's C rows
        int totq = 64 * (7 - j1);
        for (int qsv = 0; qsv < totq; qsv += CH) {
            int m = (totq - qsv < CH) ? (totq - qsv) : CH;
            fft_stage1<1, 2><<<m * 16, 256, 0, stream>>>(nullptr, C, D, qsv, j1);
            fft_stage2<1, 1><<<m * 16, 256, 0, stream>>>(D, nullptr, U2T, 0);
            s2conv_kernel<<<m * 64, 256, 0, stream>>>(U2T, gbuf, out, j1, qsv);
        }
    }
}

// Round 3
// 1303.325 us; speedup vs baseline: 2.1681x; 1.6329x over previous
//
#include <hip/hip_runtime.h>
#include <hip/hip_fp16.h>
#include <math.h>

#define NN 65536
#define TWO_PI 6.283185307179586f
#define RSTR 264   // LDS row stride in floats: 264 % 32 == 8 -> conflict-free phases

typedef float2 cplx;

// swizzle within a 256-slot row (stays inside each 16-block)
#define SWZ(m) ((m) ^ (((m) >> 4) & 15))

__device__ __forceinline__ void lds_fence() {
    asm volatile("s_waitcnt lgkmcnt(0)" ::: "memory");
}

// ---------------- radix-4 x radix-4 16-point FFT, natural order in/out ----------------
// X[k] = sum_n x[n] e^{SIGN*i*2*pi*n*k/16}
template<int SIGN>
__device__ __forceinline__ void fft16(float* xr, float* xi, float* yr, float* yi)
{
    const float S = (SIGN > 0) ? 1.0f : -1.0f;
    const float C8 = 0.92387953251f, S8 = 0.38268343236f, R2 = 0.70710678119f;
    // step A: DFT4 over n1 (x[n0+4*n1]) -> A[n0][p] stored at slot n0+4p
#pragma unroll
    for (int n0 = 0; n0 < 4; ++n0) {
        float z0r=xr[n0],    z0i=xi[n0];
        float z1r=xr[n0+4],  z1i=xi[n0+4];
        float z2r=xr[n0+8],  z2i=xi[n0+8];
        float z3r=xr[n0+12], z3i=xi[n0+12];
        float t0r=z0r+z2r, t0i=z0i+z2i;
        float t1r=z0r-z2r, t1i=z0i-z2i;
        float t2r=z1r+z3r, t2i=z1i+z3i;
        float t3r=S*(z1r-z3r), t3i=S*(z1i-z3i);
        xr[n0]=t0r+t2r;      xi[n0]=t0i+t2i;
        xr[n0+4]=t1r-t3i;    xi[n0+4]=t1i+t3r;
        xr[n0+8]=t0r-t2r;    xi[n0+8]=t0i-t2i;
        xr[n0+12]=t1r+t3i;   xi[n0+12]=t1i-t3r;
    }
    // step B: twiddle slot[n0+4p] *= W16^{n0*p}
    {
        const float W1r=C8,  W1i=S*S8;
        const float W2r=R2,  W2i=S*R2;
        const float W3r=S8,  W3i=S*C8;
        const float W6r=-R2, W6i=S*R2;
        const float W9r=-C8, W9i=-S*S8;
#define TWID(idx, wr, wi) { float ar=xr[idx], ai=xi[idx]; xr[idx]=ar*(wr)-ai*(wi); xi[idx]=ar*(wi)+ai*(wr); }
        TWID(5,W1r,W1i)  TWID(9,W2r,W2i)   TWID(13,W3r,W3i)
        TWID(6,W2r,W2i)  { float ar=xr[10], ai=xi[10]; xr[10]=-S*ai; xi[10]=S*ar; } TWID(14,W6r,W6i)
        TWID(7,W3r,W3i)  TWID(11,W6r,W6i)  TWID(15,W9r,W9i)
#undef TWID
    }
    // step C: DFT4 over n0 (slots 4p..4p+3) -> X[p+4q]
#pragma unroll
    for (int p = 0; p < 4; ++p) {
        float z0r=xr[4*p],   z0i=xi[4*p];
        float z1r=xr[4*p+1], z1i=xi[4*p+1];
        float z2r=xr[4*p+2], z2i=xi[4*p+2];
        float z3r=xr[4*p+3], z3i=xi[4*p+3];
        float t0r=z0r+z2r, t0i=z0i+z2i;
        float t1r=z0r-z2r, t1i=z0i-z2i;
        float t2r=z1r+z3r, t2i=z1i+z3i;
        float t3r=S*(z1r-z3r), t3i=S*(z1i-z3i);
        yr[p]=t0r+t2r;     yi[p]=t0i+t2i;
        yr[p+4]=t1r-t3i;   yi[p+4]=t1i+t3r;
        yr[p+8]=t0r-t2r;   yi[p+8]=t0i-t2i;
        yr[p+12]=t1r+t3i;  yi[p+12]=t1i-t3r;
    }
}

// ---------------- 256-pt FFT on one group's SoA LDS row (16 lanes, one wave) ----------
// OUT: 0 = complex back to LDS, 1 = |.|*mscale to re-plane (im-plane zeroed)
template<int SIGN, bool BIGTW, int OUT>
__device__ __forceinline__ void fft256_soa(float* rr, float* ri, int u, int n1, float mscale)
{
    float xr[16], xi[16], yr[16], yi[16];
#pragma unroll
    for (int b = 0; b < 16; ++b) {
        int s = SWZ(u + (b << 4));
        xr[b] = rr[s]; xi[b] = ri[s];
    }
    fft16<SIGN>(xr, xi, yr, yi);
    float sa, ca;
    __sincosf((float)SIGN * (TWO_PI / 256.0f) * (float)u, &sa, &ca);
    float twr = 1.f, twi = 0.f;
#pragma unroll
    for (int c = 0; c < 16; ++c) {
        int s = SWZ((c << 4) + u);
        rr[s] = yr[c] * twr - yi[c] * twi;
        ri[s] = yr[c] * twi + yi[c] * twr;
        float nr = twr * ca - twi * sa; twi = twr * sa + twi * ca; twr = nr;
    }
    lds_fence();
#pragma unroll
    for (int a = 0; a < 16; ++a) {
        int s = SWZ((u << 4) + a);
        xr[a] = rr[s]; xi[a] = ri[s];
    }
    fft16<SIGN>(xr, xi, yr, yi);
    float tbr = 1.f, tbi = 0.f, str = 1.f, sti = 0.f;
    if (BIGTW) {
        float s0, c0, s1, c1;
        __sincosf((float)SIGN * (TWO_PI / (float)NN) * (float)(n1 * u), &s0, &c0);
        __sincosf((float)SIGN * (TWO_PI / (float)NN) * (float)(n1 << 4), &s1, &c1);
        tbr = c0; tbi = s0; str = c1; sti = s1;
    }
#pragma unroll
    for (int d = 0; d < 16; ++d) {
        float vr = yr[d], vi = yi[d];
        if (BIGTW) {
            float pr = vr * tbr - vi * tbi, pi = vr * tbi + vi * tbr;
            vr = pr; vi = pi;
            float nr = tbr * str - tbi * sti; tbi = tbr * sti + tbi * str; tbr = nr;
        }
        int s = SWZ(u + (d << 4));
        if (OUT == 1) { rr[s] = sqrtf(fmaf(vr, vr, vi * vi)) * mscale; ri[s] = 0.f; }
        else { rr[s] = vr; ri[s] = vi; }
    }
    lds_fence();
}

// -------- 4-step 64K FFT stage 1: FFT over n2 per n1-column + big twiddle --------
// MODE 0: real rows from srcR. MODE 1: XF[b]*psi1. MODE 2: C[rb]*psi2 (band-truncated loads).
template<int SIGN, int MODE, bool HALFOUT>
__global__ __launch_bounds__(256)
void fft_stage1(const float* __restrict__ srcR, const float2* __restrict__ srcC,
                void* __restrict__ Dout, int base, int j1)
{
    __shared__ float sre[16 * RSTR];
    __shared__ float sim[16 * RSTR];
    const int t = threadIdx.x;
    const int r = blockIdx.x >> 4;
    const int n10 = (blockIdx.x & 15) << 4;
    const int q = base + r;
    int srow = q;
    float kc = 0.f, Hh = 0.f, invsig = 0.f, xi = 0.f;
    if (MODE == 1) {
        srow = q >> 3;
        int lam = j1 * 8 + (q & 7);
        xi = 0.35f * exp2f(-(float)lam * 0.125f);
        invsig = 8.0f / xi;
        kc = xi * (float)NN;
        Hh = 6.10f * (xi * 0.125f) * (float)NN;
    } else if (MODE == 2) {
        srow = q & 63;
        int j2 = j1 + 1 + (q >> 6);
        xi = 0.35f * exp2f(-(float)j2);
        invsig = 1.0f / (0.6f * xi);
        kc = xi * (float)NN;
        Hh = 6.10f * (0.6f * xi) * (float)NN;
    }
#pragma unroll
    for (int it = 0; it < 16; ++it) {
        int flat = it * 256 + t;
        int i = flat & 15;
        int n2 = flat >> 4;
        int n = (n10 + i) + (n2 << 8);
        float vr, vi;
        if (MODE == 0) {
            vr = srcR[(size_t)srow * NN + n]; vi = 0.f;
        } else {
            float nsf = (float)((n < NN / 2) ? n : n - NN);
            vr = 0.f; vi = 0.f;
            if (fabsf(nsf - kc) <= Hh) {
                float2 v = srcC[(size_t)srow * NN + n];
                float a = (nsf * (1.0f / (float)NN) - xi) * invsig;
                float w = __expf(-0.5f * a * a);
                vr = v.x * w; vi = v.y * w;
            }
        }
        sre[i * RSTR + SWZ(n2)] = vr;
        sim[i * RSTR + SWZ(n2)] = vi;
    }
    __syncthreads();
    const int g = t >> 4, u = t & 15;
    fft256_soa<SIGN, true, 0>(sre + g * RSTR, sim + g * RSTR, u, n10 + g, 1.f);
    __syncthreads();
#pragma unroll
    for (int it = 0; it < 16; ++it) {
        int flat = it * 256 + t;
        int i = flat & 15;
        int k2 = flat >> 4;
        int s = i * RSTR + SWZ(k2);
        if (HALFOUT)
            ((__half2*)Dout)[(size_t)r * NN + (k2 << 8) + (n10 + i)] =
                __floats2half2_rn(sre[s] * (1.0f / 256.0f), sim[s] * (1.0f / 256.0f));
        else
            ((float2*)Dout)[(size_t)r * NN + (k2 << 8) + (n10 + i)] = make_float2(sre[s], sim[s]);
    }
}

// -------- stage 2, complex output (forward FFTs: XF and C) --------
template<int SIGN>
__global__ __launch_bounds__(256)
void fft_stage2c(const float2* __restrict__ Din, float2* __restrict__ outC, int obase)
{
    __shared__ float sre[16 * RSTR];
    __shared__ float sim[16 * RSTR];
    const int t = threadIdx.x;
    const int r = blockIdx.x >> 4;
    const int k20 = (blockIdx.x & 15) << 4;
#pragma unroll
    for (int it = 0; it < 16; ++it) {
        float2 v = Din[(size_t)r * NN + ((size_t)(k20 + it) << 8) + t];
        sre[it * RSTR + SWZ(t)] = v.x;
        sim[it * RSTR + SWZ(t)] = v.y;
    }
    __syncthreads();
    const int g = t >> 4, u = t & 15;
    fft256_soa<SIGN, false, 0>(sre + g * RSTR, sim + g * RSTR, u, 0, 1.f);
    __syncthreads();
    const size_t orow = (size_t)(obase + r) * NN;
#pragma unroll
    for (int it = 0; it < 16; ++it) {
        int flat = it * 256 + t;
        int fi = flat & 15;
        int k1 = flat >> 4;
        int s = fi * RSTR + SWZ(k1);
        outC[orow + (size_t)(k20 + fi) + ((size_t)k1 << 8)] = make_float2(sre[s], sim[s]);
    }
}

// -------- fused U1 middle: ifft-stage2 + modulus + fwd-stage1(+bigtw) --------
__global__ __launch_bounds__(256)
void fft_mid(const float2* __restrict__ Din, float2* __restrict__ D2)
{
    __shared__ float sre[16 * RSTR];
    __shared__ float sim[16 * RSTR];
    const int t = threadIdx.x;
    const int r = blockIdx.x >> 4;
    const int k20 = (blockIdx.x & 15) << 4;
#pragma unroll
    for (int it = 0; it < 16; ++it) {
        float2 v = Din[(size_t)r * NN + ((size_t)(k20 + it) << 8) + t];
        sre[it * RSTR + SWZ(t)] = v.x;
        sim[it * RSTR + SWZ(t)] = v.y;
    }
    __syncthreads();
    const int g = t >> 4, u = t & 15;
    float* rr = sre + g * RSTR; float* ri = sim + g * RSTR;
    // ifft + |.|/N -> true U1 samples at k = (k20+g) + 256*k1 (slot k1)
    fft256_soa<1, false, 1>(rr, ri, u, 0, 1.0f / (float)NN);
    // those samples are column n1=k20+g of the fwd 4-step
    fft256_soa<-1, true, 0>(rr, ri, u, k20 + g, 1.f);
    __syncthreads();
#pragma unroll
    for (int it = 0; it < 16; ++it) {
        int flat = it * 256 + t;
        int i = flat & 15;
        int k2 = flat >> 4;
        int s = i * RSTR + SWZ(k2);
        D2[(size_t)r * NN + (k2 << 8) + (k20 + i)] = make_float2(sre[s], sim[s]);
    }
}

// -------- second-order stage 2: half-precision in, ifft + |.| + fused Gaussian lowpass --------
// Writes per-block partial lowpass sums P[r][blk16][n] (sum over this block's 16 k2-rows).
__global__ __launch_bounds__(256)
void fft_stage2_s2(const __half2* __restrict__ Din, float* __restrict__ P)
{
    __shared__ float sre[16 * RSTR];
    __shared__ float sim[16 * RSTR];
    __shared__ float wtab[16][8];
    const int t = threadIdx.x;
    const int r = blockIdx.x >> 4;
    const int k20 = (blockIdx.x & 15) << 4;
#pragma unroll
    for (int it = 0; it < 16; ++it) {
        float2 v = __half22float2(Din[(size_t)r * NN + ((size_t)(k20 + it) << 8) + t]);
        sre[it * RSTR + SWZ(t)] = v.x;
        sim[it * RSTR + SWZ(t)] = v.y;
    }
    // per-block lowpass weights: w index k20+fi+256*Delta+768 is independent of n
    if (t < 128) {
        int fi = t >> 3, dd = (t & 7) - 4;
        int w = k20 + fi + (dd << 8) + 768;
        float val = 0.f;
        if (w >= 0 && w <= 1536) {
            float m = (float)(w - 768);
            val = 0.003426963f * __expf(-3.690276e-5f * m * m);  // sigphi*sqrt(2pi), 2pi^2 sigphi^2
        }
        wtab[fi][t & 7] = val;
    }
    __syncthreads();
    const int g = t >> 4, u = t & 15;
    fft256_soa<1, false, 1>(sre + g * RSTR, sim + g * RSTR, u, 0, 1.f);
    __syncthreads();
    // thread n=t accumulates sum over fi (16 rows) and Delta (8 taps)
    float acc = 0.f;
#pragma unroll
    for (int fi = 0; fi < 16; ++fi) {
        const float* row = sre + fi * RSTR;
#pragma unroll
        for (int dd = 0; dd < 8; ++dd) {
            int k1 = (t + dd - 4) & 255;
            acc = fmaf(row[SWZ(k1)], wtab[fi][dd], acc);
        }
    }
    // mags carried x256 (fp16 D scaled 1/256, ifft unnormalized): restore here
    P[((size_t)r * 16 + (blockIdx.x & 15)) * 256 + t] = acc * (1.0f / 256.0f);
}

__global__ __launch_bounds__(256)
void s2reduce_kernel(const float* __restrict__ P, float* __restrict__ out, int j1, int qs)
{
    const int r = blockIdx.x, n = threadIdx.x;
    const int q = qs + r;
    float s = 0.f;
#pragma unroll
    for (int b16 = 0; b16 < 16; ++b16) s += P[((size_t)r * 16 + b16) * 256 + n];
    const int j2 = j1 + 1 + (q >> 6);
    const int rb = q & 63;
    const int b = rb >> 3;
    const int chan = 65 + 4 * j2 * (j2 - 1) + j1 * 8 + (rb & 7);
    float mag = sqrtf(fmaf(s, s, 1e-8f));
    out[((size_t)b * 289 + chan) * 256 + n] = logf(mag + 1e-8f);
}

// ---- S0/S1: fold spectrum*phi mod 256 bins, 256-pt ifft (real part), log-mag ----
__global__ __launch_bounds__(256)
void sfold_kernel(const cplx* __restrict__ src, float* __restrict__ out, int j1)
{
    __shared__ cplx G[256];
    const int r = blockIdx.x;
    const int t = threadIdx.x;
    const float invsigphi = 731.428571f;   // 1 / (0.35 * 2^-8)
    cplx acc = make_float2(0.f, 0.f);
#pragma unroll
    for (int qq = -4; qq <= 4; ++qq) {
        int ks = t + (qq << 8);
        int k = ks & (NN - 1);
        float f = (float)ks * (1.0f / (float)NN);
        float a = f * invsigphi;
        float w = __expf(-0.5f * a * a);
        cplx v = src[(size_t)r * NN + k];
        acc.x = fmaf(v.x, w, acc.x);
        acc.y = fmaf(v.y, w, acc.y);
    }
    G[t] = acc;
    __syncthreads();
    float sb, cb;
    __sincosf((TWO_PI / 256.0f) * (float)t, &sb, &cb);
    float wr = 1.f, wi = 0.f;
    float s = 0.f;
    for (int kk = 0; kk < 256; ++kk) {
        s = fmaf(G[kk].x, wr, s);
        s = fmaf(-G[kk].y, wi, s);
        float nr = wr * cb - wi * sb; wi = wr * sb + wi * cb; wr = nr;
    }
    s *= (1.0f / (float)NN);
    float mag = sqrtf(fmaf(s, s, 1e-8f));
    float val = logf(mag + 1e-8f);
    int b, chan;
    if (j1 < 0) { b = r; chan = 0; }
    else { b = r >> 3; chan = 1 + j1 * 8 + (r & 7); }
    out[((size_t)b * 289 + chan) * 256 + t] = val;
}

__global__ void zero_kernel(float* p, int nElem)
{
    int i = blockIdx.x * 256 + threadIdx.x;
    if (i < nElem) p[i] = 0.f;
}

extern "C" void kernel_launch(void* const* d_in, const int* in_sizes, int n_in,
                              void* d_out, int out_size, void* d_ws, size_t ws_size,
                              hipStream_t stream)
{
    const float* x = (const float*)d_in[0];
    float* out = (float*)d_out;
    char* ws = (char*)d_ws;

    const size_t NB = (size_t)NN;
    float2* XF = (float2*)ws;                               // 8 rows cplx
    float2* C  = (float2*)(ws + 8 * NB * 8);                // 64 rows cplx
    const size_t fixedEnd = 8 * NB * 8 + 64 * NB * 8;

    long avail = (long)ws_size - (long)fixedEnd;
    int CH = (int)(avail / (long)(NB * 16));   // D (8B/elem) + D2 (8B/elem)
    if (CH > 64) CH = 64;
    if (CH < 1) CH = 1;
    float2*  D   = (float2*)(ws + fixedEnd);
    float2*  D2  = (float2*)(ws + fixedEnd + (size_t)CH * NB * 8);
    __half2* Dh  = (__half2*)D;    // second-order half-precision intermediate (reuses D)
    float*   P   = (float*)D2;     // second-order partial lowpass (reuses D2)

    {
        int nz = 8 * 289 * 256;
        zero_kernel<<<(nz + 255) / 256, 256, 0, stream>>>(out + nz, nz);
    }

    // XF = fft(x)
    for (int cs = 0; cs < 8; cs += CH) {
        int m = (8 - cs < CH) ? (8 - cs) : CH;
        fft_stage1<-1, 0, false><<<m * 16, 256, 0, stream>>>(x, nullptr, (void*)D, cs, 0);
        fft_stage2c<-1><<<m * 16, 256, 0, stream>>>(D, XF, cs);
    }
    sfold_kernel<<<8, 256, 0, stream>>>(XF, out, -1);

    for (int j1 = 0; j1 < 8; ++j1) {
        // C = fft(|ifft(XF * psi1)|) for this octave's 64 (b,lam) rows
        for (int cs = 0; cs < 64; cs += CH) {
            int m = (64 - cs < CH) ? (64 - cs) : CH;
            fft_stage1<1, 1, false><<<m * 16, 256, 0, stream>>>(nullptr, XF, (void*)D, cs, j1);
            fft_mid<<<m * 16, 256, 0, stream>>>(D, D2);
            fft_stage2c<-1><<<m * 16, 256, 0, stream>>>(D2, C, cs);
        }
        sfold_kernel<<<64, 256, 0, stream>>>(C, out, j1);
        // second order: all j2 > j1 from this octave's C rows
        int totq = 64 * (7 - j1);
        for (int qsv = 0; qsv < totq; qsv += CH) {
            int m = (totq - qsv < CH) ? (totq - qsv) : CH;
            fft_stage1<1, 2, true><<<m * 16, 256, 0, stream>>>(nullptr, C, (void*)Dh, qsv, j1);
            fft_stage2_s2<<<m * 16, 256, 0, stream>>>(Dh, P);
            s2reduce_kernel<<<m, 256, 0, stream>>>(P, out, j1, qsv);
        }
    }
}

// Round 4
// 801.715 us; speedup vs baseline: 3.5246x; 1.6257x over previous
//
#include <hip/hip_runtime.h>
#include <hip/hip_fp16.h>
#include <math.h>

#define NN 65536
#define TWO_PI 6.283185307179586f
#define RSTR 264   // LDS row stride in floats (264 % 32 == 8 -> conflict-free phases)
#define SWZ(m) ((m) ^ (((m) >> 4) & 15))
#define CTOT 9781248ul   // total fp16-windowed C elements (sum of 64*CW[j1])

// per-octave C window: signed-bin lo, width, element offset (compile-time, 6.1-sigma bands)
__constant__ int CLO[8] = {-32768, -15360, -7680, -3840, -2048, -1024, -1024, -1024};
__constant__ int CWW[8] = {65536, 42240, 21248, 10752, 5632, 2816, 2304, 2304};
__constant__ unsigned long COFF[8] = {0ul, 4194304ul, 6897664ul, 8257536ul,
                                      8945664ul, 9306112ul, 9486336ul, 9633792ul};

__device__ __forceinline__ void lds_fence() {
    asm volatile("s_waitcnt lgkmcnt(0)" ::: "memory");
}

// ---------------- radix-4 x radix-4 16-point FFT, natural order in/out ----------------
template<int SIGN>
__device__ __forceinline__ void fft16(float* xr, float* xi, float* yr, float* yi)
{
    const float S = (SIGN > 0) ? 1.0f : -1.0f;
    const float C8 = 0.92387953251f, S8 = 0.38268343236f, R2 = 0.70710678119f;
#pragma unroll
    for (int n0 = 0; n0 < 4; ++n0) {
        float z0r=xr[n0],    z0i=xi[n0];
        float z1r=xr[n0+4],  z1i=xi[n0+4];
        float z2r=xr[n0+8],  z2i=xi[n0+8];
        float z3r=xr[n0+12], z3i=xi[n0+12];
        float t0r=z0r+z2r, t0i=z0i+z2i;
        float t1r=z0r-z2r, t1i=z0i-z2i;
        float t2r=z1r+z3r, t2i=z1i+z3i;
        float t3r=S*(z1r-z3r), t3i=S*(z1i-z3i);
        xr[n0]=t0r+t2r;      xi[n0]=t0i+t2i;
        xr[n0+4]=t1r-t3i;    xi[n0+4]=t1i+t3r;
        xr[n0+8]=t0r-t2r;    xi[n0+8]=t0i-t2i;
        xr[n0+12]=t1r+t3i;   xi[n0+12]=t1i-t3r;
    }
    {
        const float W1r=C8,  W1i=S*S8;
        const float W2r=R2,  W2i=S*R2;
        const float W3r=S8,  W3i=S*C8;
        const float W6r=-R2, W6i=S*R2;
        const float W9r=-C8, W9i=-S*S8;
#define TWID(idx, wr, wi) { float ar=xr[idx], ai=xi[idx]; xr[idx]=ar*(wr)-ai*(wi); xi[idx]=ar*(wi)+ai*(wr); }
        TWID(5,W1r,W1i)  TWID(9,W2r,W2i)   TWID(13,W3r,W3i)
        TWID(6,W2r,W2i)  { float ar=xr[10], ai=xi[10]; xr[10]=-S*ai; xi[10]=S*ar; } TWID(14,W6r,W6i)
        TWID(7,W3r,W3i)  TWID(11,W6r,W6i)  TWID(15,W9r,W9i)
#undef TWID
    }
#pragma unroll
    for (int p = 0; p < 4; ++p) {
        float z0r=xr[4*p],   z0i=xi[4*p];
        float z1r=xr[4*p+1], z1i=xi[4*p+1];
        float z2r=xr[4*p+2], z2i=xi[4*p+2];
        float z3r=xr[4*p+3], z3i=xi[4*p+3];
        float t0r=z0r+z2r, t0i=z0i+z2i;
        float t1r=z0r-z2r, t1i=z0i-z2i;
        float t2r=z1r+z3r, t2i=z1i+z3i;
        float t3r=S*(z1r-z3r), t3i=S*(z1i-z3i);
        yr[p]=t0r+t2r;     yi[p]=t0i+t2i;
        yr[p+4]=t1r-t3i;   yi[p+4]=t1i+t3r;
        yr[p+8]=t0r-t2r;   yi[p+8]=t0i-t2i;
        yr[p+12]=t1r+t3i;  yi[p+12]=t1i-t3r;
    }
}

// ---------------- 256-pt FFT on one group's SoA LDS row (16 lanes, one wave) ----------
// OUT: 0 = complex back to LDS, 1 = |.|*mscale to re-plane
template<int SIGN, bool BIGTW, int OUT>
__device__ __forceinline__ void fft256_soa(float* rr, float* ri, int u, int n1, float mscale)
{
    float xr[16], xi[16], yr[16], yi[16];
#pragma unroll
    for (int b = 0; b < 16; ++b) {
        int s = SWZ(u + (b << 4));
        xr[b] = rr[s]; xi[b] = ri[s];
    }
    fft16<SIGN>(xr, xi, yr, yi);
    float sa, ca;
    __sincosf((float)SIGN * (TWO_PI / 256.0f) * (float)u, &sa, &ca);
    float twr = 1.f, twi = 0.f;
#pragma unroll
    for (int c = 0; c < 16; ++c) {
        int s = SWZ((c << 4) + u);
        rr[s] = yr[c] * twr - yi[c] * twi;
        ri[s] = yr[c] * twi + yi[c] * twr;
        float nr = twr * ca - twi * sa; twi = twr * sa + twi * ca; twr = nr;
    }
    lds_fence();
#pragma unroll
    for (int a = 0; a < 16; ++a) {
        int s = SWZ((u << 4) + a);
        xr[a] = rr[s]; xi[a] = ri[s];
    }
    fft16<SIGN>(xr, xi, yr, yi);
    float tbr = 1.f, tbi = 0.f, str = 1.f, sti = 0.f;
    if (BIGTW) {
        float s0, c0, s1, c1;
        __sincosf((float)SIGN * (TWO_PI / (float)NN) * (float)(n1 * u), &s0, &c0);
        __sincosf((float)SIGN * (TWO_PI / (float)NN) * (float)(n1 << 4), &s1, &c1);
        tbr = c0; tbi = s0; str = c1; sti = s1;
    }
#pragma unroll
    for (int d = 0; d < 16; ++d) {
        float vr = yr[d], vi = yi[d];
        if (BIGTW) {
            float pr = vr * tbr - vi * tbi, pi = vr * tbi + vi * tbr;
            vr = pr; vi = pi;
            float nr = tbr * str - tbi * sti; tbi = tbr * sti + tbi * str; tbr = nr;
        }
        int s = SWZ(u + (d << 4));
        if (OUT == 1) { rr[s] = sqrtf(fmaf(vr, vr, vi * vi)) * mscale; ri[s] = 0.f; }
        else { rr[s] = vr; ri[s] = vi; }
    }
    lds_fence();
}

// ================= XF chain (fp32, 8 rows) =================
__global__ __launch_bounds__(256)
void xf_stage1(const float* __restrict__ x, float2* __restrict__ D)
{
    __shared__ float sre[16 * RSTR];
    __shared__ float sim[16 * RSTR];
    const int t = threadIdx.x;
    const int r = blockIdx.x >> 4;
    const int n10 = (blockIdx.x & 15) << 4;
#pragma unroll
    for (int it = 0; it < 16; ++it) {
        int flat = it * 256 + t;
        int i = flat & 15, n2 = flat >> 4;
        int n = (n10 + i) + (n2 << 8);
        sre[i * RSTR + SWZ(n2)] = x[(size_t)r * NN + n];
        sim[i * RSTR + SWZ(n2)] = 0.f;
    }
    __syncthreads();
    const int g = t >> 4, u = t & 15;
    fft256_soa<-1, true, 0>(sre + g * RSTR, sim + g * RSTR, u, n10 + g, 1.f);
    __syncthreads();
#pragma unroll
    for (int it = 0; it < 16; ++it) {
        int flat = it * 256 + t;
        int i = flat & 15, k2 = flat >> 4;
        int s = i * RSTR + SWZ(k2);
        D[(size_t)r * NN + (k2 << 8) + (n10 + i)] = make_float2(sre[s], sim[s]);
    }
}

__global__ __launch_bounds__(256)
void xf_stage2(const float2* __restrict__ D, float2* __restrict__ XF)
{
    __shared__ float sre[16 * RSTR];
    __shared__ float sim[16 * RSTR];
    const int t = threadIdx.x;
    const int r = blockIdx.x >> 4;
    const int k20 = (blockIdx.x & 15) << 4;
#pragma unroll
    for (int it = 0; it < 16; ++it) {
        float2 v = D[(size_t)r * NN + ((size_t)(k20 + it) << 8) + t];
        sre[it * RSTR + SWZ(t)] = v.x;
        sim[it * RSTR + SWZ(t)] = v.y;
    }
    __syncthreads();
    const int g = t >> 4, u = t & 15;
    fft256_soa<-1, false, 0>(sre + g * RSTR, sim + g * RSTR, u, 0, 1.f);
    __syncthreads();
#pragma unroll
    for (int it = 0; it < 16; ++it) {
        int flat = it * 256 + t;
        int fi = flat & 15, k1 = flat >> 4;
        int s = fi * RSTR + SWZ(k1);
        XF[(size_t)r * NN + (size_t)(k20 + fi) + ((size_t)k1 << 8)] = make_float2(sre[s], sim[s]);
    }
}

// ================= first-order chain (all 512 rows, fp16 intermediates) =================
// stage1: ifft cols of XF*psi1, scaled 1/16, q = qbase + r, j1=q>>6, batch=(q>>3)&7, w=q&7
__global__ __launch_bounds__(256)
void fo_stage1(const float2* __restrict__ XF, __half2* __restrict__ Dh, int qbase)
{
    __shared__ float sre[16 * RSTR];
    __shared__ float sim[16 * RSTR];
    const int t = threadIdx.x;
    const int r = blockIdx.x >> 4;
    const int n10 = (blockIdx.x & 15) << 4;
    const int q = qbase + r;
    const int j1 = q >> 6, ql = q & 63;
    const int srow = ql >> 3, w = ql & 7;
    const int lam = j1 * 8 + w;
    const float xi = 0.35f * exp2f(-(float)lam * 0.125f);
    const float invsig = 8.0f / xi;
    const float kc = xi * (float)NN;
    const float Hh = 6.10f * (xi * 0.125f) * (float)NN;
#pragma unroll
    for (int it = 0; it < 16; ++it) {
        int flat = it * 256 + t;
        int i = flat & 15, n2 = flat >> 4;
        int n = (n10 + i) + (n2 << 8);
        float nsf = (float)((n < NN / 2) ? n : n - NN);
        float vr = 0.f, vi = 0.f;
        if (fabsf(nsf - kc) <= Hh) {
            float2 v = XF[(size_t)srow * NN + n];
            float a = (nsf * (1.0f / (float)NN) - xi) * invsig;
            float wg = __expf(-0.5f * a * a) * 0.0625f;   // 1/16 fp16 headroom
            vr = v.x * wg; vi = v.y * wg;
        }
        sre[i * RSTR + SWZ(n2)] = vr;
        sim[i * RSTR + SWZ(n2)] = vi;
    }
    __syncthreads();
    const int g = t >> 4, u = t & 15;
    fft256_soa<1, true, 0>(sre + g * RSTR, sim + g * RSTR, u, n10 + g, 1.f);
    __syncthreads();
#pragma unroll
    for (int it = 0; it < 16; ++it) {
        int flat = it * 256 + t;
        int i = flat & 15, k2 = flat >> 4;
        int s = i * RSTR + SWZ(k2);
        Dh[(size_t)r * NN + (k2 << 8) + (n10 + i)] = __floats2half2_rn(sre[s], sim[s]);
    }
}

// mid: ifft rows + |.| (true U1 via mscale=16/N) + fwd cols with big twiddle
__global__ __launch_bounds__(256)
void fo_mid(const __half2* __restrict__ Dh, __half2* __restrict__ D2h)
{
    __shared__ float sre[16 * RSTR];
    __shared__ float sim[16 * RSTR];
    const int t = threadIdx.x;
    const int r = blockIdx.x >> 4;
    const int k20 = (blockIdx.x & 15) << 4;
#pragma unroll
    for (int it = 0; it < 16; ++it) {
        float2 v = __half22float2(Dh[(size_t)r * NN + ((size_t)(k20 + it) << 8) + t]);
        sre[it * RSTR + SWZ(t)] = v.x;
        sim[it * RSTR + SWZ(t)] = v.y;
    }
    __syncthreads();
    const int g = t >> 4, u = t & 15;
    float* rr = sre + g * RSTR; float* ri = sim + g * RSTR;
    fft256_soa<1, false, 1>(rr, ri, u, 0, 16.0f / (float)NN);
    fft256_soa<-1, true, 0>(rr, ri, u, k20 + g, 1.f);
    __syncthreads();
#pragma unroll
    for (int it = 0; it < 16; ++it) {
        int flat = it * 256 + t;
        int i = flat & 15, k2 = flat >> 4;
        int s = i * RSTR + SWZ(k2);
        D2h[(size_t)r * NN + (k2 << 8) + (k20 + i)] = __floats2half2_rn(sre[s], sim[s]);
    }
}

// stage2: fwd rows -> C, fp16, windowed store per octave
__global__ __launch_bounds__(256)
void fo_stage2(const __half2* __restrict__ D2h, __half2* __restrict__ Cw, int qbase)
{
    __shared__ float sre[16 * RSTR];
    __shared__ float sim[16 * RSTR];
    const int t = threadIdx.x;
    const int r = blockIdx.x >> 4;
    const int k20 = (blockIdx.x & 15) << 4;
    const int q = qbase + r;
    const int j1 = q >> 6, ql = q & 63;
#pragma unroll
    for (int it = 0; it < 16; ++it) {
        float2 v = __half22float2(D2h[(size_t)r * NN + ((size_t)(k20 + it) << 8) + t]);
        sre[it * RSTR + SWZ(t)] = v.x;
        sim[it * RSTR + SWZ(t)] = v.y;
    }
    __syncthreads();
    const int g = t >> 4, u = t & 15;
    fft256_soa<-1, false, 0>(sre + g * RSTR, sim + g * RSTR, u, 0, 1.f);
    __syncthreads();
    const size_t base = COFF[j1] + (size_t)ql * CWW[j1];
    const int lo = CLO[j1], Wd = CWW[j1];
#pragma unroll
    for (int it = 0; it < 16; ++it) {
        int flat = it * 256 + t;
        int fi = flat & 15, k1 = flat >> 4;
        int k = (k20 + fi) + (k1 << 8);
        int ksg = (k < NN / 2) ? k : k - NN;
        int idx = ksg - lo;
        if (idx >= 0 && idx < Wd) {
            int s = fi * RSTR + SWZ(k1);
            Cw[base + idx] = __floats2half2_rn(sre[s], sim[s]);
        }
    }
}

// ============== S0 + S1 fold (one launch, 8 + 512 blocks) ==============
__global__ __launch_bounds__(256)
void sfold_all(const float2* __restrict__ XF, const __half2* __restrict__ Cw,
               float* __restrict__ out)
{
    __shared__ float Gr[256];
    __shared__ float Gi[256];
    const int blk = blockIdx.x;
    const int t = threadIdx.x;
    const float invsigphi = 731.428571f;   // 1 / (0.35 * 2^-8)
    float ar = 0.f, ai = 0.f;
    if (blk < 8) {
#pragma unroll
        for (int qq = -4; qq <= 4; ++qq) {
            int ks = t + (qq << 8);
            int k = ks & (NN - 1);
            float a = ((float)ks * (1.0f / (float)NN)) * invsigphi;
            float wg = __expf(-0.5f * a * a);
            float2 v = XF[(size_t)blk * NN + k];
            ar = fmaf(v.x, wg, ar); ai = fmaf(v.y, wg, ai);
        }
    } else {
        int q = blk - 8;
        int j1 = q >> 6, ql = q & 63;
        size_t base = COFF[j1] + (size_t)ql * CWW[j1];
        int lo = CLO[j1];
#pragma unroll
        for (int qq = -4; qq <= 4; ++qq) {
            int ks = t + (qq << 8);
            float a = ((float)ks * (1.0f / (float)NN)) * invsigphi;
            float wg = __expf(-0.5f * a * a);
            float2 v = __half22float2(Cw[base + (ks - lo)]);
            ar = fmaf(v.x, wg, ar); ai = fmaf(v.y, wg, ai);
        }
    }
    Gr[t] = ar; Gi[t] = ai;
    __syncthreads();
    float sb, cb;
    __sincosf((TWO_PI / 256.0f) * (float)t, &sb, &cb);
    float wr = 1.f, wi = 0.f, s = 0.f;
    for (int kk = 0; kk < 256; ++kk) {
        s = fmaf(Gr[kk], wr, s);
        s = fmaf(-Gi[kk], wi, s);
        float nr = wr * cb - wi * sb; wi = wr * sb + wi * cb; wr = nr;
    }
    s *= (1.0f / (float)NN);
    float mag = sqrtf(fmaf(s, s, 1e-8f));
    float val = logf(mag + 1e-8f);
    int b, chan;
    if (blk < 8) { b = blk; chan = 0; }
    else { int q = blk - 8; int j1 = q >> 6, ql = q & 63; b = ql >> 3; chan = 1 + j1 * 8 + (ql & 7); }
    out[((size_t)b * 289 + chan) * 256 + t] = val;
}

// ============== second-order chain (all 1792 rows) ==============
__device__ __forceinline__ void so_decode(int q, int& j1, int& j2, int& rb)
{
    int pp = q >> 6;
    rb = q & 63;
    j2 = 1;
#pragma unroll
    for (int m = 1; m < 8; ++m)
        if (pp >= (m * (m + 1)) / 2) j2 = m + 1;
    j1 = pp - (j2 * (j2 - 1)) / 2;
}

__global__ __launch_bounds__(256)
void so_stage1(const __half2* __restrict__ Cw, __half2* __restrict__ Dh, int qbase)
{
    __shared__ float sre[16 * RSTR];
    __shared__ float sim[16 * RSTR];
    const int t = threadIdx.x;
    const int r = blockIdx.x >> 4;
    const int n10 = (blockIdx.x & 15) << 4;
    int j1, j2, rb;
    so_decode(qbase + r, j1, j2, rb);
    const float xi2 = 0.35f * exp2f(-(float)j2);
    const float invsig = 1.0f / (0.6f * xi2);
    const float kc = xi2 * (float)NN;
    const float Hh = 6.10f * (0.6f * xi2) * (float)NN;
    const size_t base = COFF[j1] + (size_t)rb * CWW[j1];
    const int lo = CLO[j1];
#pragma unroll
    for (int it = 0; it < 16; ++it) {
        int flat = it * 256 + t;
        int i = flat & 15, n2 = flat >> 4;
        int n = (n10 + i) + (n2 << 8);
        int ksg = (n < NN / 2) ? n : n - NN;
        float nsf = (float)ksg;
        float vr = 0.f, vi = 0.f;
        if (fabsf(nsf - kc) <= Hh) {
            float2 v = __half22float2(Cw[base + (ksg - lo)]);
            float a = (nsf * (1.0f / (float)NN) - xi2) * invsig;
            float wg = __expf(-0.5f * a * a) * (1.0f / 256.0f);
            vr = v.x * wg; vi = v.y * wg;
        }
        sre[i * RSTR + SWZ(n2)] = vr;
        sim[i * RSTR + SWZ(n2)] = vi;
    }
    __syncthreads();
    const int g = t >> 4, u = t & 15;
    fft256_soa<1, true, 0>(sre + g * RSTR, sim + g * RSTR, u, n10 + g, 1.f);
    __syncthreads();
#pragma unroll
    for (int it = 0; it < 16; ++it) {
        int flat = it * 256 + t;
        int i = flat & 15, k2 = flat >> 4;
        int s = i * RSTR + SWZ(k2);
        Dh[(size_t)r * NN + (k2 << 8) + (n10 + i)] = __floats2half2_rn(sre[s], sim[s]);
    }
}

// ifft rows + modulus + fused Gaussian-lowpass partial; atomic accumulate into S2acc
__global__ __launch_bounds__(256)
void so_stage2(const __half2* __restrict__ Dh, float* __restrict__ S2acc, int qbase)
{
    __shared__ float sre[16 * RSTR];
    __shared__ float sim[16 * RSTR];
    __shared__ float wtab[16][8];
    const int t = threadIdx.x;
    const int r = blockIdx.x >> 4;
    const int k20 = (blockIdx.x & 15) << 4;
#pragma unroll
    for (int it = 0; it < 16; ++it) {
        float2 v = __half22float2(Dh[(size_t)r * NN + ((size_t)(k20 + it) << 8) + t]);
        sre[it * RSTR + SWZ(t)] = v.x;
        sim[it * RSTR + SWZ(t)] = v.y;
    }
    if (t < 128) {
        int fi = t >> 3, dd = (t & 7) - 4;
        int w = k20 + fi + (dd << 8) + 768;
        float val = 0.f;
        if (w >= 0 && w <= 1536) {
            float m = (float)(w - 768);
            val = 0.003426963f * __expf(-3.690276e-5f * m * m);
        }
        wtab[fi][t & 7] = val;
    }
    __syncthreads();
    const int g = t >> 4, u = t & 15;
    fft256_soa<1, false, 1>(sre + g * RSTR, sim + g * RSTR, u, 0, 1.f);
    __syncthreads();
    float acc = 0.f;
#pragma unroll
    for (int fi = 0; fi < 16; ++fi) {
        const float* row = sre + fi * RSTR;
#pragma unroll
        for (int dd = 0; dd < 8; ++dd) {
            int k1 = (t + dd - 4) & 255;
            acc = fmaf(row[SWZ(k1)], wtab[fi][dd], acc);
        }
    }
    atomicAdd(&S2acc[(size_t)(qbase + r) * 256 + t], acc * (1.0f / 256.0f));
}

__global__ __launch_bounds__(256)
void s2final(const float* __restrict__ S2acc, float* __restrict__ out)
{
    const int q = blockIdx.x, n = threadIdx.x;
    int j1, j2, rb;
    so_decode(q, j1, j2, rb);
    const int b = rb >> 3;
    const int chan = 65 + 4 * j2 * (j2 - 1) + j1 * 8 + (rb & 7);
    float s = S2acc[(size_t)q * 256 + n];
    float mag = sqrtf(fmaf(s, s, 1e-8f));
    out[((size_t)b * 289 + chan) * 256 + n] = logf(mag + 1e-8f);
}

__global__ void zero_kernel(float* p, int nElem)
{
    int i = blockIdx.x * 256 + threadIdx.x;
    if (i < nElem) p[i] = 0.f;
}

extern "C" void kernel_launch(void* const* d_in, const int* in_sizes, int n_in,
                              void* d_out, int out_size, void* d_ws, size_t ws_size,
                              hipStream_t stream)
{
    const float* x = (const float*)d_in[0];
    float* out = (float*)d_out;
    char* ws = (char*)d_ws;

    float2*  XF    = (float2*)ws;                                  // 8 rows fp32 = 4 MB
    __half2* Cw    = (__half2*)(ws + 8ul * NN * 8);                // windowed fp16 C ≈ 37.3 MB
    float*   S2acc = (float*)(ws + 8ul * NN * 8 + CTOT * 4ul);     // 1792*256 fp32 ≈ 1.75 MB
    size_t offCh = 8ul * NN * 8 + CTOT * 4ul + 1792ul * 256 * 4;
    offCh = (offCh + 255) & ~255ul;
    size_t avail = (ws_size > offCh) ? (ws_size - offCh) : 0;

    int CHB = (int)(avail / (2ul * NN * 4));   // Dh + D2h, 256 KB/row each
    if (CHB > 512) CHB = 512;
    if (CHB < 1) CHB = 1;
    int CHD = (int)(avail / ((size_t)NN * 4)); // Dh only
    if (CHD > 1792) CHD = 1792;
    if (CHD < 1) CHD = 1;

    __half2* DhB = (__half2*)(ws + offCh);
    __half2* D2h = DhB + (size_t)CHB * NN;
    float2*  Df  = (float2*)(ws + offCh);      // fp32 scratch for XF chain (4 MB)
    __half2* DhD = (__half2*)(ws + offCh);

    {   // zero imag half of out + S2 accumulator
        int nz = 8 * 289 * 256;
        zero_kernel<<<(nz + 255) / 256, 256, 0, stream>>>(out + nz, nz);
        int na = 1792 * 256;
        zero_kernel<<<(na + 255) / 256, 256, 0, stream>>>(S2acc, na);
    }

    // XF = fft(x)
    xf_stage1<<<8 * 16, 256, 0, stream>>>(x, Df);
    xf_stage2<<<8 * 16, 256, 0, stream>>>(Df, XF);

    // first order: all 512 rows -> windowed fp16 C
    for (int cs = 0; cs < 512; cs += CHB) {
        int m = (512 - cs < CHB) ? (512 - cs) : CHB;
        fo_stage1<<<m * 16, 256, 0, stream>>>(XF, DhB, cs);
        fo_mid<<<m * 16, 256, 0, stream>>>(DhB, D2h);
        fo_stage2<<<m * 16, 256, 0, stream>>>(D2h, Cw, cs);
    }

    // S0 + S1 in one launch
    sfold_all<<<8 + 512, 256, 0, stream>>>(XF, Cw, out);

    // second order: all 1792 rows
    for (int qs = 0; qs < 1792; qs += CHD) {
        int m = (1792 - qs < CHD) ? (1792 - qs) : CHD;
        so_stage1<<<m * 16, 256, 0, stream>>>(Cw, DhD, qs);
        so_stage2<<<m * 16, 256, 0, stream>>>(DhD, S2acc, qs);
    }
    s2final<<<1792, 256, 0, stream>>>(S2acc, out);
}

// Round 5
// 395.622 us; speedup vs baseline: 7.1425x; 2.0265x over previous
//
#include <hip/hip_runtime.h>
#include <hip/hip_fp16.h>
#include <math.h>

#define NN 65536
#define TWO_PI 6.283185307179586f
#define RSTR 264   // LDS row stride in floats (264 % 32 == 8 -> conflict-free phases)
#define SWZ(m) ((m) ^ (((m) >> 4) & 15))
#define CTOT 9781248ul   // total fp16-windowed C elements

// per-octave C window: signed-bin lo, width, element offset (6.1-sigma unions)
__constant__ int CLO[8] = {-32768, -15360, -7680, -3840, -2048, -1024, -1024, -1024};
__constant__ int CWW[8] = {65536, 42240, 21248, 10752, 5632, 2816, 2304, 2304};
__constant__ unsigned long COFF[8] = {0ul, 4194304ul, 6897664ul, 8257536ul,
                                      8945664ul, 9306112ul, 9486336ul, 9633792ul};

__device__ __forceinline__ void lds_fence() {
    asm volatile("s_waitcnt lgkmcnt(0)" ::: "memory");
}
__device__ __forceinline__ int rev16(int p) { return ((p & 3) << 2) | (p >> 2); }
__device__ __forceinline__ int rev64(int p) { return ((p & 3) << 4) | (p & 12) | (p >> 4); }

// ---------------- radix-4 x radix-4 16-point FFT, natural order in/out ----------------
template<int SIGN>
__device__ __forceinline__ void fft16(float* xr, float* xi, float* yr, float* yi)
{
    const float S = (SIGN > 0) ? 1.0f : -1.0f;
    const float C8 = 0.92387953251f, S8 = 0.38268343236f, R2 = 0.70710678119f;
#pragma unroll
    for (int n0 = 0; n0 < 4; ++n0) {
        float z0r=xr[n0],    z0i=xi[n0];
        float z1r=xr[n0+4],  z1i=xi[n0+4];
        float z2r=xr[n0+8],  z2i=xi[n0+8];
        float z3r=xr[n0+12], z3i=xi[n0+12];
        float t0r=z0r+z2r, t0i=z0i+z2i;
        float t1r=z0r-z2r, t1i=z0i-z2i;
        float t2r=z1r+z3r, t2i=z1i+z3i;
        float t3r=S*(z1r-z3r), t3i=S*(z1i-z3i);
        xr[n0]=t0r+t2r;      xi[n0]=t0i+t2i;
        xr[n0+4]=t1r-t3i;    xi[n0+4]=t1i+t3r;
        xr[n0+8]=t0r-t2r;    xi[n0+8]=t0i-t2i;
        xr[n0+12]=t1r+t3i;   xi[n0+12]=t1i-t3r;
    }
    {
        const float W1r=C8,  W1i=S*S8;
        const float W2r=R2,  W2i=S*R2;
        const float W3r=S8,  W3i=S*C8;
        const float W6r=-R2, W6i=S*R2;
        const float W9r=-C8, W9i=-S*S8;
#define TWID(idx, wr, wi) { float ar=xr[idx], ai=xi[idx]; xr[idx]=ar*(wr)-ai*(wi); xi[idx]=ar*(wi)+ai*(wr); }
        TWID(5,W1r,W1i)  TWID(9,W2r,W2i)   TWID(13,W3r,W3i)
        TWID(6,W2r,W2i)  { float ar=xr[10], ai=xi[10]; xr[10]=-S*ai; xi[10]=S*ar; } TWID(14,W6r,W6i)
        TWID(7,W3r,W3i)  TWID(11,W6r,W6i)  TWID(15,W9r,W9i)
#undef TWID
    }
#pragma unroll
    for (int p = 0; p < 4; ++p) {
        float z0r=xr[4*p],   z0i=xi[4*p];
        float z1r=xr[4*p+1], z1i=xi[4*p+1];
        float z2r=xr[4*p+2], z2i=xi[4*p+2];
        float z3r=xr[4*p+3], z3i=xi[4*p+3];
        float t0r=z0r+z2r, t0i=z0i+z2i;
        float t1r=z0r-z2r, t1i=z0i-z2i;
        float t2r=z1r+z3r, t2i=z1i+z3i;
        float t3r=S*(z1r-z3r), t3i=S*(z1i-z3i);
        yr[p]=t0r+t2r;     yi[p]=t0i+t2i;
        yr[p+4]=t1r-t3i;   yi[p+4]=t1i+t3r;
        yr[p+8]=t0r-t2r;   yi[p+8]=t0i-t2i;
        yr[p+12]=t1r+t3i;  yi[p+12]=t1i-t3r;
    }
}

// ---------------- 256-pt FFT on one group's SoA LDS row (16 lanes, one wave) ----------
// OUT: 0 = complex back to LDS, 1 = |.|*mscale to re-plane (im zeroed)
// BIGTW multiplies output k by e^{i*SIGN*twrate*n1*k}
template<int SIGN, bool BIGTW, int OUT>
__device__ __forceinline__ void fft256_soa(float* rr, float* ri, int u, int n1,
                                           float twrate, float mscale)
{
    float xr[16], xi[16], yr[16], yi[16];
#pragma unroll
    for (int b = 0; b < 16; ++b) {
        int s = SWZ(u + (b << 4));
        xr[b] = rr[s]; xi[b] = ri[s];
    }
    fft16<SIGN>(xr, xi, yr, yi);
    float sa, ca;
    __sincosf((float)SIGN * (TWO_PI / 256.0f) * (float)u, &sa, &ca);
    float twr = 1.f, twi = 0.f;
#pragma unroll
    for (int c = 0; c < 16; ++c) {
        int s = SWZ((c << 4) + u);
        rr[s] = yr[c] * twr - yi[c] * twi;
        ri[s] = yr[c] * twi + yi[c] * twr;
        float nr = twr * ca - twi * sa; twi = twr * sa + twi * ca; twr = nr;
    }
    lds_fence();
#pragma unroll
    for (int a = 0; a < 16; ++a) {
        int s = SWZ((u << 4) + a);
        xr[a] = rr[s]; xi[a] = ri[s];
    }
    fft16<SIGN>(xr, xi, yr, yi);
    float tbr = 1.f, tbi = 0.f, str = 1.f, sti = 0.f;
    if (BIGTW) {
        float s0, c0, s1, c1;
        __sincosf((float)SIGN * twrate * (float)(n1 * u), &s0, &c0);
        __sincosf((float)SIGN * twrate * (float)(n1 << 4), &s1, &c1);
        tbr = c0; tbi = s0; str = c1; sti = s1;
    }
#pragma unroll
    for (int d = 0; d < 16; ++d) {
        float vr = yr[d], vi = yi[d];
        if (BIGTW) {
            float pr = vr * tbr - vi * tbi, pi = vr * tbi + vi * tbr;
            vr = pr; vi = pi;
            float nr = tbr * str - tbi * sti; tbi = tbr * sti + tbi * str; tbr = nr;
        }
        int s = SWZ(u + (d << 4));
        if (OUT == 1) { rr[s] = sqrtf(fmaf(vr, vr, vi * vi)) * mscale; ri[s] = 0.f; }
        else { rr[s] = vr; ri[s] = vi; }
    }
    lds_fence();
}

// ---------- generic LDS radix-4 passes over the row axis (L rows, NC cols) ----------
// DIT: input rows digit-reversed, output natural. DIF: natural in, reversed out.
template<int L, int CLOG, int RST, int SIGN, bool SWZC>
__device__ __forceinline__ void lds_dit(float* re, float* im, int t, int T)
{
    const int NC = 1 << CLOG;
    const int nbf = NC * (L >> 2);
    for (int h = 1; h < L; h <<= 2) {
        __syncthreads();
        for (int i = t; i < nbf; i += T) {
            int c = i & (NC - 1);
            int bf = i >> CLOG;
            int j = bf & (h - 1);
            int q0 = ((bf - j) << 2) + j;
            int cs = SWZC ? SWZ(c) : c;
            int a0 = q0 * RST + cs;
            int a1 = a0 + h * RST, a2 = a1 + h * RST, a3 = a2 + h * RST;
            float x0r = re[a0], x0i = im[a0];
            float x1r = re[a1], x1i = im[a1];
            float x2r = re[a2], x2i = im[a2];
            float x3r = re[a3], x3i = im[a3];
            if (h > 1) {
                float ang = (float)SIGN * (TWO_PI / (float)(4 * h)) * (float)j;
                float sj, cj; __sincosf(ang, &sj, &cj);
                float c2 = cj * cj - sj * sj, s2 = 2.f * cj * sj;
                float c3 = c2 * cj - s2 * sj, s3 = c2 * sj + s2 * cj;
                float r;
                r = x1r * cj - x1i * sj; x1i = x1r * sj + x1i * cj; x1r = r;
                r = x2r * c2 - x2i * s2; x2i = x2r * s2 + x2i * c2; x2r = r;
                r = x3r * c3 - x3i * s3; x3i = x3r * s3 + x3i * c3; x3r = r;
            }
            float t0r = x0r + x2r, t0i = x0i + x2i;
            float t1r = x0r - x2r, t1i = x0i - x2i;
            float t2r = x1r + x3r, t2i = x1i + x3i;
            float t3r = -(float)SIGN * (x1i - x3i), t3i = (float)SIGN * (x1r - x3r);
            re[a0] = t0r + t2r; im[a0] = t0i + t2i;
            re[a1] = t1r + t3r; im[a1] = t1i + t3i;
            re[a2] = t0r - t2r; im[a2] = t0i - t2i;
            re[a3] = t1r - t3r; im[a3] = t1i - t3i;
        }
    }
    __syncthreads();
}

template<int L, int CLOG, int RST, int SIGN, bool SWZC>
__device__ __forceinline__ void lds_dif(float* re, float* im, int t, int T)
{
    const int NC = 1 << CLOG;
    const int nbf = NC * (L >> 2);
    for (int h = L >> 2; h >= 1; h >>= 2) {
        __syncthreads();
        for (int i = t; i < nbf; i += T) {
            int c = i & (NC - 1);
            int bf = i >> CLOG;
            int j = bf & (h - 1);
            int q0 = ((bf - j) << 2) + j;
            int cs = SWZC ? SWZ(c) : c;
            int a0 = q0 * RST + cs;
            int a1 = a0 + h * RST, a2 = a1 + h * RST, a3 = a2 + h * RST;
            float x0r = re[a0], x0i = im[a0];
            float x1r = re[a1], x1i = im[a1];
            float x2r = re[a2], x2i = im[a2];
            float x3r = re[a3], x3i = im[a3];
            float t0r = x0r + x2r, t0i = x0i + x2i;
            float t1r = x0r - x2r, t1i = x0i - x2i;
            float t2r = x1r + x3r, t2i = x1i + x3i;
            float t3r = -(float)SIGN * (x1i - x3i), t3i = (float)SIGN * (x1r - x3r);
            float y1r = t1r + t3r, y1i = t1i + t3i;
            float y2r = t0r - t2r, y2i = t0i - t2i;
            float y3r = t1r - t3r, y3i = t1i - t3i;
            re[a0] = t0r + t2r; im[a0] = t0i + t2i;
            if (h > 1) {
                float ang = (float)SIGN * (TWO_PI / (float)(4 * h)) * (float)j;
                float sj, cj; __sincosf(ang, &sj, &cj);
                float c2 = cj * cj - sj * sj, s2 = 2.f * cj * sj;
                float c3 = c2 * cj - s2 * sj, s3 = c2 * sj + s2 * cj;
                re[a1] = y1r * cj - y1i * sj; im[a1] = y1r * sj + y1i * cj;
                re[a2] = y2r * c2 - y2i * s2; im[a2] = y2r * s2 + y2i * c2;
                re[a3] = y3r * c3 - y3i * s3; im[a3] = y3r * s3 + y3i * c3;
            } else {
                re[a1] = y1r; im[a1] = y1i;
                re[a2] = y2r; im[a2] = y2i;
                re[a3] = y3r; im[a3] = y3i;
            }
        }
    }
    __syncthreads();
}

// ================= XF chain (fp32, 8 rows) =================
__global__ __launch_bounds__(256)
void xf_stage1(const float* __restrict__ x, float2* __restrict__ D)
{
    __shared__ float sre[16 * RSTR];
    __shared__ float sim[16 * RSTR];
    const int t = threadIdx.x;
    const int r = blockIdx.x >> 4;
    const int n10 = (blockIdx.x & 15) << 4;
#pragma unroll
    for (int it = 0; it < 16; ++it) {
        int flat = it * 256 + t;
        int i = flat & 15, n2 = flat >> 4;
        int n = (n10 + i) + (n2 << 8);
        sre[i * RSTR + SWZ(n2)] = x[(size_t)r * NN + n];
        sim[i * RSTR + SWZ(n2)] = 0.f;
    }
    __syncthreads();
    const int g = t >> 4, u = t & 15;
    fft256_soa<-1, true, 0>(sre + g * RSTR, sim + g * RSTR, u, n10 + g, TWO_PI / (float)NN, 1.f);
    __syncthreads();
#pragma unroll
    for (int it = 0; it < 16; ++it) {
        int flat = it * 256 + t;
        int i = flat & 15, k2 = flat >> 4;
        int s = i * RSTR + SWZ(k2);
        D[(size_t)r * NN + (k2 << 8) + (n10 + i)] = make_float2(sre[s], sim[s]);
    }
}

__global__ __launch_bounds__(256)
void xf_stage2(const float2* __restrict__ D, float2* __restrict__ XF)
{
    __shared__ float sre[16 * RSTR];
    __shared__ float sim[16 * RSTR];
    const int t = threadIdx.x;
    const int r = blockIdx.x >> 4;
    const int k20 = (blockIdx.x & 15) << 4;
#pragma unroll
    for (int it = 0; it < 16; ++it) {
        float2 v = D[(size_t)r * NN + ((size_t)(k20 + it) << 8) + t];
        sre[it * RSTR + SWZ(t)] = v.x;
        sim[it * RSTR + SWZ(t)] = v.y;
    }
    __syncthreads();
    const int g = t >> 4, u = t & 15;
    fft256_soa<-1, false, 0>(sre + g * RSTR, sim + g * RSTR, u, 0, 0.f, 1.f);
    __syncthreads();
#pragma unroll
    for (int it = 0; it < 16; ++it) {
        int flat = it * 256 + t;
        int fi = flat & 15, k1 = flat >> 4;
        int s = fi * RSTR + SWZ(k1);
        XF[(size_t)r * NN + (size_t)(k20 + fi) + ((size_t)k1 << 8)] = make_float2(sre[s], sim[s]);
    }
}

// ================= FULL first-order chain (j1 <= 2, 192 rows) =================
__global__ __launch_bounds__(256)
void fo_stage1(const float2* __restrict__ XF, __half2* __restrict__ Dh, int qbase)
{
    __shared__ float sre[16 * RSTR];
    __shared__ float sim[16 * RSTR];
    const int t = threadIdx.x;
    const int r = blockIdx.x >> 4;
    const int n10 = (blockIdx.x & 15) << 4;
    const int q = qbase + r;
    const int j1 = q >> 6, ql = q & 63;
    const int srow = ql >> 3, w = ql & 7;
    const int lam = j1 * 8 + w;
    const float xi = 0.35f * exp2f(-(float)lam * 0.125f);
    const float invsig = 8.0f / xi;
    const float kc = xi * (float)NN;
    const float Hh = 6.10f * (xi * 0.125f) * (float)NN;
#pragma unroll
    for (int it = 0; it < 16; ++it) {
        int flat = it * 256 + t;
        int i = flat & 15, n2 = flat >> 4;
        int n = (n10 + i) + (n2 << 8);
        float nsf = (float)((n < NN / 2) ? n : n - NN);
        float vr = 0.f, vi = 0.f;
        if (fabsf(nsf - kc) <= Hh) {
            float2 v = XF[(size_t)srow * NN + n];
            float a = (nsf * (1.0f / (float)NN) - xi) * invsig;
            float wg = __expf(-0.5f * a * a) * 0.0625f;
            vr = v.x * wg; vi = v.y * wg;
        }
        sre[i * RSTR + SWZ(n2)] = vr;
        sim[i * RSTR + SWZ(n2)] = vi;
    }
    __syncthreads();
    const int g = t >> 4, u = t & 15;
    fft256_soa<1, true, 0>(sre + g * RSTR, sim + g * RSTR, u, n10 + g, TWO_PI / (float)NN, 1.f);
    __syncthreads();
#pragma unroll
    for (int it = 0; it < 16; ++it) {
        int flat = it * 256 + t;
        int i = flat & 15, k2 = flat >> 4;
        int s = i * RSTR + SWZ(k2);
        Dh[(size_t)r * NN + (k2 << 8) + (n10 + i)] = __floats2half2_rn(sre[s], sim[s]);
    }
}

__global__ __launch_bounds__(256)
void fo_mid(const __half2* __restrict__ Dh, __half2* __restrict__ D2h)
{
    __shared__ float sre[16 * RSTR];
    __shared__ float sim[16 * RSTR];
    const int t = threadIdx.x;
    const int r = blockIdx.x >> 4;
    const int k20 = (blockIdx.x & 15) << 4;
#pragma unroll
    for (int it = 0; it < 16; ++it) {
        float2 v = __half22float2(Dh[(size_t)r * NN + ((size_t)(k20 + it) << 8) + t]);
        sre[it * RSTR + SWZ(t)] = v.x;
        sim[it * RSTR + SWZ(t)] = v.y;
    }
    __syncthreads();
    const int g = t >> 4, u = t & 15;
    float* rr = sre + g * RSTR; float* ri = sim + g * RSTR;
    fft256_soa<1, false, 1>(rr, ri, u, 0, 0.f, 16.0f / (float)NN);
    fft256_soa<-1, true, 0>(rr, ri, u, k20 + g, TWO_PI / (float)NN, 1.f);
    __syncthreads();
#pragma unroll
    for (int it = 0; it < 16; ++it) {
        int flat = it * 256 + t;
        int i = flat & 15, k2 = flat >> 4;
        int s = i * RSTR + SWZ(k2);
        D2h[(size_t)r * NN + (k2 << 8) + (k20 + i)] = __floats2half2_rn(sre[s], sim[s]);
    }
}

__global__ __launch_bounds__(256)
void fo_stage2(const __half2* __restrict__ D2h, __half2* __restrict__ Cw, int qbase)
{
    __shared__ float sre[16 * RSTR];
    __shared__ float sim[16 * RSTR];
    const int t = threadIdx.x;
    const int r = blockIdx.x >> 4;
    const int k20 = (blockIdx.x & 15) << 4;
    const int q = qbase + r;
    const int j1 = q >> 6, ql = q & 63;
#pragma unroll
    for (int it = 0; it < 16; ++it) {
        float2 v = __half22float2(D2h[(size_t)r * NN + ((size_t)(k20 + it) << 8) + t]);
        sre[it * RSTR + SWZ(t)] = v.x;
        sim[it * RSTR + SWZ(t)] = v.y;
    }
    __syncthreads();
    const int g = t >> 4, u = t & 15;
    fft256_soa<-1, false, 0>(sre + g * RSTR, sim + g * RSTR, u, 0, 0.f, 1.f);
    __syncthreads();
    const size_t base = COFF[j1] + (size_t)ql * CWW[j1];
    const int lo = CLO[j1], Wd = CWW[j1];
#pragma unroll
    for (int it = 0; it < 16; ++it) {
        int flat = it * 256 + t;
        int fi = flat & 15, k1 = flat >> 4;
        int k = (k20 + fi) + (k1 << 8);
        int ksg = (k < NN / 2) ? k : k - NN;
        int idx = ksg - lo;
        if (idx >= 0 && idx < Wd) {
            int s = fi * RSTR + SWZ(k1);
            Cw[base + idx] = __floats2half2_rn(sre[s], sim[s]);
        }
    }
}

// ============== S0 + S1 fold (8 + 512 blocks) ==============
__global__ __launch_bounds__(256)
void sfold_all(const float2* __restrict__ XF, const __half2* __restrict__ Cw,
               float* __restrict__ out)
{
    __shared__ float Gr[256];
    __shared__ float Gi[256];
    const int blk = blockIdx.x;
    const int t = threadIdx.x;
    const float invsigphi = 731.428571f;
    float ar = 0.f, ai = 0.f;
    if (blk < 8) {
#pragma unroll
        for (int qq = -4; qq <= 4; ++qq) {
            int ks = t + (qq << 8);
            int k = ks & (NN - 1);
            float a = ((float)ks * (1.0f / (float)NN)) * invsigphi;
            float wg = __expf(-0.5f * a * a);
            float2 v = XF[(size_t)blk * NN + k];
            ar = fmaf(v.x, wg, ar); ai = fmaf(v.y, wg, ai);
        }
    } else {
        int q = blk - 8;
        int j1 = q >> 6, ql = q & 63;
        size_t base = COFF[j1] + (size_t)ql * CWW[j1];
        int lo = CLO[j1];
#pragma unroll
        for (int qq = -4; qq <= 4; ++qq) {
            int ks = t + (qq << 8);
            float a = ((float)ks * (1.0f / (float)NN)) * invsigphi;
            float wg = __expf(-0.5f * a * a);
            float2 v = __half22float2(Cw[base + (ks - lo)]);
            ar = fmaf(v.x, wg, ar); ai = fmaf(v.y, wg, ai);
        }
    }
    Gr[t] = ar; Gi[t] = ai;
    __syncthreads();
    float sb, cb;
    __sincosf((TWO_PI / 256.0f) * (float)t, &sb, &cb);
    float wr = 1.f, wi = 0.f, s = 0.f;
    for (int kk = 0; kk < 256; ++kk) {
        s = fmaf(Gr[kk], wr, s);
        s = fmaf(-Gi[kk], wi, s);
        float nr = wr * cb - wi * sb; wi = wr * sb + wi * cb; wr = nr;
    }
    s *= (1.0f / (float)NN);
    float mag = sqrtf(fmaf(s, s, 1e-8f));
    float val = logf(mag + 1e-8f);
    int b, chan;
    if (blk < 8) { b = blk; chan = 0; }
    else { int q = blk - 8; int j1 = q >> 6, ql = q & 63; b = ql >> 3; chan = 1 + j1 * 8 + (ql & 7); }
    out[((size_t)b * 289 + chan) * 256 + t] = val;
}

// ============== FULL second order (j2 <= 3, 384 rows) ==============
__device__ __forceinline__ void so_decode_full(int q, int& j1, int& j2, int& rb)
{
    int pp = q >> 6;
    rb = q & 63;
    j2 = (pp == 0) ? 1 : ((pp < 3) ? 2 : 3);
    j1 = (pp == 0) ? 0 : ((pp < 3) ? pp - 1 : pp - 3);
}

__global__ __launch_bounds__(256)
void so_stage1(const __half2* __restrict__ Cw, __half2* __restrict__ Dh, int qbase)
{
    __shared__ float sre[16 * RSTR];
    __shared__ float sim[16 * RSTR];
    const int t = threadIdx.x;
    const int r = blockIdx.x >> 4;
    const int n10 = (blockIdx.x & 15) << 4;
    int j1, j2, rb;
    so_decode_full(qbase + r, j1, j2, rb);
    const float xi2 = 0.35f * exp2f(-(float)j2);
    const float invsig = 1.0f / (0.6f * xi2);
    const float kc = xi2 * (float)NN;
    const float Hh = 6.10f * (0.6f * xi2) * (float)NN;
    const size_t base = COFF[j1] + (size_t)rb * CWW[j1];
    const int lo = CLO[j1], Wd = CWW[j1];
#pragma unroll
    for (int it = 0; it < 16; ++it) {
        int flat = it * 256 + t;
        int i = flat & 15, n2 = flat >> 4;
        int n = (n10 + i) + (n2 << 8);
        int ksg = (n < NN / 2) ? n : n - NN;
        float nsf = (float)ksg;
        float vr = 0.f, vi = 0.f;
        int idx = ksg - lo;
        if (fabsf(nsf - kc) <= Hh && idx >= 0 && idx < Wd) {
            float2 v = __half22float2(Cw[base + idx]);
            float a = (nsf * (1.0f / (float)NN) - xi2) * invsig;
            float wg = __expf(-0.5f * a * a) * (1.0f / 256.0f);
            vr = v.x * wg; vi = v.y * wg;
        }
        sre[i * RSTR + SWZ(n2)] = vr;
        sim[i * RSTR + SWZ(n2)] = vi;
    }
    __syncthreads();
    const int g = t >> 4, u = t & 15;
    fft256_soa<1, true, 0>(sre + g * RSTR, sim + g * RSTR, u, n10 + g, TWO_PI / (float)NN, 1.f);
    __syncthreads();
#pragma unroll
    for (int it = 0; it < 16; ++it) {
        int flat = it * 256 + t;
        int i = flat & 15, k2 = flat >> 4;
        int s = i * RSTR + SWZ(k2);
        Dh[(size_t)r * NN + (k2 << 8) + (n10 + i)] = __floats2half2_rn(sre[s], sim[s]);
    }
}

__global__ __launch_bounds__(256)
void so_stage2(const __half2* __restrict__ Dh, float* __restrict__ S2acc, int qbase)
{
    __shared__ float sre[16 * RSTR];
    __shared__ float sim[16 * RSTR];
    __shared__ float wtab[16][8];
    const int t = threadIdx.x;
    const int r = blockIdx.x >> 4;
    const int k20 = (blockIdx.x & 15) << 4;
#pragma unroll
    for (int it = 0; it < 16; ++it) {
        float2 v = __half22float2(Dh[(size_t)r * NN + ((size_t)(k20 + it) << 8) + t]);
        sre[it * RSTR + SWZ(t)] = v.x;
        sim[it * RSTR + SWZ(t)] = v.y;
    }
    if (t < 128) {
        int fi = t >> 3, dd = (t & 7) - 4;
        int w = k20 + fi + (dd << 8) + 768;
        float val = 0.f;
        if (w >= 0 && w <= 1536) {
            float m = (float)(w - 768);
            val = 0.003426963f * __expf(-3.690276e-5f * m * m);
        }
        wtab[fi][t & 7] = val;
    }
    __syncthreads();
    const int g = t >> 4, u = t & 15;
    fft256_soa<1, false, 1>(sre + g * RSTR, sim + g * RSTR, u, 0, 0.f, 1.f);
    __syncthreads();
    float acc = 0.f;
#pragma unroll
    for (int fi = 0; fi < 16; ++fi) {
        const float* row = sre + fi * RSTR;
#pragma unroll
        for (int dd = 0; dd < 8; ++dd) {
            int k1 = (t + dd - 4) & 255;
            acc = fmaf(row[SWZ(k1)], wtab[fi][dd], acc);
        }
    }
    atomicAdd(&S2acc[(size_t)(qbase + r) * 256 + t], acc * (1.0f / 256.0f));
}

// ============== decimated M=16384 (s=4, L=64) ==============
// stage 1: fold-load + 64-pt column DIT + twiddle -> Dh16 (fp16, scale 1/64)
template<int MODE>   // 1 = fo (XF*psi1, j1=3,4), 2 = so (Cw*psi2, j2=4,5)
__global__ __launch_bounds__(256)
void dec16_s1(const float2* __restrict__ XF, const __half2* __restrict__ Cw,
              __half2* __restrict__ Dh16, int qbase)
{
    __shared__ float sre[64 * 64];
    __shared__ float sim[64 * 64];
    const int t = threadIdx.x;
    const int r = blockIdx.x >> 2;
    const int c0 = (blockIdx.x & 3) << 6;
    const int q = qbase + r;
    float xi, invsig, kc, Hh; int srow = 0; size_t cbase = 0; int lo = 0, Wd = 0;
    if (MODE == 1) {
        int j1 = 3 + (q >> 6); int ql = q & 63; srow = ql >> 3;
        int lam = j1 * 8 + (ql & 7);
        xi = 0.35f * exp2f(-(float)lam * 0.125f);
        invsig = 8.0f / xi; kc = xi * (float)NN; Hh = 6.10f * (xi * 0.125f) * (float)NN;
    } else {
        int pp = q >> 6, rb = q & 63;
        int j2 = (pp < 4) ? 4 : 5; int j1 = (pp < 4) ? pp : pp - 4;
        xi = 0.35f * exp2f(-(float)j2);
        invsig = 1.0f / (0.6f * xi); kc = xi * (float)NN; Hh = 6.10f * (0.6f * xi) * (float)NN;
        cbase = COFF[j1] + (size_t)rb * CWW[j1]; lo = CLO[j1]; Wd = CWW[j1];
    }
    const int klo = (int)ceilf(kc - Hh);
#pragma unroll
    for (int it = 0; it < 16; ++it) {
        int flat = it * 256 + t;
        int c = flat & 63, n2 = flat >> 6;
        int kap = (c0 + c) + (n2 << 8);
        int kk = klo + (int)(((unsigned)(kap - klo)) & 16383u);
        float vr = 0.f, vi = 0.f;
        if (fabsf((float)kk - kc) <= Hh) {
            float2 v;
            if (MODE == 1) v = XF[(size_t)srow * NN + (kk & (NN - 1))];
            else {
                int idx = kk - lo;
                v = (idx >= 0 && idx < Wd) ? __half22float2(Cw[cbase + idx])
                                           : make_float2(0.f, 0.f);
            }
            float a = ((float)kk * (1.0f / (float)NN) - xi) * invsig;
            float wg = __expf(-0.5f * a * a) * 0.015625f;
            vr = v.x * wg; vi = v.y * wg;
        }
        int p = rev64(n2);
        sre[(p << 6) + c] = vr;
        sim[(p << 6) + c] = vi;
    }
    lds_dit<64, 6, 64, 1, false>(sre, sim, t, 256);
#pragma unroll
    for (int it = 0; it < 16; ++it) {
        int flat = it * 256 + t;
        int c = flat & 63, row = flat >> 6;
        int a = (row << 6) + c;
        float ang = (TWO_PI / 16384.0f) * (float)(row * (c0 + c));
        float sj, cj; __sincosf(ang, &sj, &cj);
        float rr = sre[a] * cj - sim[a] * sj;
        sim[a] = sre[a] * sj + sim[a] * cj; sre[a] = rr;
    }
    __syncthreads();
#pragma unroll
    for (int it = 0; it < 16; ++it) {
        int flat = it * 256 + t;
        int c = flat & 63, row = flat >> 6;
        Dh16[(size_t)r * 16384 + (row << 8) + (c0 + c)] =
            __floats2half2_rn(sre[(row << 6) + c], sim[(row << 6) + c]);
    }
}

// so stage 2: row ifft + modulus + Gaussian conv partial -> atomic S2acc
__global__ __launch_bounds__(256)
void dec16_s2so(const __half2* __restrict__ Dh16, float* __restrict__ S2acc, int qbase)
{
    __shared__ float sre[16 * RSTR];
    __shared__ float sim[16 * RSTR];
    __shared__ float wtab[16][6];
    const int t = threadIdx.x;
    const int r = blockIdx.x >> 2;
    const int k2base = (blockIdx.x & 3) << 4;
#pragma unroll
    for (int it = 0; it < 16; ++it) {
        float2 v = __half22float2(Dh16[(size_t)r * 16384 + ((k2base + it) << 8) + t]);
        sre[it * RSTR + SWZ(t)] = v.x;
        sim[it * RSTR + SWZ(t)] = v.y;
    }
    if (t < 96) {
        int p = t / 6, dl = t % 6;
        float w = (float)(256 * (dl - 2) - 4 * (k2base + p));
        wtab[p][dl] = 0.003426963f * __expf(-3.690276e-5f * w * w);
    }
    __syncthreads();
    const int g = t >> 4, u = t & 15;
    fft256_soa<1, false, 1>(sre + g * RSTR, sim + g * RSTR, u, 0, 0.f, 64.0f / (float)NN);
    __syncthreads();
    float acc = 0.f;
#pragma unroll
    for (int p = 0; p < 16; ++p) {
        const float* row = sre + p * RSTR;
#pragma unroll
        for (int dl = 0; dl < 6; ++dl) {
            int k1 = (t - (dl - 2)) & 255;
            acc = fmaf(row[SWZ(k1)], wtab[p][dl], acc);
        }
    }
    atomicAdd(&S2acc[(size_t)(384 + qbase + r) * 256 + t], acc * 4.0f);
}

// fo stage 2: row ifft + modulus + fwd row fft (M-twiddle) -> D2h16
__global__ __launch_bounds__(256)
void dec16_s2fo(const __half2* __restrict__ Dh16, __half2* __restrict__ D2h16)
{
    __shared__ float sre[16 * RSTR];
    __shared__ float sim[16 * RSTR];
    const int t = threadIdx.x;
    const int r = blockIdx.x >> 2;
    const int k2base = (blockIdx.x & 3) << 4;
#pragma unroll
    for (int it = 0; it < 16; ++it) {
        float2 v = __half22float2(Dh16[(size_t)r * 16384 + ((k2base + it) << 8) + t]);
        sre[it * RSTR + SWZ(t)] = v.x;
        sim[it * RSTR + SWZ(t)] = v.y;
    }
    __syncthreads();
    const int g = t >> 4, u = t & 15;
    float* rr = sre + g * RSTR; float* ri = sim + g * RSTR;
    fft256_soa<1, false, 1>(rr, ri, u, 0, 0.f, 256.0f / (float)NN);   // u = 4*U1
    fft256_soa<-1, true, 0>(rr, ri, u, k2base + g, TWO_PI / 16384.0f, 1.f);
    __syncthreads();
#pragma unroll
    for (int it = 0; it < 16; ++it) {
        int a = it * RSTR + SWZ(t);
        D2h16[(size_t)r * 16384 + ((k2base + it) << 8) + t] = __floats2half2_rn(sre[a], sim[a]);
    }
}

// fo stage 3: 64-pt column DIF + windowed store
__global__ __launch_bounds__(256)
void dec16_s3fo(const __half2* __restrict__ D2h16, __half2* __restrict__ Cw, int qbase)
{
    __shared__ float sre[64 * 64];
    __shared__ float sim[64 * 64];
    const int t = threadIdx.x;
    const int r = blockIdx.x >> 2;
    const int c0 = (blockIdx.x & 3) << 6;
    const int q = qbase + r;
    const int j1 = 3 + (q >> 6), ql = q & 63;
#pragma unroll
    for (int it = 0; it < 16; ++it) {
        int flat = it * 256 + t;
        int c = flat & 63, m2 = flat >> 6;
        float2 v = __half22float2(D2h16[(size_t)r * 16384 + (m2 << 8) + (c0 + c)]);
        sre[(m2 << 6) + c] = v.x;
        sim[(m2 << 6) + c] = v.y;
    }
    lds_dif<64, 6, 64, -1, false>(sre, sim, t, 256);
    const int lo = CLO[j1], Wd = CWW[j1];
    const size_t rbase = COFF[j1] + (size_t)ql * Wd;
#pragma unroll
    for (int it = 0; it < 16; ++it) {
        int flat = it * 256 + t;
        int c = flat & 63, p = flat >> 6;
        int kap = (c0 + c) + (rev64(p) << 8);
        int ks = (kap < 8192) ? kap : kap - 16384;
        int idx = ks - lo;
        if (idx >= 0 && idx < Wd) {
            int a = (p << 6) + c;
            Cw[rbase + idx] = __floats2half2_rn(sre[a], sim[a]);
        }
    }
}

// ============== decimated M=4096 (s=16, L=16) — single-kernel ==============
__global__ __launch_bounds__(256)
void m4k_fo(const float2* __restrict__ XF, __half2* __restrict__ Cw)
{
    __shared__ float sre[16 * RSTR];
    __shared__ float sim[16 * RSTR];
    const int t = threadIdx.x;
    const int q = blockIdx.x;
    const int j1 = 5 + (q >> 6), ql = q & 63;
    const int srow = ql >> 3;
    const int lam = j1 * 8 + (ql & 7);
    const float xi = 0.35f * exp2f(-(float)lam * 0.125f);
    const float invsig = 8.0f / xi;
    const float kc = xi * (float)NN;
    const float Hh = 6.10f * (xi * 0.125f) * (float)NN;
    const int klo = (int)ceilf(kc - Hh);
#pragma unroll
    for (int it = 0; it < 16; ++it) {
        int kap = t + (it << 8);
        int kk = klo + (int)(((unsigned)(kap - klo)) & 4095u);
        float vr = 0.f, vi = 0.f;
        if (fabsf((float)kk - kc) <= Hh) {
            float2 v = XF[(size_t)srow * NN + (kk & (NN - 1))];
            float a = ((float)kk * (1.0f / (float)NN) - xi) * invsig;
            float wg = __expf(-0.5f * a * a);
            vr = v.x * wg; vi = v.y * wg;
        }
        int p = rev16(it);
        sre[p * RSTR + SWZ(t)] = vr;
        sim[p * RSTR + SWZ(t)] = vi;
    }
    lds_dit<16, 8, RSTR, 1, true>(sre, sim, t, 256);
#pragma unroll
    for (int it = 0; it < 16; ++it) {
        int a = it * RSTR + SWZ(t);
        float ang = (TWO_PI / 4096.0f) * (float)(it * t);
        float sj, cj; __sincosf(ang, &sj, &cj);
        float rr = sre[a] * cj - sim[a] * sj;
        sim[a] = sre[a] * sj + sim[a] * cj; sre[a] = rr;
    }
    __syncthreads();
    const int g = t >> 4, u = t & 15;
    float* rr = sre + g * RSTR; float* ri = sim + g * RSTR;
    fft256_soa<1, false, 1>(rr, ri, u, 0, 0.f, 16.0f / (float)NN);   // u = 16*U1
    fft256_soa<-1, true, 0>(rr, ri, u, g, TWO_PI / 4096.0f, 1.f);
    lds_dif<16, 8, RSTR, -1, true>(sre, sim, t, 256);
    const int lo = CLO[j1], Wd = CWW[j1];
    const size_t rbase = COFF[j1] + (size_t)ql * Wd;
#pragma unroll
    for (int it = 0; it < 16; ++it) {
        int kap = t + (rev16(it) << 8);
        int ks = (kap < 2048) ? kap : kap - 4096;
        int idx = ks - lo;
        if (idx >= 0 && idx < Wd) {
            int a = it * RSTR + SWZ(t);
            Cw[rbase + idx] = __floats2half2_rn(sre[a], sim[a]);
        }
    }
}

__global__ __launch_bounds__(256)
void m4k_so(const __half2* __restrict__ Cw, float* __restrict__ out)
{
    __shared__ float sre[16 * RSTR];
    __shared__ float sim[16 * RSTR];
    __shared__ float wtab[16][6];
    const int t = threadIdx.x;
    const int q = blockIdx.x;
    const int pp = q >> 6, rb = q & 63;
    const int j2 = (pp < 6) ? 6 : 7;
    const int j1 = (pp < 6) ? pp : pp - 6;
    const float xi2 = 0.35f * exp2f(-(float)j2);
    const float invsig = 1.0f / (0.6f * xi2);
    const float kc = xi2 * (float)NN;
    const float Hh = 6.10f * (0.6f * xi2) * (float)NN;
    const int klo = (int)ceilf(kc - Hh);
    const size_t cbase = COFF[j1] + (size_t)rb * CWW[j1];
    const int lo = CLO[j1], Wd = CWW[j1];
#pragma unroll
    for (int it = 0; it < 16; ++it) {
        int kap = t + (it << 8);
        int kk = klo + (int)(((unsigned)(kap - klo)) & 4095u);
        float vr = 0.f, vi = 0.f;
        int idx = kk - lo;
        if (fabsf((float)kk - kc) <= Hh && idx >= 0 && idx < Wd) {
            float2 v = __half22float2(Cw[cbase + idx]);
            float a = ((float)kk * (1.0f / (float)NN) - xi2) * invsig;
            float wg = __expf(-0.5f * a * a);
            vr = v.x * wg; vi = v.y * wg;
        }
        int p = rev16(it);
        sre[p * RSTR + SWZ(t)] = vr;
        sim[p * RSTR + SWZ(t)] = vi;
    }
    if (t < 96) {
        int p = t / 6, dl = t % 6;
        float w = (float)(256 * (dl - 2) - 16 * p);
        wtab[p][dl] = 0.003426963f * __expf(-3.690276e-5f * w * w);
    }
    lds_dit<16, 8, RSTR, 1, true>(sre, sim, t, 256);
#pragma unroll
    for (int it = 0; it < 16; ++it) {
        int a = it * RSTR + SWZ(t);
        float ang = (TWO_PI / 4096.0f) * (float)(it * t);
        float sj, cj; __sincosf(ang, &sj, &cj);
        float rr = sre[a] * cj - sim[a] * sj;
        sim[a] = sre[a] * sj + sim[a] * cj; sre[a] = rr;
    }
    __syncthreads();
    const int g = t >> 4, u = t & 15;
    fft256_soa<1, false, 1>(sre + g * RSTR, sim + g * RSTR, u, 0, 0.f, 1.0f / (float)NN);
    __syncthreads();
    float acc = 0.f;
#pragma unroll
    for (int p = 0; p < 16; ++p) {
        const float* row = sre + p * RSTR;
#pragma unroll
        for (int dl = 0; dl < 6; ++dl) {
            int k1 = (t - (dl - 2)) & 255;
            acc = fmaf(row[SWZ(k1)], wtab[p][dl], acc);
        }
    }
    acc *= 16.0f;
    const int b = rb >> 3;
    const int chan = 65 + 4 * j2 * (j2 - 1) + j1 * 8 + (rb & 7);
    float mag = sqrtf(fmaf(acc, acc, 1e-8f));
    out[((size_t)b * 289 + chan) * 256 + t] = logf(mag + 1e-8f);
}

__global__ __launch_bounds__(256)
void s2final(const float* __restrict__ S2acc, float* __restrict__ out)
{
    const int q = blockIdx.x, n = threadIdx.x;
    int j1, j2, rb;
    if (q < 384) {
        so_decode_full(q, j1, j2, rb);
    } else {
        int qq = q - 384;
        int pp = qq >> 6; rb = qq & 63;
        j2 = (pp < 4) ? 4 : 5; j1 = (pp < 4) ? pp : pp - 4;
    }
    const int b = rb >> 3;
    const int chan = 65 + 4 * j2 * (j2 - 1) + j1 * 8 + (rb & 7);
    float s = S2acc[(size_t)q * 256 + n];
    float mag = sqrtf(fmaf(s, s, 1e-8f));
    out[((size_t)b * 289 + chan) * 256 + n] = logf(mag + 1e-8f);
}

__global__ void zero_kernel(float* p, int nElem)
{
    int i = blockIdx.x * 256 + threadIdx.x;
    if (i < nElem) p[i] = 0.f;
}

extern "C" void kernel_launch(void* const* d_in, const int* in_sizes, int n_in,
                              void* d_out, int out_size, void* d_ws, size_t ws_size,
                              hipStream_t stream)
{
    const float* x = (const float*)d_in[0];
    float* out = (float*)d_out;
    char* ws = (char*)d_ws;

    size_t off = 0;
    float2*  XF    = (float2*)ws;                 off += 8ul * NN * 8;
    __half2* Cw    = (__half2*)(ws + off);        off += CTOT * 4ul;
    float*   S2acc = (float*)(ws + off);          off += 960ul * 256 * 4;
    off = (off + 255) & ~255ul;
    char* reg0 = ws + off;
    size_t avail = (ws_size > off) ? (ws_size - off) : 0;

    int CHB = (int)(avail / (512ul * 1024));  if (CHB > 192) CHB = 192;  if (CHB < 1) CHB = 1;
    int CHD = (int)(avail / (256ul * 1024));  if (CHD > 384) CHD = 384;  if (CHD < 1) CHD = 1;
    int CHE = (int)(avail / (128ul * 1024));  if (CHE > 128) CHE = 128;  if (CHE < 1) CHE = 1;
    int CHF = (int)(avail / (64ul * 1024));   if (CHF > 576) CHF = 576;  if (CHF < 1) CHF = 1;

    {
        int nz = 8 * 289 * 256;
        zero_kernel<<<(nz + 255) / 256, 256, 0, stream>>>(out + nz, nz);
        int na = 960 * 256;
        zero_kernel<<<(na + 255) / 256, 256, 0, stream>>>(S2acc, na);
    }

    // XF = fft(x)
    {
        float2* Df = (float2*)reg0;
        xf_stage1<<<8 * 16, 256, 0, stream>>>(x, Df);
        xf_stage2<<<8 * 16, 256, 0, stream>>>(Df, XF);
    }

    // first order FULL (j1 = 0..2)
    for (int cs = 0; cs < 192; cs += CHB) {
        int m = (192 - cs < CHB) ? (192 - cs) : CHB;
        __half2* DhB = (__half2*)reg0;
        __half2* D2h = DhB + (size_t)CHB * NN;
        fo_stage1<<<m * 16, 256, 0, stream>>>(XF, DhB, cs);
        fo_mid<<<m * 16, 256, 0, stream>>>(DhB, D2h);
        fo_stage2<<<m * 16, 256, 0, stream>>>(D2h, Cw, cs);
    }
    // first order M=16384 (j1 = 3,4)
    for (int cs = 0; cs < 128; cs += CHE) {
        int m = (128 - cs < CHE) ? (128 - cs) : CHE;
        __half2* Dh16  = (__half2*)reg0;
        __half2* D2h16 = Dh16 + (size_t)CHE * 16384;
        dec16_s1<1><<<m * 4, 256, 0, stream>>>(XF, Cw, Dh16, cs);
        dec16_s2fo<<<m * 4, 256, 0, stream>>>(Dh16, D2h16);
        dec16_s3fo<<<m * 4, 256, 0, stream>>>(D2h16, Cw, cs);
    }
    // first order M=4096 (j1 = 5..7), no scratch
    m4k_fo<<<192, 256, 0, stream>>>(XF, Cw);

    // S0 + S1
    sfold_all<<<8 + 512, 256, 0, stream>>>(XF, Cw, out);

    // second order FULL (j2 <= 3)
    for (int qs = 0; qs < 384; qs += CHD) {
        int m = (384 - qs < CHD) ? (384 - qs) : CHD;
        __half2* DhS = (__half2*)reg0;
        so_stage1<<<m * 16, 256, 0, stream>>>(Cw, DhS, qs);
        so_stage2<<<m * 16, 256, 0, stream>>>(DhS, S2acc, qs);
    }
    // second order M=16384 (j2 = 4,5)
    for (int qs = 0; qs < 576; qs += CHF) {
        int m = (576 - qs < CHF) ? (576 - qs) : CHF;
        __half2* Dh16 = (__half2*)reg0;
        dec16_s1<2><<<m * 4, 256, 0, stream>>>(XF, Cw, Dh16, qs);
        dec16_s2so<<<m * 4, 256, 0, stream>>>(Dh16, S2acc, qs);
    }
    // second order M=4096 (j2 = 6,7), direct output
    m4k_so<<<832, 256, 0, stream>>>(Cw, out);

    s2final<<<960, 256, 0, stream>>>(S2acc, out);
}

// Round 6
// 384.588 us; speedup vs baseline: 7.3474x; 1.0287x over previous
//
#include <hip/hip_runtime.h>
#include <hip/hip_fp16.h>
#include <math.h>

#define NN 65536
#define TWO_PI 6.283185307179586f
#define RSTR 264   // LDS row stride in floats
#define SWZ(m) ((m) ^ (((m) >> 4) & 15))
// per-row column swizzle: kills the 4-way conflict of i-fast staging loops
#define SWZI(m, r) (SWZ(m) ^ ((r) & 12))
#define CTOT 9781248ul   // total fp16-windowed C elements

// per-octave C window: signed-bin lo, width, element offset (6.1-sigma unions)
__constant__ int CLO[8] = {-32768, -15360, -7680, -3840, -2048, -1024, -1024, -1024};
__constant__ int CWW[8] = {65536, 42240, 21248, 10752, 5632, 2816, 2304, 2304};
__constant__ unsigned long COFF[8] = {0ul, 4194304ul, 6897664ul, 8257536ul,
                                      8945664ul, 9306112ul, 9486336ul, 9633792ul};

__device__ __forceinline__ void lds_fence() {
    asm volatile("s_waitcnt lgkmcnt(0)" ::: "memory");
}
__device__ __forceinline__ int rev16(int p) { return ((p & 3) << 2) | (p >> 2); }
__device__ __forceinline__ int rev64(int p) { return ((p & 3) << 4) | (p & 12) | (p >> 4); }

// ---------------- radix-4 x radix-4 16-point FFT, natural order in/out ----------------
template<int SIGN>
__device__ __forceinline__ void fft16(float* xr, float* xi, float* yr, float* yi)
{
    const float S = (SIGN > 0) ? 1.0f : -1.0f;
    const float C8 = 0.92387953251f, S8 = 0.38268343236f, R2 = 0.70710678119f;
#pragma unroll
    for (int n0 = 0; n0 < 4; ++n0) {
        float z0r=xr[n0],    z0i=xi[n0];
        float z1r=xr[n0+4],  z1i=xi[n0+4];
        float z2r=xr[n0+8],  z2i=xi[n0+8];
        float z3r=xr[n0+12], z3i=xi[n0+12];
        float t0r=z0r+z2r, t0i=z0i+z2i;
        float t1r=z0r-z2r, t1i=z0i-z2i;
        float t2r=z1r+z3r, t2i=z1i+z3i;
        float t3r=S*(z1r-z3r), t3i=S*(z1i-z3i);
        xr[n0]=t0r+t2r;      xi[n0]=t0i+t2i;
        xr[n0+4]=t1r-t3i;    xi[n0+4]=t1i+t3r;
        xr[n0+8]=t0r-t2r;    xi[n0+8]=t0i-t2i;
        xr[n0+12]=t1r+t3i;   xi[n0+12]=t1i-t3r;
    }
    {
        const float W1r=C8,  W1i=S*S8;
        const float W2r=R2,  W2i=S*R2;
        const float W3r=S8,  W3i=S*C8;
        const float W6r=-R2, W6i=S*R2;
        const float W9r=-C8, W9i=-S*S8;
#define TWID(idx, wr, wi) { float ar=xr[idx], ai=xi[idx]; xr[idx]=ar*(wr)-ai*(wi); xi[idx]=ar*(wi)+ai*(wr); }
        TWID(5,W1r,W1i)  TWID(9,W2r,W2i)   TWID(13,W3r,W3i)
        TWID(6,W2r,W2i)  { float ar=xr[10], ai=xi[10]; xr[10]=-S*ai; xi[10]=S*ar; } TWID(14,W6r,W6i)
        TWID(7,W3r,W3i)  TWID(11,W6r,W6i)  TWID(15,W9r,W9i)
#undef TWID
    }
#pragma unroll
    for (int p = 0; p < 4; ++p) {
        float z0r=xr[4*p],   z0i=xi[4*p];
        float z1r=xr[4*p+1], z1i=xi[4*p+1];
        float z2r=xr[4*p+2], z2i=xi[4*p+2];
        float z3r=xr[4*p+3], z3i=xi[4*p+3];
        float t0r=z0r+z2r, t0i=z0i+z2i;
        float t1r=z0r-z2r, t1i=z0i-z2i;
        float t2r=z1r+z3r, t2i=z1i+z3i;
        float t3r=S*(z1r-z3r), t3i=S*(z1i-z3i);
        yr[p]=t0r+t2r;     yi[p]=t0i+t2i;
        yr[p+4]=t1r-t3i;   yi[p+4]=t1i+t3r;
        yr[p+8]=t0r-t2r;   yi[p+8]=t0i-t2i;
        yr[p+12]=t1r+t3i;  yi[p+12]=t1i-t3r;
    }
}

// ---------------- 256-pt FFT on one group's SoA LDS row (16 lanes, one wave) ----------
// OUT: 0 = complex back to LDS, 1 = |.|*mscale to re-plane.  cxor = (row & 12).
// qmask: which 64-element quarters of the row are (possibly) nonzero — dead quarters
// skip the pass-1 LDS reads (registers zero-filled; exact since slots hold 0).
template<int SIGN, bool BIGTW, int OUT>
__device__ __forceinline__ void fft256_soa(float* rr, float* ri, int u, int n1,
                                           float twrate, float mscale, int cxor, int qmask)
{
    float xr[16], xi[16], yr[16], yi[16];
#pragma unroll
    for (int qq = 0; qq < 4; ++qq) {
        if (qmask & (1 << qq)) {
#pragma unroll
            for (int j = 0; j < 4; ++j) {
                int b = qq * 4 + j;
                int s = SWZ(u + (b << 4)) ^ cxor;
                xr[b] = rr[s]; xi[b] = ri[s];
            }
        } else {
#pragma unroll
            for (int j = 0; j < 4; ++j) { xr[qq * 4 + j] = 0.f; xi[qq * 4 + j] = 0.f; }
        }
    }
    fft16<SIGN>(xr, xi, yr, yi);
    float sa, ca;
    __sincosf((float)SIGN * (TWO_PI / 256.0f) * (float)u, &sa, &ca);
    float twr = 1.f, twi = 0.f;
#pragma unroll
    for (int c = 0; c < 16; ++c) {
        int s = SWZ((c << 4) + u) ^ cxor;
        rr[s] = yr[c] * twr - yi[c] * twi;
        ri[s] = yr[c] * twi + yi[c] * twr;
        float nr = twr * ca - twi * sa; twi = twr * sa + twi * ca; twr = nr;
    }
    lds_fence();
#pragma unroll
    for (int a = 0; a < 16; ++a) {
        int s = SWZ((u << 4) + a) ^ cxor;
        xr[a] = rr[s]; xi[a] = ri[s];
    }
    fft16<SIGN>(xr, xi, yr, yi);
    float tbr = 1.f, tbi = 0.f, str = 1.f, sti = 0.f;
    if (BIGTW) {
        float s0, c0, s1, c1;
        __sincosf((float)SIGN * twrate * (float)(n1 * u), &s0, &c0);
        __sincosf((float)SIGN * twrate * (float)(n1 << 4), &s1, &c1);
        tbr = c0; tbi = s0; str = c1; sti = s1;
    }
#pragma unroll
    for (int d = 0; d < 16; ++d) {
        float vr = yr[d], vi = yi[d];
        if (BIGTW) {
            float pr = vr * tbr - vi * tbi, pi = vr * tbi + vi * tbr;
            vr = pr; vi = pi;
            float nr = tbr * str - tbi * sti; tbi = tbr * sti + tbi * str; tbr = nr;
        }
        int s = SWZ(u + (d << 4)) ^ cxor;
        if (OUT == 1) { rr[s] = sqrtf(fmaf(vr, vr, vi * vi)) * mscale; ri[s] = 0.f; }
        else { rr[s] = vr; ri[s] = vi; }
    }
    lds_fence();
}

// ---------- generic LDS radix-4 passes over the row axis (L rows, NC cols) ----------
template<int L, int CLOG, int RST, int SIGN, bool SWZC>
__device__ __forceinline__ void lds_dit(float* re, float* im, int t, int T)
{
    const int NC = 1 << CLOG;
    const int nbf = NC * (L >> 2);
    for (int h = 1; h < L; h <<= 2) {
        __syncthreads();
        for (int i = t; i < nbf; i += T) {
            int c = i & (NC - 1);
            int bf = i >> CLOG;
            int j = bf & (h - 1);
            int q0 = ((bf - j) << 2) + j;
            int r0 = q0, r1 = q0 + h, r2 = q0 + 2 * h, r3 = q0 + 3 * h;
            int a0, a1, a2, a3;
            if (SWZC) {
                a0 = r0 * RST + SWZI(c, r0); a1 = r1 * RST + SWZI(c, r1);
                a2 = r2 * RST + SWZI(c, r2); a3 = r3 * RST + SWZI(c, r3);
            } else {
                a0 = r0 * RST + c; a1 = r1 * RST + c; a2 = r2 * RST + c; a3 = r3 * RST + c;
            }
            float x0r = re[a0], x0i = im[a0];
            float x1r = re[a1], x1i = im[a1];
            float x2r = re[a2], x2i = im[a2];
            float x3r = re[a3], x3i = im[a3];
            if (h > 1) {
                float ang = (float)SIGN * (TWO_PI / (float)(4 * h)) * (float)j;
                float sj, cj; __sincosf(ang, &sj, &cj);
                float c2 = cj * cj - sj * sj, s2 = 2.f * cj * sj;
                float c3 = c2 * cj - s2 * sj, s3 = c2 * sj + s2 * cj;
                float r;
                r = x1r * cj - x1i * sj; x1i = x1r * sj + x1i * cj; x1r = r;
                r = x2r * c2 - x2i * s2; x2i = x2r * s2 + x2i * c2; x2r = r;
                r = x3r * c3 - x3i * s3; x3i = x3r * s3 + x3i * c3; x3r = r;
            }
            float t0r = x0r + x2r, t0i = x0i + x2i;
            float t1r = x0r - x2r, t1i = x0i - x2i;
            float t2r = x1r + x3r, t2i = x1i + x3i;
            float t3r = -(float)SIGN * (x1i - x3i), t3i = (float)SIGN * (x1r - x3r);
            re[a0] = t0r + t2r; im[a0] = t0i + t2i;
            re[a1] = t1r + t3r; im[a1] = t1i + t3i;
            re[a2] = t0r - t2r; im[a2] = t0i - t2i;
            re[a3] = t1r - t3r; im[a3] = t1i - t3i;
        }
    }
    __syncthreads();
}

template<int L, int CLOG, int RST, int SIGN, bool SWZC>
__device__ __forceinline__ void lds_dif(float* re, float* im, int t, int T)
{
    const int NC = 1 << CLOG;
    const int nbf = NC * (L >> 2);
    for (int h = L >> 2; h >= 1; h >>= 2) {
        __syncthreads();
        for (int i = t; i < nbf; i += T) {
            int c = i & (NC - 1);
            int bf = i >> CLOG;
            int j = bf & (h - 1);
            int q0 = ((bf - j) << 2) + j;
            int r0 = q0, r1 = q0 + h, r2 = q0 + 2 * h, r3 = q0 + 3 * h;
            int a0, a1, a2, a3;
            if (SWZC) {
                a0 = r0 * RST + SWZI(c, r0); a1 = r1 * RST + SWZI(c, r1);
                a2 = r2 * RST + SWZI(c, r2); a3 = r3 * RST + SWZI(c, r3);
            } else {
                a0 = r0 * RST + c; a1 = r1 * RST + c; a2 = r2 * RST + c; a3 = r3 * RST + c;
            }
            float x0r = re[a0], x0i = im[a0];
            float x1r = re[a1], x1i = im[a1];
            float x2r = re[a2], x2i = im[a2];
            float x3r = re[a3], x3i = im[a3];
            float t0r = x0r + x2r, t0i = x0i + x2i;
            float t1r = x0r - x2r, t1i = x0i - x2i;
            float t2r = x1r + x3r, t2i = x1i + x3i;
            float t3r = -(float)SIGN * (x1i - x3i), t3i = (float)SIGN * (x1r - x3r);
            float y1r = t1r + t3r, y1i = t1i + t3i;
            float y2r = t0r - t2r, y2i = t0i - t2i;
            float y3r = t1r - t3r, y3i = t1i - t3i;
            re[a0] = t0r + t2r; im[a0] = t0i + t2i;
            if (h > 1) {
                float ang = (float)SIGN * (TWO_PI / (float)(4 * h)) * (float)j;
                float sj, cj; __sincosf(ang, &sj, &cj);
                float c2 = cj * cj - sj * sj, s2 = 2.f * cj * sj;
                float c3 = c2 * cj - s2 * sj, s3 = c2 * sj + s2 * cj;
                re[a1] = y1r * cj - y1i * sj; im[a1] = y1r * sj + y1i * cj;
                re[a2] = y2r * c2 - y2i * s2; im[a2] = y2r * s2 + y2i * c2;
                re[a3] = y3r * c3 - y3i * s3; im[a3] = y3r * s3 + y3i * c3;
            } else {
                re[a1] = y1r; im[a1] = y1i;
                re[a2] = y2r; im[a2] = y2i;
                re[a3] = y3r; im[a3] = y3i;
            }
        }
    }
    __syncthreads();
}

// ================= XF chain (fp32, 8 rows) =================
__global__ __launch_bounds__(256)
void xf_stage1(const float* __restrict__ x, float2* __restrict__ D)
{
    __shared__ float sre[16 * RSTR];
    __shared__ float sim[16 * RSTR];
    const int t = threadIdx.x;
    const int r = blockIdx.x >> 4;
    const int n10 = (blockIdx.x & 15) << 4;
#pragma unroll
    for (int it = 0; it < 16; ++it) {
        int flat = it * 256 + t;
        int i = flat & 15, n2 = flat >> 4;
        int n = (n10 + i) + (n2 << 8);
        sre[i * RSTR + SWZI(n2, i)] = x[(size_t)r * NN + n];
        sim[i * RSTR + SWZI(n2, i)] = 0.f;
    }
    __syncthreads();
    const int g = t >> 4, u = t & 15;
    fft256_soa<-1, true, 0>(sre + g * RSTR, sim + g * RSTR, u, n10 + g,
                            TWO_PI / (float)NN, 1.f, g & 12, 15);
    __syncthreads();
#pragma unroll
    for (int it = 0; it < 16; ++it) {
        int flat = it * 256 + t;
        int i = flat & 15, k2 = flat >> 4;
        int s = i * RSTR + SWZI(k2, i);
        D[(size_t)r * NN + (k2 << 8) + (n10 + i)] = make_float2(sre[s], sim[s]);
    }
}

__global__ __launch_bounds__(256)
void xf_stage2(const float2* __restrict__ D, float2* __restrict__ XF)
{
    __shared__ float sre[16 * RSTR];
    __shared__ float sim[16 * RSTR];
    const int t = threadIdx.x;
    const int r = blockIdx.x >> 4;
    const int k20 = (blockIdx.x & 15) << 4;
#pragma unroll
    for (int it = 0; it < 16; ++it) {
        float2 v = D[(size_t)r * NN + ((size_t)(k20 + it) << 8) + t];
        sre[it * RSTR + SWZI(t, it)] = v.x;
        sim[it * RSTR + SWZI(t, it)] = v.y;
    }
    __syncthreads();
    const int g = t >> 4, u = t & 15;
    fft256_soa<-1, false, 0>(sre + g * RSTR, sim + g * RSTR, u, 0, 0.f, 1.f, g & 12, 15);
    __syncthreads();
#pragma unroll
    for (int it = 0; it < 16; ++it) {
        int flat = it * 256 + t;
        int fi = flat & 15, k1 = flat >> 4;
        int s = fi * RSTR + SWZI(k1, fi);
        XF[(size_t)r * NN + (size_t)(k20 + fi) + ((size_t)k1 << 8)] = make_float2(sre[s], sim[s]);
    }
}

// ================= FULL first-order chain (j1 <= 2, 192 rows) =================
__global__ __launch_bounds__(256)
void fo_stage1(const float2* __restrict__ XF, __half2* __restrict__ Dh, int qbase)
{
    __shared__ float sre[16 * RSTR];
    __shared__ float sim[16 * RSTR];
    const int t = threadIdx.x;
    const int r = blockIdx.x >> 4;
    const int n10 = (blockIdx.x & 15) << 4;
    const int q = qbase + r;
    const int j1 = q >> 6, ql = q & 63;
    const int srow = ql >> 3, w = ql & 7;
    const int lam = j1 * 8 + w;
    const float xi = 0.35f * exp2f(-(float)lam * 0.125f);
    const float invsig = 8.0f / xi;
    const float kc = xi * (float)NN;
    const float Hh = 6.10f * (xi * 0.125f) * (float)NN;
    const int klo = (int)(kc - Hh), khi = (int)(kc + Hh) + 1;
    int qm = 0;
    if (klo < 0 || khi >= NN) qm = 15;
    else {
#pragma unroll
        for (int qq = 0; qq < 4; ++qq)
            if (16384 * qq + 16896 >= klo && 16384 * qq - 512 <= khi) qm |= (1 << qq);
    }
#pragma unroll
    for (int it = 0; it < 16; ++it) {
        int flat = it * 256 + t;
        int i = flat & 15, n2 = flat >> 4;
        int n = (n10 + i) + (n2 << 8);
        float nsf = (float)((n < NN / 2) ? n : n - NN);
        float vr = 0.f, vi = 0.f;
        if (fabsf(nsf - kc) <= Hh) {
            float2 v = XF[(size_t)srow * NN + n];
            float a = (nsf * (1.0f / (float)NN) - xi) * invsig;
            float wg = __expf(-0.5f * a * a) * 0.0625f;
            vr = v.x * wg; vi = v.y * wg;
        }
        sre[i * RSTR + SWZI(n2, i)] = vr;
        sim[i * RSTR + SWZI(n2, i)] = vi;
    }
    __syncthreads();
    const int g = t >> 4, u = t & 15;
    fft256_soa<1, true, 0>(sre + g * RSTR, sim + g * RSTR, u, n10 + g,
                           TWO_PI / (float)NN, 1.f, g & 12, qm);
    __syncthreads();
#pragma unroll
    for (int it = 0; it < 16; ++it) {
        int flat = it * 256 + t;
        int i = flat & 15, k2 = flat >> 4;
        int s = i * RSTR + SWZI(k2, i);
        Dh[(size_t)r * NN + (k2 << 8) + (n10 + i)] = __floats2half2_rn(sre[s], sim[s]);
    }
}

__global__ __launch_bounds__(256)
void fo_mid(const __half2* __restrict__ Dh, __half2* __restrict__ D2h)
{
    __shared__ float sre[16 * RSTR];
    __shared__ float sim[16 * RSTR];
    const int t = threadIdx.x;
    const int r = blockIdx.x >> 4;
    const int k20 = (blockIdx.x & 15) << 4;
#pragma unroll
    for (int it = 0; it < 16; ++it) {
        float2 v = __half22float2(Dh[(size_t)r * NN + ((size_t)(k20 + it) << 8) + t]);
        sre[it * RSTR + SWZI(t, it)] = v.x;
        sim[it * RSTR + SWZI(t, it)] = v.y;
    }
    __syncthreads();
    const int g = t >> 4, u = t & 15;
    float* rr = sre + g * RSTR; float* ri = sim + g * RSTR;
    fft256_soa<1, false, 1>(rr, ri, u, 0, 0.f, 16.0f / (float)NN, g & 12, 15);
    fft256_soa<-1, true, 0>(rr, ri, u, k20 + g, TWO_PI / (float)NN, 1.f, g & 12, 15);
    __syncthreads();
#pragma unroll
    for (int it = 0; it < 16; ++it) {
        int flat = it * 256 + t;
        int i = flat & 15, k2 = flat >> 4;
        int s = i * RSTR + SWZI(k2, i);
        D2h[(size_t)r * NN + (k2 << 8) + (k20 + i)] = __floats2half2_rn(sre[s], sim[s]);
    }
}

__global__ __launch_bounds__(256)
void fo_stage2(const __half2* __restrict__ D2h, __half2* __restrict__ Cw, int qbase)
{
    __shared__ float sre[16 * RSTR];
    __shared__ float sim[16 * RSTR];
    const int t = threadIdx.x;
    const int r = blockIdx.x >> 4;
    const int k20 = (blockIdx.x & 15) << 4;
    const int q = qbase + r;
    const int j1 = q >> 6, ql = q & 63;
#pragma unroll
    for (int it = 0; it < 16; ++it) {
        float2 v = __half22float2(D2h[(size_t)r * NN + ((size_t)(k20 + it) << 8) + t]);
        sre[it * RSTR + SWZI(t, it)] = v.x;
        sim[it * RSTR + SWZI(t, it)] = v.y;
    }
    __syncthreads();
    const int g = t >> 4, u = t & 15;
    fft256_soa<-1, false, 0>(sre + g * RSTR, sim + g * RSTR, u, 0, 0.f, 1.f, g & 12, 15);
    __syncthreads();
    const size_t base = COFF[j1] + (size_t)ql * CWW[j1];
    const int lo = CLO[j1], Wd = CWW[j1];
#pragma unroll
    for (int it = 0; it < 16; ++it) {
        int flat = it * 256 + t;
        int fi = flat & 15, k1 = flat >> 4;
        int k = (k20 + fi) + (k1 << 8);
        int ksg = (k < NN / 2) ? k : k - NN;
        int idx = ksg - lo;
        if (idx >= 0 && idx < Wd) {
            int s = fi * RSTR + SWZI(k1, fi);
            Cw[base + idx] = __floats2half2_rn(sre[s], sim[s]);
        }
    }
}

// ============== S0 + S1 fold (8 + 512 blocks) ==============
__global__ __launch_bounds__(256)
void sfold_all(const float2* __restrict__ XF, const __half2* __restrict__ Cw,
               float* __restrict__ out)
{
    __shared__ float Gr[256];
    __shared__ float Gi[256];
    const int blk = blockIdx.x;
    const int t = threadIdx.x;
    const float invsigphi = 731.428571f;
    float ar = 0.f, ai = 0.f;
    if (blk < 8) {
#pragma unroll
        for (int qq = -4; qq <= 4; ++qq) {
            int ks = t + (qq << 8);
            int k = ks & (NN - 1);
            float a = ((float)ks * (1.0f / (float)NN)) * invsigphi;
            float wg = __expf(-0.5f * a * a);
            float2 v = XF[(size_t)blk * NN + k];
            ar = fmaf(v.x, wg, ar); ai = fmaf(v.y, wg, ai);
        }
    } else {
        int q = blk - 8;
        int j1 = q >> 6, ql = q & 63;
        size_t base = COFF[j1] + (size_t)ql * CWW[j1];
        int lo = CLO[j1];
#pragma unroll
        for (int qq = -4; qq <= 4; ++qq) {
            int ks = t + (qq << 8);
            float a = ((float)ks * (1.0f / (float)NN)) * invsigphi;
            float wg = __expf(-0.5f * a * a);
            float2 v = __half22float2(Cw[base + (ks - lo)]);
            ar = fmaf(v.x, wg, ar); ai = fmaf(v.y, wg, ai);
        }
    }
    Gr[t] = ar; Gi[t] = ai;
    __syncthreads();
    float sb, cb;
    __sincosf((TWO_PI / 256.0f) * (float)t, &sb, &cb);
    float wr = 1.f, wi = 0.f, s = 0.f;
    for (int kk = 0; kk < 256; ++kk) {
        s = fmaf(Gr[kk], wr, s);
        s = fmaf(-Gi[kk], wi, s);
        float nr = wr * cb - wi * sb; wi = wr * sb + wi * cb; wr = nr;
    }
    s *= (1.0f / (float)NN);
    float mag = sqrtf(fmaf(s, s, 1e-8f));
    float val = logf(mag + 1e-8f);
    int b, chan;
    if (blk < 8) { b = blk; chan = 0; }
    else { int q = blk - 8; int j1 = q >> 6, ql = q & 63; b = ql >> 3; chan = 1 + j1 * 8 + (ql & 7); }
    out[((size_t)b * 289 + chan) * 256 + t] = val;
}

// ============== FULL second order (j2 <= 3, 384 rows) ==============
__device__ __forceinline__ void so_decode_full(int q, int& j1, int& j2, int& rb)
{
    int pp = q >> 6;
    rb = q & 63;
    j2 = (pp == 0) ? 1 : ((pp < 3) ? 2 : 3);
    j1 = (pp == 0) ? 0 : ((pp < 3) ? pp - 1 : pp - 3);
}

__global__ __launch_bounds__(256)
void so_stage1(const __half2* __restrict__ Cw, __half2* __restrict__ Dh, int qbase)
{
    __shared__ float sre[16 * RSTR];
    __shared__ float sim[16 * RSTR];
    const int t = threadIdx.x;
    const int r = blockIdx.x >> 4;
    const int n10 = (blockIdx.x & 15) << 4;
    int j1, j2, rb;
    so_decode_full(qbase + r, j1, j2, rb);
    const float xi2 = 0.35f * exp2f(-(float)j2);
    const float invsig = 1.0f / (0.6f * xi2);
    const float kc = xi2 * (float)NN;
    const float Hh = 6.10f * (0.6f * xi2) * (float)NN;
    const size_t base = COFF[j1] + (size_t)rb * CWW[j1];
    const int lo = CLO[j1], Wd = CWW[j1];
#pragma unroll
    for (int it = 0; it < 16; ++it) {
        int flat = it * 256 + t;
        int i = flat & 15, n2 = flat >> 4;
        int n = (n10 + i) + (n2 << 8);
        int ksg = (n < NN / 2) ? n : n - NN;
        float nsf = (float)ksg;
        float vr = 0.f, vi = 0.f;
        int idx = ksg - lo;
        if (fabsf(nsf - kc) <= Hh && idx >= 0 && idx < Wd) {
            float2 v = __half22float2(Cw[base + idx]);
            float a = (nsf * (1.0f / (float)NN) - xi2) * invsig;
            float wg = __expf(-0.5f * a * a) * (1.0f / 256.0f);
            vr = v.x * wg; vi = v.y * wg;
        }
        sre[i * RSTR + SWZI(n2, i)] = vr;
        sim[i * RSTR + SWZI(n2, i)] = vi;
    }
    __syncthreads();
    const int g = t >> 4, u = t & 15;
    fft256_soa<1, true, 0>(sre + g * RSTR, sim + g * RSTR, u, n10 + g,
                           TWO_PI / (float)NN, 1.f, g & 12, 15);
    __syncthreads();
#pragma unroll
    for (int it = 0; it < 16; ++it) {
        int flat = it * 256 + t;
        int i = flat & 15, k2 = flat >> 4;
        int s = i * RSTR + SWZI(k2, i);
        Dh[(size_t)r * NN + (k2 << 8) + (n10 + i)] = __floats2half2_rn(sre[s], sim[s]);
    }
}

__global__ __launch_bounds__(256)
void so_stage2(const __half2* __restrict__ Dh, float* __restrict__ S2acc, int qbase)
{
    __shared__ float sre[16 * RSTR];
    __shared__ float sim[16 * RSTR];
    __shared__ float wtab[16][8];
    const int t = threadIdx.x;
    const int r = blockIdx.x >> 4;
    const int k20 = (blockIdx.x & 15) << 4;
#pragma unroll
    for (int it = 0; it < 16; ++it) {
        float2 v = __half22float2(Dh[(size_t)r * NN + ((size_t)(k20 + it) << 8) + t]);
        sre[it * RSTR + SWZI(t, it)] = v.x;
        sim[it * RSTR + SWZI(t, it)] = v.y;
    }
    if (t < 128) {
        int fi = t >> 3, dd = (t & 7) - 4;
        int w = k20 + fi + (dd << 8) + 768;
        float val = 0.f;
        if (w >= 0 && w <= 1536) {
            float m = (float)(w - 768);
            val = 0.003426963f * __expf(-3.690276e-5f * m * m);
        }
        wtab[fi][t & 7] = val;
    }
    __syncthreads();
    const int g = t >> 4, u = t & 15;
    fft256_soa<1, false, 1>(sre + g * RSTR, sim + g * RSTR, u, 0, 0.f, 1.f, g & 12, 15);
    __syncthreads();
    float acc = 0.f;
#pragma unroll
    for (int fi = 0; fi < 16; ++fi) {
        const float* row = sre + fi * RSTR;
#pragma unroll
        for (int dd = 0; dd < 8; ++dd) {
            int k1 = (t + dd - 4) & 255;
            acc = fmaf(row[SWZI(k1, fi)], wtab[fi][dd], acc);
        }
    }
    atomicAdd(&S2acc[(size_t)(qbase + r) * 256 + t], acc * (1.0f / 256.0f));
}

// ============== decimated M=16384 (s=4, L=64) ==============
template<int MODE>   // 1 = fo (XF*psi1, j1=3,4), 2 = so (Cw*psi2, j2=4,5)
__global__ __launch_bounds__(256)
void dec16_s1(const float2* __restrict__ XF, const __half2* __restrict__ Cw,
              __half2* __restrict__ Dh16, int qbase)
{
    __shared__ float sre[64 * 64];
    __shared__ float sim[64 * 64];
    const int t = threadIdx.x;
    const int r = blockIdx.x >> 2;
    const int c0 = (blockIdx.x & 3) << 6;
    const int q = qbase + r;
    float xi, invsig, kc, Hh; int srow = 0; size_t cbase = 0; int lo = 0, Wd = 0;
    if (MODE == 1) {
        int j1 = 3 + (q >> 6); int ql = q & 63; srow = ql >> 3;
        int lam = j1 * 8 + (ql & 7);
        xi = 0.35f * exp2f(-(float)lam * 0.125f);
        invsig = 8.0f / xi; kc = xi * (float)NN; Hh = 6.10f * (xi * 0.125f) * (float)NN;
    } else {
        int pp = q >> 6, rb = q & 63;
        int j2 = (pp < 4) ? 4 : 5; int j1 = (pp < 4) ? pp : pp - 4;
        xi = 0.35f * exp2f(-(float)j2);
        invsig = 1.0f / (0.6f * xi); kc = xi * (float)NN; Hh = 6.10f * (0.6f * xi) * (float)NN;
        cbase = COFF[j1] + (size_t)rb * CWW[j1]; lo = CLO[j1]; Wd = CWW[j1];
    }
    const int klo = (int)ceilf(kc - Hh);
#pragma unroll
    for (int it = 0; it < 16; ++it) {
        int flat = it * 256 + t;
        int c = flat & 63, n2 = flat >> 6;
        int kap = (c0 + c) + (n2 << 8);
        int kk = klo + (int)(((unsigned)(kap - klo)) & 16383u);
        float vr = 0.f, vi = 0.f;
        if (fabsf((float)kk - kc) <= Hh) {
            float2 v;
            if (MODE == 1) v = XF[(size_t)srow * NN + (kk & (NN - 1))];
            else {
                int idx = kk - lo;
                v = (idx >= 0 && idx < Wd) ? __half22float2(Cw[cbase + idx])
                                           : make_float2(0.f, 0.f);
            }
            float a = ((float)kk * (1.0f / (float)NN) - xi) * invsig;
            float wg = __expf(-0.5f * a * a) * 0.015625f;
            vr = v.x * wg; vi = v.y * wg;
        }
        int p = rev64(n2);
        sre[(p << 6) + c] = vr;
        sim[(p << 6) + c] = vi;
    }
    lds_dit<64, 6, 64, 1, false>(sre, sim, t, 256);
#pragma unroll
    for (int it = 0; it < 16; ++it) {
        int flat = it * 256 + t;
        int c = flat & 63, row = flat >> 6;
        int a = (row << 6) + c;
        float ang = (TWO_PI / 16384.0f) * (float)(row * (c0 + c));
        float sj, cj; __sincosf(ang, &sj, &cj);
        float rr = sre[a] * cj - sim[a] * sj;
        sim[a] = sre[a] * sj + sim[a] * cj; sre[a] = rr;
    }
    __syncthreads();
#pragma unroll
    for (int it = 0; it < 16; ++it) {
        int flat = it * 256 + t;
        int c = flat & 63, row = flat >> 6;
        Dh16[(size_t)r * 16384 + (row << 8) + (c0 + c)] =
            __floats2half2_rn(sre[(row << 6) + c], sim[(row << 6) + c]);
    }
}

__global__ __launch_bounds__(256)
void dec16_s2so(const __half2* __restrict__ Dh16, float* __restrict__ S2acc, int qbase)
{
    __shared__ float sre[16 * RSTR];
    __shared__ float sim[16 * RSTR];
    __shared__ float wtab[16][6];
    const int t = threadIdx.x;
    const int r = blockIdx.x >> 2;
    const int k2base = (blockIdx.x & 3) << 4;
#pragma unroll
    for (int it = 0; it < 16; ++it) {
        float2 v = __half22float2(Dh16[(size_t)r * 16384 + ((k2base + it) << 8) + t]);
        sre[it * RSTR + SWZI(t, it)] = v.x;
        sim[it * RSTR + SWZI(t, it)] = v.y;
    }
    if (t < 96) {
        int p = t / 6, dl = t % 6;
        float w = (float)(256 * (dl - 2) - 4 * (k2base + p));
        wtab[p][dl] = 0.003426963f * __expf(-3.690276e-5f * w * w);
    }
    __syncthreads();
    const int g = t >> 4, u = t & 15;
    fft256_soa<1, false, 1>(sre + g * RSTR, sim + g * RSTR, u, 0, 0.f,
                            64.0f / (float)NN, g & 12, 15);
    __syncthreads();
    float acc = 0.f;
#pragma unroll
    for (int p = 0; p < 16; ++p) {
        const float* row = sre + p * RSTR;
#pragma unroll
        for (int dl = 0; dl < 6; ++dl) {
            int k1 = (t - (dl - 2)) & 255;
            acc = fmaf(row[SWZI(k1, p)], wtab[p][dl], acc);
        }
    }
    atomicAdd(&S2acc[(size_t)(384 + qbase + r) * 256 + t], acc * 4.0f);
}

__global__ __launch_bounds__(256)
void dec16_s2fo(const __half2* __restrict__ Dh16, __half2* __restrict__ D2h16)
{
    __shared__ float sre[16 * RSTR];
    __shared__ float sim[16 * RSTR];
    const int t = threadIdx.x;
    const int r = blockIdx.x >> 2;
    const int k2base = (blockIdx.x & 3) << 4;
#pragma unroll
    for (int it = 0; it < 16; ++it) {
        float2 v = __half22float2(Dh16[(size_t)r * 16384 + ((k2base + it) << 8) + t]);
        sre[it * RSTR + SWZI(t, it)] = v.x;
        sim[it * RSTR + SWZI(t, it)] = v.y;
    }
    __syncthreads();
    const int g = t >> 4, u = t & 15;
    float* rr = sre + g * RSTR; float* ri = sim + g * RSTR;
    fft256_soa<1, false, 1>(rr, ri, u, 0, 0.f, 256.0f / (float)NN, g & 12, 15);
    fft256_soa<-1, true, 0>(rr, ri, u, k2base + g, TWO_PI / 16384.0f, 1.f, g & 12, 15);
    __syncthreads();
#pragma unroll
    for (int it = 0; it < 16; ++it) {
        int a = it * RSTR + SWZI(t, it);
        D2h16[(size_t)r * 16384 + ((k2base + it) << 8) + t] = __floats2half2_rn(sre[a], sim[a]);
    }
}

__global__ __launch_bounds__(256)
void dec16_s3fo(const __half2* __restrict__ D2h16, __half2* __restrict__ Cw, int qbase)
{
    __shared__ float sre[64 * 64];
    __shared__ float sim[64 * 64];
    const int t = threadIdx.x;
    const int r = blockIdx.x >> 2;
    const int c0 = (blockIdx.x & 3) << 6;
    const int q = qbase + r;
    const int j1 = 3 + (q >> 6), ql = q & 63;
#pragma unroll
    for (int it = 0; it < 16; ++it) {
        int flat = it * 256 + t;
        int c = flat & 63, m2 = flat >> 6;
        float2 v = __half22float2(D2h16[(size_t)r * 16384 + (m2 << 8) + (c0 + c)]);
        sre[(m2 << 6) + c] = v.x;
        sim[(m2 << 6) + c] = v.y;
    }
    lds_dif<64, 6, 64, -1, false>(sre, sim, t, 256);
    const int lo = CLO[j1], Wd = CWW[j1];
    const size_t rbase = COFF[j1] + (size_t)ql * Wd;
#pragma unroll
    for (int it = 0; it < 16; ++it) {
        int flat = it * 256 + t;
        int c = flat & 63, p = flat >> 6;
        int kap = (c0 + c) + (rev64(p) << 8);
        int ks = (kap < 8192) ? kap : kap - 16384;
        int idx = ks - lo;
        if (idx >= 0 && idx < Wd) {
            int a = (p << 6) + c;
            Cw[rbase + idx] = __floats2half2_rn(sre[a], sim[a]);
        }
    }
}

// ============== decimated M=4096 (s=16, L=16) — single-kernel ==============
__global__ __launch_bounds__(256)
void m4k_fo(const float2* __restrict__ XF, __half2* __restrict__ Cw)
{
    __shared__ float sre[16 * RSTR];
    __shared__ float sim[16 * RSTR];
    const int t = threadIdx.x;
    const int q = blockIdx.x;
    const int j1 = 5 + (q >> 6), ql = q & 63;
    const int srow = ql >> 3;
    const int lam = j1 * 8 + (ql & 7);
    const float xi = 0.35f * exp2f(-(float)lam * 0.125f);
    const float invsig = 8.0f / xi;
    const float kc = xi * (float)NN;
    const float Hh = 6.10f * (xi * 0.125f) * (float)NN;
    const int klo = (int)ceilf(kc - Hh);
#pragma unroll
    for (int it = 0; it < 16; ++it) {
        int kap = t + (it << 8);
        int kk = klo + (int)(((unsigned)(kap - klo)) & 4095u);
        float vr = 0.f, vi = 0.f;
        if (fabsf((float)kk - kc) <= Hh) {
            float2 v = XF[(size_t)srow * NN + (kk & (NN - 1))];
            float a = ((float)kk * (1.0f / (float)NN) - xi) * invsig;
            float wg = __expf(-0.5f * a * a);
            vr = v.x * wg; vi = v.y * wg;
        }
        int p = rev16(it);
        sre[p * RSTR + SWZI(t, p)] = vr;
        sim[p * RSTR + SWZI(t, p)] = vi;
    }
    lds_dit<16, 8, RSTR, 1, true>(sre, sim, t, 256);
#pragma unroll
    for (int it = 0; it < 16; ++it) {
        int a = it * RSTR + SWZI(t, it);
        float ang = (TWO_PI / 4096.0f) * (float)(it * t);
        float sj, cj; __sincosf(ang, &sj, &cj);
        float rr = sre[a] * cj - sim[a] * sj;
        sim[a] = sre[a] * sj + sim[a] * cj; sre[a] = rr;
    }
    __syncthreads();
    const int g = t >> 4, u = t & 15;
    float* rr = sre + g * RSTR; float* ri = sim + g * RSTR;
    fft256_soa<1, false, 1>(rr, ri, u, 0, 0.f, 16.0f / (float)NN, g & 12, 15);
    fft256_soa<-1, true, 0>(rr, ri, u, g, TWO_PI / 4096.0f, 1.f, g & 12, 15);
    lds_dif<16, 8, RSTR, -1, true>(sre, sim, t, 256);
    const int lo = CLO[j1], Wd = CWW[j1];
    const size_t rbase = COFF[j1] + (size_t)ql * Wd;
#pragma unroll
    for (int it = 0; it < 16; ++it) {
        int kap = t + (rev16(it) << 8);
        int ks = (kap < 2048) ? kap : kap - 4096;
        int idx = ks - lo;
        if (idx >= 0 && idx < Wd) {
            int a = it * RSTR + SWZI(t, it);
            Cw[rbase + idx] = __floats2half2_rn(sre[a], sim[a]);
        }
    }
}

__global__ __launch_bounds__(256)
void m4k_so(const __half2* __restrict__ Cw, float* __restrict__ out)
{
    __shared__ float sre[16 * RSTR];
    __shared__ float sim[16 * RSTR];
    __shared__ float wtab[16][6];
    const int t = threadIdx.x;
    const int q = blockIdx.x;
    const int pp = q >> 6, rb = q & 63;
    const int j2 = (pp < 6) ? 6 : 7;
    const int j1 = (pp < 6) ? pp : pp - 6;
    const float xi2 = 0.35f * exp2f(-(float)j2);
    const float invsig = 1.0f / (0.6f * xi2);
    const float kc = xi2 * (float)NN;
    const float Hh = 6.10f * (0.6f * xi2) * (float)NN;
    const int klo = (int)ceilf(kc - Hh);
    const size_t cbase = COFF[j1] + (size_t)rb * CWW[j1];
    const int lo = CLO[j1], Wd = CWW[j1];
#pragma unroll
    for (int it = 0; it < 16; ++it) {
        int kap = t + (it << 8);
        int kk = klo + (int)(((unsigned)(kap - klo)) & 4095u);
        float vr = 0.f, vi = 0.f;
        int idx = kk - lo;
        if (fabsf((float)kk - kc) <= Hh && idx >= 0 && idx < Wd) {
            float2 v = __half22float2(Cw[cbase + idx]);
            float a = ((float)kk * (1.0f / (float)NN) - xi2) * invsig;
            float wg = __expf(-0.5f * a * a);
            vr = v.x * wg; vi = v.y * wg;
        }
        int p = rev16(it);
        sre[p * RSTR + SWZI(t, p)] = vr;
        sim[p * RSTR + SWZI(t, p)] = vi;
    }
    if (t < 96) {
        int p = t / 6, dl = t % 6;
        float w = (float)(256 * (dl - 2) - 16 * p);
        wtab[p][dl] = 0.003426963f * __expf(-3.690276e-5f * w * w);
    }
    lds_dit<16, 8, RSTR, 1, true>(sre, sim, t, 256);
#pragma unroll
    for (int it = 0; it < 16; ++it) {
        int a = it * RSTR + SWZI(t, it);
        float ang = (TWO_PI / 4096.0f) * (float)(it * t);
        float sj, cj; __sincosf(ang, &sj, &cj);
        float rr = sre[a] * cj - sim[a] * sj;
        sim[a] = sre[a] * sj + sim[a] * cj; sre[a] = rr;
    }
    __syncthreads();
    const int g = t >> 4, u = t & 15;
    fft256_soa<1, false, 1>(sre + g * RSTR, sim + g * RSTR, u, 0, 0.f,
                            1.0f / (float)NN, g & 12, 15);
    __syncthreads();
    float acc = 0.f;
#pragma unroll
    for (int p = 0; p < 16; ++p) {
        const float* row = sre + p * RSTR;
#pragma unroll
        for (int dl = 0; dl < 6; ++dl) {
            int k1 = (t - (dl - 2)) & 255;
            acc = fmaf(row[SWZI(k1, p)], wtab[p][dl], acc);
        }
    }
    acc *= 16.0f;
    const int b = rb >> 3;
    const int chan = 65 + 4 * j2 * (j2 - 1) + j1 * 8 + (rb & 7);
    float mag = sqrtf(fmaf(acc, acc, 1e-8f));
    out[((size_t)b * 289 + chan) * 256 + t] = logf(mag + 1e-8f);
}

__global__ __launch_bounds__(256)
void s2final(const float* __restrict__ S2acc, float* __restrict__ out)
{
    const int q = blockIdx.x, n = threadIdx.x;
    int j1, j2, rb;
    if (q < 384) {
        so_decode_full(q, j1, j2, rb);
    } else {
        int qq = q - 384;
        int pp = qq >> 6; rb = qq & 63;
        j2 = (pp < 4) ? 4 : 5; j1 = (pp < 4) ? pp : pp - 4;
    }
    const int b = rb >> 3;
    const int chan = 65 + 4 * j2 * (j2 - 1) + j1 * 8 + (rb & 7);
    float s = S2acc[(size_t)q * 256 + n];
    float mag = sqrtf(fmaf(s, s, 1e-8f));
    out[((size_t)b * 289 + chan) * 256 + n] = logf(mag + 1e-8f);
}

__global__ void zero_kernel(float* p, int nElem)
{
    int i = blockIdx.x * 256 + threadIdx.x;
    if (i < nElem) p[i] = 0.f;
}

extern "C" void kernel_launch(void* const* d_in, const int* in_sizes, int n_in,
                              void* d_out, int out_size, void* d_ws, size_t ws_size,
                              hipStream_t stream)
{
    const float* x = (const float*)d_in[0];
    float* out = (float*)d_out;
    char* ws = (char*)d_ws;

    size_t off = 0;
    float2*  XF    = (float2*)ws;                 off += 8ul * NN * 8;
    __half2* Cw    = (__half2*)(ws + off);        off += CTOT * 4ul;
    float*   S2acc = (float*)(ws + off);          off += 960ul * 256 * 4;
    off = (off + 255) & ~255ul;
    char* reg0 = ws + off;
    size_t avail = (ws_size > off) ? (ws_size - off) : 0;

    int CHB = (int)(avail / (512ul * 1024));  if (CHB > 192) CHB = 192;  if (CHB < 1) CHB = 1;
    int CHD = (int)(avail / (256ul * 1024));  if (CHD > 384) CHD = 384;  if (CHD < 1) CHD = 1;
    int CHE = (int)(avail / (128ul * 1024));  if (CHE > 128) CHE = 128;  if (CHE < 1) CHE = 1;
    int CHF = (int)(avail / (64ul * 1024));   if (CHF > 576) CHF = 576;  if (CHF < 1) CHF = 1;

    {
        int nz = 8 * 289 * 256;
        zero_kernel<<<(nz + 255) / 256, 256, 0, stream>>>(out + nz, nz);
        int na = 960 * 256;
        zero_kernel<<<(na + 255) / 256, 256, 0, stream>>>(S2acc, na);
    }

    // XF = fft(x)
    {
        float2* Df = (float2*)reg0;
        xf_stage1<<<8 * 16, 256, 0, stream>>>(x, Df);
        xf_stage2<<<8 * 16, 256, 0, stream>>>(Df, XF);
    }

    // first order FULL (j1 = 0..2)
    for (int cs = 0; cs < 192; cs += CHB) {
        int m = (192 - cs < CHB) ? (192 - cs) : CHB;
        __half2* DhB = (__half2*)reg0;
        __half2* D2h = DhB + (size_t)CHB * NN;
        fo_stage1<<<m * 16, 256, 0, stream>>>(XF, DhB, cs);
        fo_mid<<<m * 16, 256, 0, stream>>>(DhB, D2h);
        fo_stage2<<<m * 16, 256, 0, stream>>>(D2h, Cw, cs);
    }
    // first order M=16384 (j1 = 3,4)
    for (int cs = 0; cs < 128; cs += CHE) {
        int m = (128 - cs < CHE) ? (128 - cs) : CHE;
        __half2* Dh16  = (__half2*)reg0;
        __half2* D2h16 = Dh16 + (size_t)CHE * 16384;
        dec16_s1<1><<<m * 4, 256, 0, stream>>>(XF, Cw, Dh16, cs);
        dec16_s2fo<<<m * 4, 256, 0, stream>>>(Dh16, D2h16);
        dec16_s3fo<<<m * 4, 256, 0, stream>>>(D2h16, Cw, cs);
    }
    // first order M=4096 (j1 = 5..7)
    m4k_fo<<<192, 256, 0, stream>>>(XF, Cw);

    // S0 + S1
    sfold_all<<<8 + 512, 256, 0, stream>>>(XF, Cw, out);

    // second order FULL (j2 <= 3)
    for (int qs = 0; qs < 384; qs += CHD) {
        int m = (384 - qs < CHD) ? (384 - qs) : CHD;
        __half2* DhS = (__half2*)reg0;
        so_stage1<<<m * 16, 256, 0, stream>>>(Cw, DhS, qs);
        so_stage2<<<m * 16, 256, 0, stream>>>(DhS, S2acc, qs);
    }
    // second order M=16384 (j2 = 4,5)
    for (int qs = 0; qs < 576; qs += CHF) {
        int m = (576 - qs < CHF) ? (576 - qs) : CHF;
        __half2* Dh16 = (__half2*)reg0;
        dec16_s1<2><<<m * 4, 256, 0, stream>>>(XF, Cw, Dh16, qs);
        dec16_s2so<<<m * 4, 256, 0, stream>>>(Dh16, S2acc, qs);
    }
    // second order M=4096 (j2 = 6,7)
    m4k_so<<<832, 256, 0, stream>>>(Cw, out);

    s2final<<<960, 256, 0, stream>>>(S2acc, out);
}

// Round 7
// 312.809 us; speedup vs baseline: 9.0334x; 1.2295x over previous
//
#include <hip/hip_runtime.h>
#include <hip/hip_fp16.h>
#include <math.h>

#define NN 65536
#define TWO_PI 6.283185307179586f
#define RSTR 264   // LDS row stride in floats
#define SWZ(m) ((m) ^ (((m) >> 4) & 15))
#define SWZI(m, r) (SWZ(m) ^ ((r) & 12))
#define CTOT 10829824ul   // total fp16 C elements (full j1=0,1; ring j1>=2)

// per-octave C storage: signed-bin lo, width, offset. j1>=2 are M-rings (mask index).
__constant__ int CLO[8]  = {-32768, -15360, -5376, -8192, -8192, -2048, -2048, -2048};
__constant__ int CWW[8]  = {65536, 42240, 16384, 16384, 16384, 4096, 4096, 4096};
__constant__ int CRING[8] = {0, 0, 1, 1, 1, 1, 1, 1};
__constant__ unsigned long COFF[8] = {0ul, 4194304ul, 6897664ul, 7946240ul,
                                      8994816ul, 10043392ul, 10305536ul, 10567680ul};

__device__ __forceinline__ void lds_fence() {
    asm volatile("s_waitcnt lgkmcnt(0)" ::: "memory");
}
__device__ __forceinline__ int rev16(int p) { return ((p & 3) << 2) | (p >> 2); }
__device__ __forceinline__ int rev64(int p) { return ((p & 3) << 4) | (p & 12) | (p >> 4); }

// ---------------- radix-4 x radix-4 16-point FFT, natural order ----------------
template<int SIGN>
__device__ __forceinline__ void fft16(float* xr, float* xi, float* yr, float* yi)
{
    const float S = (SIGN > 0) ? 1.0f : -1.0f;
    const float C8 = 0.92387953251f, S8 = 0.38268343236f, R2 = 0.70710678119f;
#pragma unroll
    for (int n0 = 0; n0 < 4; ++n0) {
        float z0r=xr[n0],    z0i=xi[n0];
        float z1r=xr[n0+4],  z1i=xi[n0+4];
        float z2r=xr[n0+8],  z2i=xi[n0+8];
        float z3r=xr[n0+12], z3i=xi[n0+12];
        float t0r=z0r+z2r, t0i=z0i+z2i;
        float t1r=z0r-z2r, t1i=z0i-z2i;
        float t2r=z1r+z3r, t2i=z1i+z3i;
        float t3r=S*(z1r-z3r), t3i=S*(z1i-z3i);
        xr[n0]=t0r+t2r;      xi[n0]=t0i+t2i;
        xr[n0+4]=t1r-t3i;    xi[n0+4]=t1i+t3r;
        xr[n0+8]=t0r-t2r;    xi[n0+8]=t0i-t2i;
        xr[n0+12]=t1r+t3i;   xi[n0+12]=t1i-t3r;
    }
    {
        const float W1r=C8,  W1i=S*S8;
        const float W2r=R2,  W2i=S*R2;
        const float W3r=S8,  W3i=S*C8;
        const float W6r=-R2, W6i=S*R2;
        const float W9r=-C8, W9i=-S*S8;
#define TWID(idx, wr, wi) { float ar=xr[idx], ai=xi[idx]; xr[idx]=ar*(wr)-ai*(wi); xi[idx]=ar*(wi)+ai*(wr); }
        TWID(5,W1r,W1i)  TWID(9,W2r,W2i)   TWID(13,W3r,W3i)
        TWID(6,W2r,W2i)  { float ar=xr[10], ai=xi[10]; xr[10]=-S*ai; xi[10]=S*ar; } TWID(14,W6r,W6i)
        TWID(7,W3r,W3i)  TWID(11,W6r,W6i)  TWID(15,W9r,W9i)
#undef TWID
    }
#pragma unroll
    for (int p = 0; p < 4; ++p) {
        float z0r=xr[4*p],   z0i=xi[4*p];
        float z1r=xr[4*p+1], z1i=xi[4*p+1];
        float z2r=xr[4*p+2], z2i=xi[4*p+2];
        float z3r=xr[4*p+3], z3i=xi[4*p+3];
        float t0r=z0r+z2r, t0i=z0i+z2i;
        float t1r=z0r-z2r, t1i=z0i-z2i;
        float t2r=z1r+z3r, t2i=z1i+z3i;
        float t3r=S*(z1r-z3r), t3i=S*(z1i-z3i);
        yr[p]=t0r+t2r;     yi[p]=t0i+t2i;
        yr[p+4]=t1r-t3i;   yi[p+4]=t1i+t3r;
        yr[p+8]=t0r-t2r;   yi[p+8]=t0i-t2i;
        yr[p+12]=t1r+t3i;  yi[p+12]=t1i-t3r;
    }
}

// ------- 256-pt FFT on one group's SoA LDS row (16 lanes, one wave) -------
// OUT 0: complex to rr/ri (SWZ). OUT 1: |.|*mscale to rr (SWZ), ri untouched.
// OUT 2: |.|*mscale to ri LINEAR with halo pads (for the conv phase).
// INREAL: pass-1 reads rr only (imag = 0).
template<int SIGN, bool BIGTW, int OUT, bool INREAL, int PADL, int PADR>
__device__ __forceinline__ void fft256_soa(float* rr, float* ri, int u, int n1,
                                           float twrate, float mscale, int cxor, int qmask)
{
    float xr[16], xi[16], yr[16], yi[16];
#pragma unroll
    for (int qq = 0; qq < 4; ++qq) {
        if (qmask & (1 << qq)) {
#pragma unroll
            for (int j = 0; j < 4; ++j) {
                int b = qq * 4 + j;
                int s = SWZ(u + (b << 4)) ^ cxor;
                xr[b] = rr[s];
                xi[b] = INREAL ? 0.f : ri[s];
            }
        } else {
#pragma unroll
            for (int j = 0; j < 4; ++j) { xr[qq * 4 + j] = 0.f; xi[qq * 4 + j] = 0.f; }
        }
    }
    fft16<SIGN>(xr, xi, yr, yi);
    float sa, ca;
    __sincosf((float)SIGN * (TWO_PI / 256.0f) * (float)u, &sa, &ca);
    float twr = 1.f, twi = 0.f;
#pragma unroll
    for (int c = 0; c < 16; ++c) {
        int s = SWZ((c << 4) + u) ^ cxor;
        rr[s] = yr[c] * twr - yi[c] * twi;
        ri[s] = yr[c] * twi + yi[c] * twr;
        float nr = twr * ca - twi * sa; twi = twr * sa + twi * ca; twr = nr;
    }
    lds_fence();
#pragma unroll
    for (int a = 0; a < 16; ++a) {
        int s = SWZ((u << 4) + a) ^ cxor;
        xr[a] = rr[s]; xi[a] = ri[s];
    }
    fft16<SIGN>(xr, xi, yr, yi);
    float tbr = 1.f, tbi = 0.f, str = 1.f, sti = 0.f;
    if (BIGTW) {
        float s0, c0, s1, c1;
        __sincosf((float)SIGN * twrate * (float)(n1 * u), &s0, &c0);
        __sincosf((float)SIGN * twrate * (float)(n1 << 4), &s1, &c1);
        tbr = c0; tbi = s0; str = c1; sti = s1;
    }
#pragma unroll
    for (int d = 0; d < 16; ++d) {
        float vr = yr[d], vi = yi[d];
        if (BIGTW) {
            float pr = vr * tbr - vi * tbi, pi = vr * tbi + vi * tbr;
            vr = pr; vi = pi;
            float nr = tbr * str - tbi * sti; tbi = tbr * sti + tbi * str; tbr = nr;
        }
        int k = u + (d << 4);
        if (OUT == 1) {
            rr[SWZ(k) ^ cxor] = sqrtf(fmaf(vr, vr, vi * vi)) * mscale;
        } else if (OUT == 2) {
            float mag = sqrtf(fmaf(vr, vr, vi * vi)) * mscale;
            ri[PADL + k] = mag;
            if (k >= 256 - PADL) ri[k - (256 - PADL)] = mag;
            if (k < PADR) ri[PADL + 256 + k] = mag;
        } else {
            int s = SWZ(k) ^ cxor;
            rr[s] = vr; ri[s] = vi;
        }
    }
    lds_fence();
}

// ---------- LDS radix-4 passes over the row axis ----------
template<int L, int CLOG, int RST, int SIGN, bool SWZC>
__device__ __forceinline__ void lds_dit(float* re, float* im, int t, int T)
{
    const int NC = 1 << CLOG;
    const int nbf = NC * (L >> 2);
    for (int h = 1; h < L; h <<= 2) {
        __syncthreads();
        for (int i = t; i < nbf; i += T) {
            int c = i & (NC - 1);
            int bf = i >> CLOG;
            int j = bf & (h - 1);
            int q0 = ((bf - j) << 2) + j;
            int r0 = q0, r1 = q0 + h, r2 = q0 + 2 * h, r3 = q0 + 3 * h;
            int a0, a1, a2, a3;
            if (SWZC) {
                a0 = r0 * RST + SWZI(c, r0); a1 = r1 * RST + SWZI(c, r1);
                a2 = r2 * RST + SWZI(c, r2); a3 = r3 * RST + SWZI(c, r3);
            } else {
                a0 = r0 * RST + c; a1 = r1 * RST + c; a2 = r2 * RST + c; a3 = r3 * RST + c;
            }
            float x0r = re[a0], x0i = im[a0];
            float x1r = re[a1], x1i = im[a1];
            float x2r = re[a2], x2i = im[a2];
            float x3r = re[a3], x3i = im[a3];
            if (h > 1) {
                float ang = (float)SIGN * (TWO_PI / (float)(4 * h)) * (float)j;
                float sj, cj; __sincosf(ang, &sj, &cj);
                float c2 = cj * cj - sj * sj, s2 = 2.f * cj * sj;
                float c3 = c2 * cj - s2 * sj, s3 = c2 * sj + s2 * cj;
                float r;
                r = x1r * cj - x1i * sj; x1i = x1r * sj + x1i * cj; x1r = r;
                r = x2r * c2 - x2i * s2; x2i = x2r * s2 + x2i * c2; x2r = r;
                r = x3r * c3 - x3i * s3; x3i = x3r * s3 + x3i * c3; x3r = r;
            }
            float t0r = x0r + x2r, t0i = x0i + x2i;
            float t1r = x0r - x2r, t1i = x0i - x2i;
            float t2r = x1r + x3r, t2i = x1i + x3i;
            float t3r = -(float)SIGN * (x1i - x3i), t3i = (float)SIGN * (x1r - x3r);
            re[a0] = t0r + t2r; im[a0] = t0i + t2i;
            re[a1] = t1r + t3r; im[a1] = t1i + t3i;
            re[a2] = t0r - t2r; im[a2] = t0i - t2i;
            re[a3] = t1r - t3r; im[a3] = t1i - t3i;
        }
    }
    __syncthreads();
}

template<int L, int CLOG, int RST, int SIGN, bool SWZC>
__device__ __forceinline__ void lds_dif(float* re, float* im, int t, int T)
{
    const int NC = 1 << CLOG;
    const int nbf = NC * (L >> 2);
    for (int h = L >> 2; h >= 1; h >>= 2) {
        __syncthreads();
        for (int i = t; i < nbf; i += T) {
            int c = i & (NC - 1);
            int bf = i >> CLOG;
            int j = bf & (h - 1);
            int q0 = ((bf - j) << 2) + j;
            int r0 = q0, r1 = q0 + h, r2 = q0 + 2 * h, r3 = q0 + 3 * h;
            int a0, a1, a2, a3;
            if (SWZC) {
                a0 = r0 * RST + SWZI(c, r0); a1 = r1 * RST + SWZI(c, r1);
                a2 = r2 * RST + SWZI(c, r2); a3 = r3 * RST + SWZI(c, r3);
            } else {
                a0 = r0 * RST + c; a1 = r1 * RST + c; a2 = r2 * RST + c; a3 = r3 * RST + c;
            }
            float x0r = re[a0], x0i = im[a0];
            float x1r = re[a1], x1i = im[a1];
            float x2r = re[a2], x2i = im[a2];
            float x3r = re[a3], x3i = im[a3];
            float t0r = x0r + x2r, t0i = x0i + x2i;
            float t1r = x0r - x2r, t1i = x0i - x2i;
            float t2r = x1r + x3r, t2i = x1i + x3i;
            float t3r = -(float)SIGN * (x1i - x3i), t3i = (float)SIGN * (x1r - x3r);
            float y1r = t1r + t3r, y1i = t1i + t3i;
            float y2r = t0r - t2r, y2i = t0i - t2i;
            float y3r = t1r - t3r, y3i = t1i - t3i;
            re[a0] = t0r + t2r; im[a0] = t0i + t2i;
            if (h > 1) {
                float ang = (float)SIGN * (TWO_PI / (float)(4 * h)) * (float)j;
                float sj, cj; __sincosf(ang, &sj, &cj);
                float c2 = cj * cj - sj * sj, s2 = 2.f * cj * sj;
                float c3 = c2 * cj - s2 * sj, s3 = c2 * sj + s2 * cj;
                re[a1] = y1r * cj - y1i * sj; im[a1] = y1r * sj + y1i * cj;
                re[a2] = y2r * c2 - y2i * s2; im[a2] = y2r * s2 + y2i * c2;
                re[a3] = y3r * c3 - y3i * s3; im[a3] = y3r * s3 + y3i * c3;
            } else {
                re[a1] = y1r; im[a1] = y1i;
                re[a2] = y2r; im[a2] = y2i;
                re[a3] = y3r; im[a3] = y3i;
            }
        }
    }
    __syncthreads();
}

// ================= XF chain (fp32, 8 rows) =================
__global__ __launch_bounds__(256)
void xf_stage1(const float* __restrict__ x, float2* __restrict__ D)
{
    __shared__ float sre[16 * RSTR];
    __shared__ float sim[16 * RSTR];
    const int t = threadIdx.x;
    const int r = blockIdx.x >> 4;
    const int n10 = (blockIdx.x & 15) << 4;
#pragma unroll
    for (int it = 0; it < 16; ++it) {
        int flat = it * 256 + t;
        int i = flat & 15, n2 = flat >> 4;
        int n = (n10 + i) + (n2 << 8);
        sre[i * RSTR + SWZI(n2, i)] = x[(size_t)r * NN + n];
        sim[i * RSTR + SWZI(n2, i)] = 0.f;
    }
    __syncthreads();
    const int g = t >> 4, u = t & 15;
    fft256_soa<-1, true, 0, false, 0, 0>(sre + g * RSTR, sim + g * RSTR, u, n10 + g,
                                         TWO_PI / (float)NN, 1.f, g & 12, 15);
    __syncthreads();
#pragma unroll
    for (int it = 0; it < 16; ++it) {
        int flat = it * 256 + t;
        int i = flat & 15, k2 = flat >> 4;
        int s = i * RSTR + SWZI(k2, i);
        D[(size_t)r * NN + (k2 << 8) + (n10 + i)] = make_float2(sre[s], sim[s]);
    }
}

__global__ __launch_bounds__(256)
void xf_stage2(const float2* __restrict__ D, float2* __restrict__ XF)
{
    __shared__ float sre[16 * RSTR];
    __shared__ float sim[16 * RSTR];
    const int t = threadIdx.x;
    const int r = blockIdx.x >> 4;
    const int k20 = (blockIdx.x & 15) << 4;
#pragma unroll
    for (int it = 0; it < 16; ++it) {
        float2 v = D[(size_t)r * NN + ((size_t)(k20 + it) << 8) + t];
        sre[it * RSTR + SWZI(t, it)] = v.x;
        sim[it * RSTR + SWZI(t, it)] = v.y;
    }
    __syncthreads();
    const int g = t >> 4, u = t & 15;
    fft256_soa<-1, false, 0, false, 0, 0>(sre + g * RSTR, sim + g * RSTR, u, 0, 0.f, 1.f, g & 12, 15);
    __syncthreads();
#pragma unroll
    for (int it = 0; it < 16; ++it) {
        int flat = it * 256 + t;
        int fi = flat & 15, k1 = flat >> 4;
        int s = fi * RSTR + SWZI(k1, fi);
        XF[(size_t)r * NN + (size_t)(k20 + fi) + ((size_t)k1 << 8)] = make_float2(sre[s], sim[s]);
    }
}

// ================= FULL first-order chain (j1 = 0,1 : 128 rows) =================
__global__ __launch_bounds__(256)
void fo_stage1(const float2* __restrict__ XF, __half2* __restrict__ Dh, int qbase)
{
    __shared__ float sre[16 * RSTR];
    __shared__ float sim[16 * RSTR];
    const int t = threadIdx.x;
    const int r = blockIdx.x >> 4;
    const int n10 = (blockIdx.x & 15) << 4;
    const int q = qbase + r;
    const int j1 = q >> 6, ql = q & 63;
    const int srow = ql >> 3, w = ql & 7;
    const int lam = j1 * 8 + w;
    const float xi = 0.35f * exp2f(-(float)lam * 0.125f);
    const float invsig = 8.0f / xi;
    const float kc = xi * (float)NN;
    const float Hh = 6.10f * (xi * 0.125f) * (float)NN;
    const int klo = (int)(kc - Hh), khi = (int)(kc + Hh) + 1;
    int qm = 0;
    if (klo < 0 || khi >= NN) qm = 15;
    else {
#pragma unroll
        for (int qq = 0; qq < 4; ++qq)
            if (16384 * qq + 16896 >= klo && 16384 * qq - 512 <= khi) qm |= (1 << qq);
    }
#pragma unroll
    for (int it = 0; it < 16; ++it) {
        int flat = it * 256 + t;
        int i = flat & 15, n2 = flat >> 4;
        int n = (n10 + i) + (n2 << 8);
        float nsf = (float)((n < NN / 2) ? n : n - NN);
        float vr = 0.f, vi = 0.f;
        if (fabsf(nsf - kc) <= Hh) {
            float2 v = XF[(size_t)srow * NN + n];
            float a = (nsf * (1.0f / (float)NN) - xi) * invsig;
            float wg = __expf(-0.5f * a * a) * 0.0625f;
            vr = v.x * wg; vi = v.y * wg;
        }
        sre[i * RSTR + SWZI(n2, i)] = vr;
        sim[i * RSTR + SWZI(n2, i)] = vi;
    }
    __syncthreads();
    const int g = t >> 4, u = t & 15;
    fft256_soa<1, true, 0, false, 0, 0>(sre + g * RSTR, sim + g * RSTR, u, n10 + g,
                                        TWO_PI / (float)NN, 1.f, g & 12, qm);
    __syncthreads();
#pragma unroll
    for (int it = 0; it < 16; ++it) {
        int flat = it * 256 + t;
        int i = flat & 15, k2 = flat >> 4;
        int s = i * RSTR + SWZI(k2, i);
        Dh[(size_t)r * NN + (k2 << 8) + (n10 + i)] = __floats2half2_rn(sre[s], sim[s]);
    }
}

__global__ __launch_bounds__(256)
void fo_mid(const __half2* __restrict__ Dh, __half2* __restrict__ D2h)
{
    __shared__ float sre[16 * RSTR];
    __shared__ float sim[16 * RSTR];
    const int t = threadIdx.x;
    const int r = blockIdx.x >> 4;
    const int k20 = (blockIdx.x & 15) << 4;
#pragma unroll
    for (int it = 0; it < 16; ++it) {
        float2 v = __half22float2(Dh[(size_t)r * NN + ((size_t)(k20 + it) << 8) + t]);
        sre[it * RSTR + SWZI(t, it)] = v.x;
        sim[it * RSTR + SWZI(t, it)] = v.y;
    }
    __syncthreads();
    const int g = t >> 4, u = t & 15;
    float* rr = sre + g * RSTR; float* ri = sim + g * RSTR;
    fft256_soa<1, false, 1, false, 0, 0>(rr, ri, u, 0, 0.f, 16.0f / (float)NN, g & 12, 15);
    fft256_soa<-1, true, 0, true, 0, 0>(rr, ri, u, k20 + g, TWO_PI / (float)NN, 1.f, g & 12, 15);
    __syncthreads();
#pragma unroll
    for (int it = 0; it < 16; ++it) {
        int flat = it * 256 + t;
        int i = flat & 15, k2 = flat >> 4;
        int s = i * RSTR + SWZI(k2, i);
        D2h[(size_t)r * NN + (k2 << 8) + (k20 + i)] = __floats2half2_rn(sre[s], sim[s]);
    }
}

__global__ __launch_bounds__(256)
void fo_stage2(const __half2* __restrict__ D2h, __half2* __restrict__ Cw, int qbase)
{
    __shared__ float sre[16 * RSTR];
    __shared__ float sim[16 * RSTR];
    const int t = threadIdx.x;
    const int r = blockIdx.x >> 4;
    const int k20 = (blockIdx.x & 15) << 4;
    const int q = qbase + r;
    const int j1 = q >> 6, ql = q & 63;
#pragma unroll
    for (int it = 0; it < 16; ++it) {
        float2 v = __half22float2(D2h[(size_t)r * NN + ((size_t)(k20 + it) << 8) + t]);
        sre[it * RSTR + SWZI(t, it)] = v.x;
        sim[it * RSTR + SWZI(t, it)] = v.y;
    }
    __syncthreads();
    const int g = t >> 4, u = t & 15;
    fft256_soa<-1, false, 0, false, 0, 0>(sre + g * RSTR, sim + g * RSTR, u, 0, 0.f, 1.f, g & 12, 15);
    __syncthreads();
    const size_t base = COFF[j1] + (size_t)ql * CWW[j1];
    const int lo = CLO[j1], Wd = CWW[j1];
#pragma unroll
    for (int it = 0; it < 16; ++it) {
        int flat = it * 256 + t;
        int fi = flat & 15, k1 = flat >> 4;
        int k = (k20 + fi) + (k1 << 8);
        int ksg = (k < NN / 2) ? k : k - NN;
        int idx = ksg - lo;
        if (idx >= 0 && idx < Wd) {
            int s = fi * RSTR + SWZI(k1, fi);
            Cw[base + idx] = __floats2half2_rn(sre[s], sim[s]);
        }
    }
}

// ============== S0 + S1 fold (8 + 512 blocks) ==============
__global__ __launch_bounds__(256)
void sfold_all(const float2* __restrict__ XF, const __half2* __restrict__ Cw,
               float* __restrict__ out)
{
    __shared__ float Gr[256];
    __shared__ float Gi[256];
    const int blk = blockIdx.x;
    const int t = threadIdx.x;
    const float invsigphi = 731.428571f;
    float ar = 0.f, ai = 0.f;
    if (blk < 8) {
#pragma unroll
        for (int qq = -4; qq <= 4; ++qq) {
            int ks = t + (qq << 8);
            int k = ks & (NN - 1);
            float a = ((float)ks * (1.0f / (float)NN)) * invsigphi;
            float wg = __expf(-0.5f * a * a);
            float2 v = XF[(size_t)blk * NN + k];
            ar = fmaf(v.x, wg, ar); ai = fmaf(v.y, wg, ai);
        }
    } else {
        int q = blk - 8;
        int j1 = q >> 6, ql = q & 63;
        size_t base = COFF[j1] + (size_t)ql * CWW[j1];
        int lo = CLO[j1], Wd = CWW[j1], ring = CRING[j1];
#pragma unroll
        for (int qq = -4; qq <= 4; ++qq) {
            int ks = t + (qq << 8);
            float a = ((float)ks * (1.0f / (float)NN)) * invsigphi;
            float wg = __expf(-0.5f * a * a);
            int idx = ring ? ((ks - lo) & (Wd - 1)) : (ks - lo);
            float2 v = __half22float2(Cw[base + idx]);
            ar = fmaf(v.x, wg, ar); ai = fmaf(v.y, wg, ai);
        }
    }
    Gr[t] = ar; Gi[t] = ai;
    __syncthreads();
    float sb, cb;
    __sincosf((TWO_PI / 256.0f) * (float)t, &sb, &cb);
    float wr = 1.f, wi = 0.f, s = 0.f;
    for (int kk = 0; kk < 256; ++kk) {
        s = fmaf(Gr[kk], wr, s);
        s = fmaf(-Gi[kk], wi, s);
        float nr = wr * cb - wi * sb; wi = wr * sb + wi * cb; wr = nr;
    }
    s *= (1.0f / (float)NN);
    float mag = sqrtf(fmaf(s, s, 1e-8f));
    float val = logf(mag + 1e-8f);
    int b, chan;
    if (blk < 8) { b = blk; chan = 0; }
    else { int q = blk - 8; int j1 = q >> 6, ql = q & 63; b = ql >> 3; chan = 1 + j1 * 8 + (ql & 7); }
    out[((size_t)b * 289 + chan) * 256 + t] = val;
}

// ============== FULL second order (j2 <= 2: 192 rows) ==============
__device__ __forceinline__ void so_decode_full(int q, int& j1, int& j2, int& rb)
{
    int pp = q >> 6;
    rb = q & 63;
    j2 = (pp == 0) ? 1 : 2;
    j1 = (pp == 0) ? 0 : pp - 1;
}
__device__ __forceinline__ void so_decode_dec16(int q, int& j1, int& j2, int& rb)
{
    int pp = q >> 6;
    rb = q & 63;
    j2 = (pp < 3) ? 3 : 4;
    j1 = (pp < 3) ? pp : pp - 3;
}

__global__ __launch_bounds__(256)
void so_stage1(const __half2* __restrict__ Cw, __half2* __restrict__ Dh, int qbase)
{
    __shared__ float sre[16 * RSTR];
    __shared__ float sim[16 * RSTR];
    const int t = threadIdx.x;
    const int r = blockIdx.x >> 4;
    const int n10 = (blockIdx.x & 15) << 4;
    int j1, j2, rb;
    so_decode_full(qbase + r, j1, j2, rb);
    const float xi2 = 0.35f * exp2f(-(float)j2);
    const float invsig = 1.0f / (0.6f * xi2);
    const float kc = xi2 * (float)NN;
    const float Hh = 6.10f * (0.6f * xi2) * (float)NN;
    const size_t base = COFF[j1] + (size_t)rb * CWW[j1];
    const int lo = CLO[j1], Wd = CWW[j1];
#pragma unroll
    for (int it = 0; it < 16; ++it) {
        int flat = it * 256 + t;
        int i = flat & 15, n2 = flat >> 4;
        int n = (n10 + i) + (n2 << 8);
        int ksg = (n < NN / 2) ? n : n - NN;
        float nsf = (float)ksg;
        float vr = 0.f, vi = 0.f;
        int idx = ksg - lo;
        if (fabsf(nsf - kc) <= Hh && idx >= 0 && idx < Wd) {
            float2 v = __half22float2(Cw[base + idx]);
            float a = (nsf * (1.0f / (float)NN) - xi2) * invsig;
            float wg = __expf(-0.5f * a * a) * (1.0f / 256.0f);
            vr = v.x * wg; vi = v.y * wg;
        }
        sre[i * RSTR + SWZI(n2, i)] = vr;
        sim[i * RSTR + SWZI(n2, i)] = vi;
    }
    __syncthreads();
    const int g = t >> 4, u = t & 15;
    fft256_soa<1, true, 0, false, 0, 0>(sre + g * RSTR, sim + g * RSTR, u, n10 + g,
                                        TWO_PI / (float)NN, 1.f, g & 12, 15);
    __syncthreads();
#pragma unroll
    for (int it = 0; it < 16; ++it) {
        int flat = it * 256 + t;
        int i = flat & 15, k2 = flat >> 4;
        int s = i * RSTR + SWZI(k2, i);
        Dh[(size_t)r * NN + (k2 << 8) + (n10 + i)] = __floats2half2_rn(sre[s], sim[s]);
    }
}

__global__ __launch_bounds__(256)
void so_stage2(const __half2* __restrict__ Dh, float* __restrict__ S2acc, int qbase)
{
    __shared__ float sre[16 * RSTR];
    __shared__ float sim[16 * RSTR];
    __shared__ float wtab[16][8];
    const int t = threadIdx.x;
    const int r = blockIdx.x >> 4;
    const int k20 = (blockIdx.x & 15) << 4;
#pragma unroll
    for (int it = 0; it < 16; ++it) {
        float2 v = __half22float2(Dh[(size_t)r * NN + ((size_t)(k20 + it) << 8) + t]);
        sre[it * RSTR + SWZI(t, it)] = v.x;
        sim[it * RSTR + SWZI(t, it)] = v.y;
    }
    if (t < 128) {
        int fi = t >> 3, dd = (t & 7) - 4;
        int w = k20 + fi + (dd << 8) + 768;
        float val = 0.f;
        if (w >= 0 && w <= 1536) {
            float m = (float)(w - 768);
            val = 0.003426963f * __expf(-3.690276e-5f * m * m);
        }
        wtab[fi][t & 7] = val;
    }
    __syncthreads();
    const int g = t >> 4, u = t & 15;
    // magnitudes land LINEAR (pad 4/3) in the sim plane for the conv
    fft256_soa<1, false, 2, false, 4, 3>(sre + g * RSTR, sim + g * RSTR, u, 0, 0.f, 1.f, g & 12, 15);
    __syncthreads();
    float acc = 0.f;
#pragma unroll
    for (int fi = 0; fi < 16; ++fi) {
        const float* row = sim + fi * RSTR;
#pragma unroll
        for (int dd = 0; dd < 8; ++dd)
            acc = fmaf(row[t + dd], wtab[fi][dd], acc);
    }
    atomicAdd(&S2acc[(size_t)(qbase + r) * 256 + t], acc * (1.0f / 256.0f));
}

// ============== decimated M=16384 (s=4, L=64) ==============
// MODE 1 = fo (XF*psi1, j1=2,3,4), MODE 2 = so (Cw*psi2, j2=3,4)
template<int MODE>
__global__ __launch_bounds__(256)
void dec16_s1(const float2* __restrict__ XF, const __half2* __restrict__ Cw,
              __half2* __restrict__ Dh16, int qbase)
{
    __shared__ float sre[64 * 64];
    __shared__ float sim[64 * 64];
    const int t = threadIdx.x;
    const int r = blockIdx.x >> 2;
    const int c0 = (blockIdx.x & 3) << 6;
    const int q = qbase + r;
    float xi, invsig, kc, Hh; int srow = 0; size_t cbase = 0; int lo = 0, Wd = 0, ring = 0;
    if (MODE == 1) {
        int j1 = 2 + (q >> 6); int ql = q & 63; srow = ql >> 3;
        int lam = j1 * 8 + (ql & 7);
        xi = 0.35f * exp2f(-(float)lam * 0.125f);
        invsig = 8.0f / xi; kc = xi * (float)NN; Hh = 6.10f * (xi * 0.125f) * (float)NN;
    } else {
        int j1, j2, rb;
        so_decode_dec16(q, j1, j2, rb);
        xi = 0.35f * exp2f(-(float)j2);
        invsig = 1.0f / (0.6f * xi); kc = xi * (float)NN;
        Hh = fminf(6.10f * (0.6f * xi) * (float)NN, 7967.0f);   // fold-safe for M=16384
        cbase = COFF[j1] + (size_t)rb * CWW[j1]; lo = CLO[j1]; Wd = CWW[j1]; ring = CRING[j1];
    }
    const int klo = (int)ceilf(kc - Hh);
#pragma unroll
    for (int it = 0; it < 16; ++it) {
        int flat = it * 256 + t;
        int c = flat & 63, n2 = flat >> 6;
        int kap = (c0 + c) + (n2 << 8);
        int kk = klo + (int)(((unsigned)(kap - klo)) & 16383u);
        float vr = 0.f, vi = 0.f;
        if (fabsf((float)kk - kc) <= Hh) {
            float2 v;
            bool ok = true;
            if (MODE == 1) v = XF[(size_t)srow * NN + (kk & (NN - 1))];
            else {
                int idx;
                if (ring) idx = (kk - lo) & (Wd - 1);
                else { idx = kk - lo; ok = (idx >= 0 && idx < Wd); }
                v = ok ? __half22float2(Cw[cbase + idx]) : make_float2(0.f, 0.f);
            }
            float a = ((float)kk * (1.0f / (float)NN) - xi) * invsig;
            float wg = __expf(-0.5f * a * a) * 0.015625f;
            vr = v.x * wg; vi = v.y * wg;
        }
        int p = rev64(n2);
        sre[(p << 6) + c] = vr;
        sim[(p << 6) + c] = vi;
    }
    lds_dit<64, 6, 64, 1, false>(sre, sim, t, 256);
#pragma unroll
    for (int it = 0; it < 16; ++it) {
        int flat = it * 256 + t;
        int c = flat & 63, row = flat >> 6;
        int a = (row << 6) + c;
        float ang = (TWO_PI / 16384.0f) * (float)(row * (c0 + c));
        float sj, cj; __sincosf(ang, &sj, &cj);
        float rr = sre[a] * cj - sim[a] * sj;
        sim[a] = sre[a] * sj + sim[a] * cj; sre[a] = rr;
    }
    __syncthreads();
#pragma unroll
    for (int it = 0; it < 16; ++it) {
        int flat = it * 256 + t;
        int c = flat & 63, row = flat >> 6;
        Dh16[(size_t)r * 16384 + (row << 8) + (c0 + c)] =
            __floats2half2_rn(sre[(row << 6) + c], sim[(row << 6) + c]);
    }
}

__global__ __launch_bounds__(256)
void dec16_s2so(const __half2* __restrict__ Dh16, float* __restrict__ S2acc, int qbase)
{
    __shared__ float sre[16 * RSTR];
    __shared__ float sim[16 * RSTR];
    __shared__ float wtab[16][6];
    const int t = threadIdx.x;
    const int r = blockIdx.x >> 2;
    const int k2base = (blockIdx.x & 3) << 4;
#pragma unroll
    for (int it = 0; it < 16; ++it) {
        float2 v = __half22float2(Dh16[(size_t)r * 16384 + ((k2base + it) << 8) + t]);
        sre[it * RSTR + SWZI(t, it)] = v.x;
        sim[it * RSTR + SWZI(t, it)] = v.y;
    }
    if (t < 96) {
        int p = t / 6, dl = t % 6;
        float w = (float)(256 * (dl - 2) - 4 * (k2base + p));
        wtab[p][dl] = 0.003426963f * __expf(-3.690276e-5f * w * w);
    }
    __syncthreads();
    const int g = t >> 4, u = t & 15;
    fft256_soa<1, false, 2, false, 3, 2>(sre + g * RSTR, sim + g * RSTR, u, 0, 0.f,
                                         64.0f / (float)NN, g & 12, 15);
    __syncthreads();
    float acc = 0.f;
#pragma unroll
    for (int p = 0; p < 16; ++p) {
        const float* row = sim + p * RSTR;
#pragma unroll
        for (int dl = 0; dl < 6; ++dl)
            acc = fmaf(row[t + 5 - dl], wtab[p][dl], acc);
    }
    atomicAdd(&S2acc[(size_t)(192 + qbase + r) * 256 + t], acc * 4.0f);
}

__global__ __launch_bounds__(256)
void dec16_s2fo(const __half2* __restrict__ Dh16, __half2* __restrict__ D2h16)
{
    __shared__ float sre[16 * RSTR];
    __shared__ float sim[16 * RSTR];
    const int t = threadIdx.x;
    const int r = blockIdx.x >> 2;
    const int k2base = (blockIdx.x & 3) << 4;
#pragma unroll
    for (int it = 0; it < 16; ++it) {
        float2 v = __half22float2(Dh16[(size_t)r * 16384 + ((k2base + it) << 8) + t]);
        sre[it * RSTR + SWZI(t, it)] = v.x;
        sim[it * RSTR + SWZI(t, it)] = v.y;
    }
    __syncthreads();
    const int g = t >> 4, u = t & 15;
    float* rr = sre + g * RSTR; float* ri = sim + g * RSTR;
    fft256_soa<1, false, 1, false, 0, 0>(rr, ri, u, 0, 0.f, 256.0f / (float)NN, g & 12, 15);
    fft256_soa<-1, true, 0, true, 0, 0>(rr, ri, u, k2base + g, TWO_PI / 16384.0f, 1.f, g & 12, 15);
    __syncthreads();
#pragma unroll
    for (int it = 0; it < 16; ++it) {
        int a = it * RSTR + SWZI(t, it);
        D2h16[(size_t)r * 16384 + ((k2base + it) << 8) + t] = __floats2half2_rn(sre[a], sim[a]);
    }
}

__global__ __launch_bounds__(256)
void dec16_s3fo(const __half2* __restrict__ D2h16, __half2* __restrict__ Cw, int qbase)
{
    __shared__ float sre[64 * 64];
    __shared__ float sim[64 * 64];
    const int t = threadIdx.x;
    const int r = blockIdx.x >> 2;
    const int c0 = (blockIdx.x & 3) << 6;
    const int q = qbase + r;
    const int j1 = 2 + (q >> 6), ql = q & 63;
#pragma unroll
    for (int it = 0; it < 16; ++it) {
        int flat = it * 256 + t;
        int c = flat & 63, m2 = flat >> 6;
        float2 v = __half22float2(D2h16[(size_t)r * 16384 + (m2 << 8) + (c0 + c)]);
        sre[(m2 << 6) + c] = v.x;
        sim[(m2 << 6) + c] = v.y;
    }
    lds_dif<64, 6, 64, -1, false>(sre, sim, t, 256);
    const int lo = CLO[j1];
    const size_t rbase = COFF[j1] + (size_t)ql * 16384;
#pragma unroll
    for (int it = 0; it < 16; ++it) {
        int flat = it * 256 + t;
        int c = flat & 63, p = flat >> 6;
        int kap = (c0 + c) + (rev64(p) << 8);
        int ks = (kap < 8192) ? kap : kap - 16384;
        int idx = (ks - lo) & 16383;             // ring store: all bins
        int a = (p << 6) + c;
        Cw[rbase + idx] = __floats2half2_rn(sre[a], sim[a]);
    }
}

// ============== decimated M=4096 (s=16, L=16) — single-kernel ==============
__global__ __launch_bounds__(256)
void m4k_fo(const float2* __restrict__ XF, __half2* __restrict__ Cw)
{
    __shared__ float sre[16 * RSTR];
    __shared__ float sim[16 * RSTR];
    const int t = threadIdx.x;
    const int q = blockIdx.x;
    const int j1 = 5 + (q >> 6), ql = q & 63;
    const int srow = ql >> 3;
    const int lam = j1 * 8 + (ql & 7);
    const float xi = 0.35f * exp2f(-(float)lam * 0.125f);
    const float invsig = 8.0f / xi;
    const float kc = xi * (float)NN;
    const float Hh = 6.10f * (xi * 0.125f) * (float)NN;
    const int klo = (int)ceilf(kc - Hh);
#pragma unroll
    for (int it = 0; it < 16; ++it) {
        int kap = t + (it << 8);
        int kk = klo + (int)(((unsigned)(kap - klo)) & 4095u);
        float vr = 0.f, vi = 0.f;
        if (fabsf((float)kk - kc) <= Hh) {
            float2 v = XF[(size_t)srow * NN + (kk & (NN - 1))];
            float a = ((float)kk * (1.0f / (float)NN) - xi) * invsig;
            float wg = __expf(-0.5f * a * a);
            vr = v.x * wg; vi = v.y * wg;
        }
        int p = rev16(it);
        sre[p * RSTR + SWZI(t, p)] = vr;
        sim[p * RSTR + SWZI(t, p)] = vi;
    }
    lds_dit<16, 8, RSTR, 1, true>(sre, sim, t, 256);
#pragma unroll
    for (int it = 0; it < 16; ++it) {
        int a = it * RSTR + SWZI(t, it);
        float ang = (TWO_PI / 4096.0f) * (float)(it * t);
        float sj, cj; __sincosf(ang, &sj, &cj);
        float rr = sre[a] * cj - sim[a] * sj;
        sim[a] = sre[a] * sj + sim[a] * cj; sre[a] = rr;
    }
    __syncthreads();
    const int g = t >> 4, u = t & 15;
    float* rr = sre + g * RSTR; float* ri = sim + g * RSTR;
    fft256_soa<1, false, 1, false, 0, 0>(rr, ri, u, 0, 0.f, 16.0f / (float)NN, g & 12, 15);
    fft256_soa<-1, true, 0, true, 0, 0>(rr, ri, u, g, TWO_PI / 4096.0f, 1.f, g & 12, 15);
    lds_dif<16, 8, RSTR, -1, true>(sre, sim, t, 256);
    const int lo = CLO[j1];
    const size_t rbase = COFF[j1] + (size_t)ql * 4096;
#pragma unroll
    for (int it = 0; it < 16; ++it) {
        int kap = t + (rev16(it) << 8);
        int ks = (kap < 2048) ? kap : kap - 4096;
        int idx = (ks - lo) & 4095;              // ring store
        int a = it * RSTR + SWZI(t, it);
        Cw[rbase + idx] = __floats2half2_rn(sre[a], sim[a]);
    }
}

// m4k second order: j2 = 5,6,7 (1152 rows), direct output
__global__ __launch_bounds__(256)
void m4k_so(const __half2* __restrict__ Cw, float* __restrict__ out)
{
    __shared__ float sre[16 * RSTR];
    __shared__ float sim[16 * RSTR];
    __shared__ float wtab[16][6];
    const int t = threadIdx.x;
    const int q = blockIdx.x;
    const int pp = q >> 6, rb = q & 63;
    int j1, j2;
    if (pp < 5)       { j2 = 5; j1 = pp; }
    else if (pp < 11) { j2 = 6; j1 = pp - 5; }
    else              { j2 = 7; j1 = pp - 11; }
    const float xi2 = 0.35f * exp2f(-(float)j2);
    const float invsig = 1.0f / (0.6f * xi2);
    const float kc = xi2 * (float)NN;
    const float Hh = fminf(6.10f * (0.6f * xi2) * (float)NN, 1823.0f);  // fold-safe M=4096
    const int klo = (int)ceilf(kc - Hh);
    const size_t cbase = COFF[j1] + (size_t)rb * CWW[j1];
    const int lo = CLO[j1], Wd = CWW[j1], ring = CRING[j1];
#pragma unroll
    for (int it = 0; it < 16; ++it) {
        int kap = t + (it << 8);
        int kk = klo + (int)(((unsigned)(kap - klo)) & 4095u);
        float vr = 0.f, vi = 0.f;
        if (fabsf((float)kk - kc) <= Hh) {
            int idx; bool ok = true;
            if (ring) idx = (kk - lo) & (Wd - 1);
            else { idx = kk - lo; ok = (idx >= 0 && idx < Wd); }
            if (ok) {
                float2 v = __half22float2(Cw[cbase + idx]);
                float a = ((float)kk * (1.0f / (float)NN) - xi2) * invsig;
                float wg = __expf(-0.5f * a * a);
                vr = v.x * wg; vi = v.y * wg;
            }
        }
        int p = rev16(it);
        sre[p * RSTR + SWZI(t, p)] = vr;
        sim[p * RSTR + SWZI(t, p)] = vi;
    }
    if (t < 96) {
        int p = t / 6, dl = t % 6;
        float w = (float)(256 * (dl - 2) - 16 * p);
        wtab[p][dl] = 0.003426963f * __expf(-3.690276e-5f * w * w);
    }
    lds_dit<16, 8, RSTR, 1, true>(sre, sim, t, 256);
#pragma unroll
    for (int it = 0; it < 16; ++it) {
        int a = it * RSTR + SWZI(t, it);
        float ang = (TWO_PI / 4096.0f) * (float)(it * t);
        float sj, cj; __sincosf(ang, &sj, &cj);
        float rr = sre[a] * cj - sim[a] * sj;
        sim[a] = sre[a] * sj + sim[a] * cj; sre[a] = rr;
    }
    __syncthreads();
    const int g = t >> 4, u = t & 15;
    fft256_soa<1, false, 2, false, 3, 2>(sre + g * RSTR, sim + g * RSTR, u, 0, 0.f,
                                         1.0f / (float)NN, g & 12, 15);
    __syncthreads();
    float acc = 0.f;
#pragma unroll
    for (int p = 0; p < 16; ++p) {
        const float* row = sim + p * RSTR;
#pragma unroll
        for (int dl = 0; dl < 6; ++dl)
            acc = fmaf(row[t + 5 - dl], wtab[p][dl], acc);
    }
    acc *= 16.0f;
    const int b = rb >> 3;
    const int chan = 65 + 4 * j2 * (j2 - 1) + j1 * 8 + (rb & 7);
    float mag = sqrtf(fmaf(acc, acc, 1e-8f));
    out[((size_t)b * 289 + chan) * 256 + t] = logf(mag + 1e-8f);
}

__global__ __launch_bounds__(256)
void s2final(const float* __restrict__ S2acc, float* __restrict__ out)
{
    const int q = blockIdx.x, n = threadIdx.x;
    int j1, j2, rb;
    if (q < 192) so_decode_full(q, j1, j2, rb);
    else         so_decode_dec16(q - 192, j1, j2, rb);
    const int b = rb >> 3;
    const int chan = 65 + 4 * j2 * (j2 - 1) + j1 * 8 + (rb & 7);
    float s = S2acc[(size_t)q * 256 + n];
    float mag = sqrtf(fmaf(s, s, 1e-8f));
    out[((size_t)b * 289 + chan) * 256 + n] = logf(mag + 1e-8f);
}

__global__ void zero_kernel(float* p, int nElem)
{
    int i = blockIdx.x * 256 + threadIdx.x;
    if (i < nElem) p[i] = 0.f;
}

extern "C" void kernel_launch(void* const* d_in, const int* in_sizes, int n_in,
                              void* d_out, int out_size, void* d_ws, size_t ws_size,
                              hipStream_t stream)
{
    const float* x = (const float*)d_in[0];
    float* out = (float*)d_out;
    char* ws = (char*)d_ws;

    size_t off = 0;
    float2*  XF    = (float2*)ws;                 off += 8ul * NN * 8;
    __half2* Cw    = (__half2*)(ws + off);        off += CTOT * 4ul;
    float*   S2acc = (float*)(ws + off);          off += 640ul * 256 * 4;
    off = (off + 255) & ~255ul;
    char* reg0 = ws + off;
    size_t avail = (ws_size > off) ? (ws_size - off) : 0;

    int CHB = (int)(avail / (512ul * 1024));  if (CHB > 128) CHB = 128;  if (CHB < 1) CHB = 1;
    int CHD = (int)(avail / (256ul * 1024));  if (CHD > 192) CHD = 192;  if (CHD < 1) CHD = 1;
    int CHE = (int)(avail / (128ul * 1024));  if (CHE > 192) CHE = 192;  if (CHE < 1) CHE = 1;
    int CHF = (int)(avail / (64ul * 1024));   if (CHF > 448) CHF = 448;  if (CHF < 1) CHF = 1;

    {
        int nz = 8 * 289 * 256;
        zero_kernel<<<(nz + 255) / 256, 256, 0, stream>>>(out + nz, nz);
        int na = 640 * 256;
        zero_kernel<<<(na + 255) / 256, 256, 0, stream>>>(S2acc, na);
    }

    // XF = fft(x)
    {
        float2* Df = (float2*)reg0;
        xf_stage1<<<8 * 16, 256, 0, stream>>>(x, Df);
        xf_stage2<<<8 * 16, 256, 0, stream>>>(Df, XF);
    }

    // first order FULL (j1 = 0,1 : 128 rows)
    for (int cs = 0; cs < 128; cs += CHB) {
        int m = (128 - cs < CHB) ? (128 - cs) : CHB;
        __half2* DhB = (__half2*)reg0;
        __half2* D2h = DhB + (size_t)CHB * NN;
        fo_stage1<<<m * 16, 256, 0, stream>>>(XF, DhB, cs);
        fo_mid<<<m * 16, 256, 0, stream>>>(DhB, D2h);
        fo_stage2<<<m * 16, 256, 0, stream>>>(D2h, Cw, cs);
    }
    // first order M=16384 (j1 = 2,3,4 : 192 rows)
    for (int cs = 0; cs < 192; cs += CHE) {
        int m = (192 - cs < CHE) ? (192 - cs) : CHE;
        __half2* Dh16  = (__half2*)reg0;
        __half2* D2h16 = Dh16 + (size_t)CHE * 16384;
        dec16_s1<1><<<m * 4, 256, 0, stream>>>(XF, Cw, Dh16, cs);
        dec16_s2fo<<<m * 4, 256, 0, stream>>>(Dh16, D2h16);
        dec16_s3fo<<<m * 4, 256, 0, stream>>>(D2h16, Cw, cs);
    }
    // first order M=4096 (j1 = 5..7)
    m4k_fo<<<192, 256, 0, stream>>>(XF, Cw);

    // S0 + S1
    sfold_all<<<8 + 512, 256, 0, stream>>>(XF, Cw, out);

    // second order FULL (j2 = 1,2 : 192 rows)
    for (int qs = 0; qs < 192; qs += CHD) {
        int m = (192 - qs < CHD) ? (192 - qs) : CHD;
        __half2* DhS = (__half2*)reg0;
        so_stage1<<<m * 16, 256, 0, stream>>>(Cw, DhS, qs);
        so_stage2<<<m * 16, 256, 0, stream>>>(DhS, S2acc, qs);
    }
    // second order M=16384 (j2 = 3,4 : 448 rows)
    for (int qs = 0; qs < 448; qs += CHF) {
        int m = (448 - qs < CHF) ? (448 - qs) : CHF;
        __half2* Dh16 = (__half2*)reg0;
        dec16_s1<2><<<m * 4, 256, 0, stream>>>(XF, Cw, Dh16, qs);
        dec16_s2so<<<m * 4, 256, 0, stream>>>(Dh16, S2acc, qs);
    }
    // second order M=4096 (j2 = 5,6,7 : 1152 rows)
    m4k_so<<<1152, 256, 0, stream>>>(Cw, out);

    s2final<<<640, 256, 0, stream>>>(S2acc, out);
}

// Round 8
// 308.059 us; speedup vs baseline: 9.1727x; 1.0154x over previous
//
#include <hip/hip_runtime.h>
#include <hip/hip_fp16.h>
#include <math.h>

#define NN 65536
#define TWO_PI 6.283185307179586f
#define RSTR 264   // LDS row stride in floats
#define SWZ(m) ((m) ^ (((m) >> 4) & 15))
#define SWZI(m, r) (SWZ(m) ^ ((r) & 12))
#define CTOT 10829824ul   // total fp16 C elements (full j1=0,1; ring j1>=2)

// per-octave C storage: signed-bin lo, width, offset. j1>=2 are M-rings (mask index).
__constant__ int CLO[8]  = {-32768, -15360, -5376, -8192, -8192, -2048, -2048, -2048};
__constant__ int CWW[8]  = {65536, 42240, 16384, 16384, 16384, 4096, 4096, 4096};
__constant__ int CRING[8] = {0, 0, 1, 1, 1, 1, 1, 1};
__constant__ unsigned long COFF[8] = {0ul, 4194304ul, 6897664ul, 7946240ul,
                                      8994816ul, 10043392ul, 10305536ul, 10567680ul};

__device__ __forceinline__ void lds_fence() {
    asm volatile("s_waitcnt lgkmcnt(0)" ::: "memory");
}
__device__ __forceinline__ int rev16(int p) { return ((p & 3) << 2) | (p >> 2); }
__device__ __forceinline__ int rev64(int p) { return ((p & 3) << 4) | (p & 12) | (p >> 4); }

// quarters of the n2 axis (bins [16384q-255, 16384q+16639] cover all n1) vs band
__device__ __forceinline__ int quarter_mask(int klo, int khi)
{
    int qm = 0;
#pragma unroll
    for (int qq = 0; qq < 4; ++qq) {
        int lo_q = 16384 * qq - 255;
        int hi_q = 16384 * qq + 16639;
        bool act;
        if (klo >= 0) act = (hi_q >= klo) && (lo_q <= khi);
        else          act = (lo_q <= khi) || (hi_q >= klo + NN);
        if (act) qm |= (1 << qq);
    }
    return qm;
}

// twiddle LUT: entry j holds (cos,sin,cos2,sin2,cos3,sin3) of theta = 2pi/64 * j.
// pass h uses entry j*(16/h)  (h=16 -> j, h=4 -> 4j).  96 floats in LDS.
__device__ __forceinline__ void build_tw6(float* twt, int t)
{
    if (t < 16) {
        float s1, c1; __sincosf((TWO_PI / 64.0f) * (float)t, &s1, &c1);
        float c2 = c1 * c1 - s1 * s1, s2 = 2.f * c1 * s1;
        float c3 = c2 * c1 - s2 * s1, s3 = c2 * s1 + s2 * c1;
        float* e = twt + 6 * t;
        e[0] = c1; e[1] = s1; e[2] = c2; e[3] = s2; e[4] = c3; e[5] = s3;
    }
}

// ---------------- radix-4 x radix-4 16-point FFT, natural order ----------------
template<int SIGN>
__device__ __forceinline__ void fft16(float* xr, float* xi, float* yr, float* yi)
{
    const float S = (SIGN > 0) ? 1.0f : -1.0f;
    const float C8 = 0.92387953251f, S8 = 0.38268343236f, R2 = 0.70710678119f;
#pragma unroll
    for (int n0 = 0; n0 < 4; ++n0) {
        float z0r=xr[n0],    z0i=xi[n0];
        float z1r=xr[n0+4],  z1i=xi[n0+4];
        float z2r=xr[n0+8],  z2i=xi[n0+8];
        float z3r=xr[n0+12], z3i=xi[n0+12];
        float t0r=z0r+z2r, t0i=z0i+z2i;
        float t1r=z0r-z2r, t1i=z0i-z2i;
        float t2r=z1r+z3r, t2i=z1i+z3i;
        float t3r=S*(z1r-z3r), t3i=S*(z1i-z3i);
        xr[n0]=t0r+t2r;      xi[n0]=t0i+t2i;
        xr[n0+4]=t1r-t3i;    xi[n0+4]=t1i+t3r;
        xr[n0+8]=t0r-t2r;    xi[n0+8]=t0i-t2i;
        xr[n0+12]=t1r+t3i;   xi[n0+12]=t1i-t3r;
    }
    {
        const float W1r=C8,  W1i=S*S8;
        const float W2r=R2,  W2i=S*R2;
        const float W3r=S8,  W3i=S*C8;
        const float W6r=-R2, W6i=S*R2;
        const float W9r=-C8, W9i=-S*S8;
#define TWID(idx, wr, wi) { float ar=xr[idx], ai=xi[idx]; xr[idx]=ar*(wr)-ai*(wi); xi[idx]=ar*(wi)+ai*(wr); }
        TWID(5,W1r,W1i)  TWID(9,W2r,W2i)   TWID(13,W3r,W3i)
        TWID(6,W2r,W2i)  { float ar=xr[10], ai=xi[10]; xr[10]=-S*ai; xi[10]=S*ar; } TWID(14,W6r,W6i)
        TWID(7,W3r,W3i)  TWID(11,W6r,W6i)  TWID(15,W9r,W9i)
#undef TWID
    }
#pragma unroll
    for (int p = 0; p < 4; ++p) {
        float z0r=xr[4*p],   z0i=xi[4*p];
        float z1r=xr[4*p+1], z1i=xi[4*p+1];
        float z2r=xr[4*p+2], z2i=xi[4*p+2];
        float z3r=xr[4*p+3], z3i=xi[4*p+3];
        float t0r=z0r+z2r, t0i=z0i+z2i;
        float t1r=z0r-z2r, t1i=z0i-z2i;
        float t2r=z1r+z3r, t2i=z1i+z3i;
        float t3r=S*(z1r-z3r), t3i=S*(z1i-z3i);
        yr[p]=t0r+t2r;     yi[p]=t0i+t2i;
        yr[p+4]=t1r-t3i;   yi[p+4]=t1i+t3r;
        yr[p+8]=t0r-t2r;   yi[p+8]=t0i-t2i;
        yr[p+12]=t1r+t3i;  yi[p+12]=t1i-t3r;
    }
}

// ------- 256-pt FFT on one group's SoA LDS row (16 lanes, one wave) -------
// OUT 0: complex to rr/ri (SWZ). OUT 1: |.|*mscale to rr (SWZ).
// OUT 2: |.|*mscale to ri LINEAR with halo pads. INREAL: pass-1 imag = 0.
template<int SIGN, bool BIGTW, int OUT, bool INREAL, int PADL, int PADR>
__device__ __forceinline__ void fft256_soa(float* rr, float* ri, int u, int n1,
                                           float twrate, float mscale, int cxor, int qmask)
{
    float xr[16], xi[16], yr[16], yi[16];
#pragma unroll
    for (int qq = 0; qq < 4; ++qq) {
        if (qmask & (1 << qq)) {
#pragma unroll
            for (int j = 0; j < 4; ++j) {
                int b = qq * 4 + j;
                int s = SWZ(u + (b << 4)) ^ cxor;
                xr[b] = rr[s];
                xi[b] = INREAL ? 0.f : ri[s];
            }
        } else {
#pragma unroll
            for (int j = 0; j < 4; ++j) { xr[qq * 4 + j] = 0.f; xi[qq * 4 + j] = 0.f; }
        }
    }
    fft16<SIGN>(xr, xi, yr, yi);
    float sa, ca;
    __sincosf((float)SIGN * (TWO_PI / 256.0f) * (float)u, &sa, &ca);
    float twr = 1.f, twi = 0.f;
#pragma unroll
    for (int c = 0; c < 16; ++c) {
        int s = SWZ((c << 4) + u) ^ cxor;
        rr[s] = yr[c] * twr - yi[c] * twi;
        ri[s] = yr[c] * twi + yi[c] * twr;
        float nr = twr * ca - twi * sa; twi = twr * sa + twi * ca; twr = nr;
    }
    lds_fence();
#pragma unroll
    for (int a = 0; a < 16; ++a) {
        int s = SWZ((u << 4) + a) ^ cxor;
        xr[a] = rr[s]; xi[a] = ri[s];
    }
    fft16<SIGN>(xr, xi, yr, yi);
    float tbr = 1.f, tbi = 0.f, str = 1.f, sti = 0.f;
    if (BIGTW) {
        float s0, c0, s1, c1;
        __sincosf((float)SIGN * twrate * (float)(n1 * u), &s0, &c0);
        __sincosf((float)SIGN * twrate * (float)(n1 << 4), &s1, &c1);
        tbr = c0; tbi = s0; str = c1; sti = s1;
    }
#pragma unroll
    for (int d = 0; d < 16; ++d) {
        float vr = yr[d], vi = yi[d];
        if (BIGTW) {
            float pr = vr * tbr - vi * tbi, pi = vr * tbi + vi * tbr;
            vr = pr; vi = pi;
            float nr = tbr * str - tbi * sti; tbi = tbr * sti + tbi * str; tbr = nr;
        }
        int k = u + (d << 4);
        if (OUT == 1) {
            rr[SWZ(k) ^ cxor] = sqrtf(fmaf(vr, vr, vi * vi)) * mscale;
        } else if (OUT == 2) {
            float mag = sqrtf(fmaf(vr, vr, vi * vi)) * mscale;
            ri[PADL + k] = mag;
            if (k >= 256 - PADL) ri[k - (256 - PADL)] = mag;
            if (k < PADR) ri[PADL + 256 + k] = mag;
        } else {
            int s = SWZ(k) ^ cxor;
            rr[s] = vr; ri[s] = vi;
        }
    }
    lds_fence();
}

// ---------- LDS radix-4 passes over the row axis (twiddles from twt LUT) ----------
template<int L, int CLOG, int RST, int SIGN, bool SWZC>
__device__ __forceinline__ void lds_dit(float* re, float* im, const float* twt, int t, int T)
{
    const float S = (float)SIGN;
    const int NC = 1 << CLOG;
    const int nbf = NC * (L >> 2);
    for (int h = 1; h < L; h <<= 2) {
        __syncthreads();
        for (int i = t; i < nbf; i += T) {
            int c = i & (NC - 1);
            int bf = i >> CLOG;
            int j = bf & (h - 1);
            int q0 = ((bf - j) << 2) + j;
            int r0 = q0, r1 = q0 + h, r2 = q0 + 2 * h, r3 = q0 + 3 * h;
            int a0, a1, a2, a3;
            if (SWZC) {
                a0 = r0 * RST + SWZI(c, r0); a1 = r1 * RST + SWZI(c, r1);
                a2 = r2 * RST + SWZI(c, r2); a3 = r3 * RST + SWZI(c, r3);
            } else {
                a0 = r0 * RST + c; a1 = r1 * RST + c; a2 = r2 * RST + c; a3 = r3 * RST + c;
            }
            float x0r = re[a0], x0i = im[a0];
            float x1r = re[a1], x1i = im[a1];
            float x2r = re[a2], x2i = im[a2];
            float x3r = re[a3], x3i = im[a3];
            if (h > 1) {
                const float* e = twt + 6 * (j * (16 / h));
                float cj = e[0], sj = S * e[1];
                float c2 = e[2], s2 = S * e[3];
                float c3 = e[4], s3 = S * e[5];
                float r;
                r = x1r * cj - x1i * sj; x1i = x1r * sj + x1i * cj; x1r = r;
                r = x2r * c2 - x2i * s2; x2i = x2r * s2 + x2i * c2; x2r = r;
                r = x3r * c3 - x3i * s3; x3i = x3r * s3 + x3i * c3; x3r = r;
            }
            float t0r = x0r + x2r, t0i = x0i + x2i;
            float t1r = x0r - x2r, t1i = x0i - x2i;
            float t2r = x1r + x3r, t2i = x1i + x3i;
            float t3r = -S * (x1i - x3i), t3i = S * (x1r - x3r);
            re[a0] = t0r + t2r; im[a0] = t0i + t2i;
            re[a1] = t1r + t3r; im[a1] = t1i + t3i;
            re[a2] = t0r - t2r; im[a2] = t0i - t2i;
            re[a3] = t1r - t3r; im[a3] = t1i - t3i;
        }
    }
    __syncthreads();
}

template<int L, int CLOG, int RST, int SIGN, bool SWZC>
__device__ __forceinline__ void lds_dif(float* re, float* im, const float* twt, int t, int T)
{
    const float S = (float)SIGN;
    const int NC = 1 << CLOG;
    const int nbf = NC * (L >> 2);
    for (int h = L >> 2; h >= 1; h >>= 2) {
        __syncthreads();
        for (int i = t; i < nbf; i += T) {
            int c = i & (NC - 1);
            int bf = i >> CLOG;
            int j = bf & (h - 1);
            int q0 = ((bf - j) << 2) + j;
            int r0 = q0, r1 = q0 + h, r2 = q0 + 2 * h, r3 = q0 + 3 * h;
            int a0, a1, a2, a3;
            if (SWZC) {
                a0 = r0 * RST + SWZI(c, r0); a1 = r1 * RST + SWZI(c, r1);
                a2 = r2 * RST + SWZI(c, r2); a3 = r3 * RST + SWZI(c, r3);
            } else {
                a0 = r0 * RST + c; a1 = r1 * RST + c; a2 = r2 * RST + c; a3 = r3 * RST + c;
            }
            float x0r = re[a0], x0i = im[a0];
            float x1r = re[a1], x1i = im[a1];
            float x2r = re[a2], x2i = im[a2];
            float x3r = re[a3], x3i = im[a3];
            float t0r = x0r + x2r, t0i = x0i + x2i;
            float t1r = x0r - x2r, t1i = x0i - x2i;
            float t2r = x1r + x3r, t2i = x1i + x3i;
            float t3r = -S * (x1i - x3i), t3i = S * (x1r - x3r);
            float y1r = t1r + t3r, y1i = t1i + t3i;
            float y2r = t0r - t2r, y2i = t0i - t2i;
            float y3r = t1r - t3r, y3i = t1i - t3i;
            re[a0] = t0r + t2r; im[a0] = t0i + t2i;
            if (h > 1) {
                const float* e = twt + 6 * (j * (16 / h));
                float cj = e[0], sj = S * e[1];
                float c2 = e[2], s2 = S * e[3];
                float c3 = e[4], s3 = S * e[5];
                re[a1] = y1r * cj - y1i * sj; im[a1] = y1r * sj + y1i * cj;
                re[a2] = y2r * c2 - y2i * s2; im[a2] = y2r * s2 + y2i * c2;
                re[a3] = y3r * c3 - y3i * s3; im[a3] = y3r * s3 + y3i * c3;
            } else {
                re[a1] = y1r; im[a1] = y1i;
                re[a2] = y2r; im[a2] = y2i;
                re[a3] = y3r; im[a3] = y3i;
            }
        }
    }
    __syncthreads();
}

// ================= XF chain (fp32, 8 rows) =================
__global__ __launch_bounds__(256)
void xf_stage1(const float* __restrict__ x, float2* __restrict__ D)
{
    __shared__ float sre[16 * RSTR];
    __shared__ float sim[16 * RSTR];
    const int t = threadIdx.x;
    const int r = blockIdx.x >> 4;
    const int n10 = (blockIdx.x & 15) << 4;
#pragma unroll
    for (int it = 0; it < 16; ++it) {
        int flat = it * 256 + t;
        int i = flat & 15, n2 = flat >> 4;
        int n = (n10 + i) + (n2 << 8);
        sre[i * RSTR + SWZI(n2, i)] = x[(size_t)r * NN + n];
        sim[i * RSTR + SWZI(n2, i)] = 0.f;
    }
    __syncthreads();
    const int g = t >> 4, u = t & 15;
    fft256_soa<-1, true, 0, false, 0, 0>(sre + g * RSTR, sim + g * RSTR, u, n10 + g,
                                         TWO_PI / (float)NN, 1.f, g & 12, 15);
    __syncthreads();
#pragma unroll
    for (int it = 0; it < 16; ++it) {
        int flat = it * 256 + t;
        int i = flat & 15, k2 = flat >> 4;
        int s = i * RSTR + SWZI(k2, i);
        D[(size_t)r * NN + (k2 << 8) + (n10 + i)] = make_float2(sre[s], sim[s]);
    }
}

__global__ __launch_bounds__(256)
void xf_stage2(const float2* __restrict__ D, float2* __restrict__ XF)
{
    __shared__ float sre[16 * RSTR];
    __shared__ float sim[16 * RSTR];
    const int t = threadIdx.x;
    const int r = blockIdx.x >> 4;
    const int k20 = (blockIdx.x & 15) << 4;
#pragma unroll
    for (int it = 0; it < 16; ++it) {
        float2 v = D[(size_t)r * NN + ((size_t)(k20 + it) << 8) + t];
        sre[it * RSTR + SWZI(t, it)] = v.x;
        sim[it * RSTR + SWZI(t, it)] = v.y;
    }
    __syncthreads();
    const int g = t >> 4, u = t & 15;
    fft256_soa<-1, false, 0, false, 0, 0>(sre + g * RSTR, sim + g * RSTR, u, 0, 0.f, 1.f, g & 12, 15);
    __syncthreads();
#pragma unroll
    for (int it = 0; it < 16; ++it) {
        int flat = it * 256 + t;
        int fi = flat & 15, k1 = flat >> 4;
        int s = fi * RSTR + SWZI(k1, fi);
        XF[(size_t)r * NN + (size_t)(k20 + fi) + ((size_t)k1 << 8)] = make_float2(sre[s], sim[s]);
    }
}

// ================= FULL first-order chain (j1 = 0,1 : 128 rows) =================
__global__ __launch_bounds__(256)
void fo_stage1(const float2* __restrict__ XF, __half2* __restrict__ Dh, int qbase)
{
    __shared__ float sre[16 * RSTR];
    __shared__ float sim[16 * RSTR];
    const int t = threadIdx.x;
    const int r = blockIdx.x >> 4;
    const int n10 = (blockIdx.x & 15) << 4;
    const int q = qbase + r;
    const int j1 = q >> 6, ql = q & 63;
    const int srow = ql >> 3, w = ql & 7;
    const int lam = j1 * 8 + w;
    const float xi = 0.35f * exp2f(-(float)lam * 0.125f);
    const float invsig = 8.0f / xi;
    const float kc = xi * (float)NN;
    const float Hh = 5.0f * (xi * 0.125f) * (float)NN;
    const int klo = (int)(kc - Hh), khi = (int)(kc + Hh) + 1;
    const int qm = (khi >= NN) ? 15 : quarter_mask(klo, khi);
#pragma unroll
    for (int it = 0; it < 16; ++it) {
        int i = t & 15, n2 = (it << 4) + (t >> 4);
        if (!(qm & (1 << (it >> 2)))) {
            sre[i * RSTR + SWZI(n2, i)] = 0.f;
            sim[i * RSTR + SWZI(n2, i)] = 0.f;
            continue;
        }
        int n = (n10 + i) + (n2 << 8);
        float nsf = (float)((n < NN / 2) ? n : n - NN);
        float vr = 0.f, vi = 0.f;
        if (fabsf(nsf - kc) <= Hh) {
            float2 v = XF[(size_t)srow * NN + n];
            float a = (nsf * (1.0f / (float)NN) - xi) * invsig;
            float wg = __expf(-0.5f * a * a) * 0.0625f;
            vr = v.x * wg; vi = v.y * wg;
        }
        sre[i * RSTR + SWZI(n2, i)] = vr;
        sim[i * RSTR + SWZI(n2, i)] = vi;
    }
    __syncthreads();
    const int g = t >> 4, u = t & 15;
    fft256_soa<1, true, 0, false, 0, 0>(sre + g * RSTR, sim + g * RSTR, u, n10 + g,
                                        TWO_PI / (float)NN, 1.f, g & 12, qm);
    __syncthreads();
#pragma unroll
    for (int it = 0; it < 16; ++it) {
        int flat = it * 256 + t;
        int i = flat & 15, k2 = flat >> 4;
        int s = i * RSTR + SWZI(k2, i);
        Dh[(size_t)r * NN + (k2 << 8) + (n10 + i)] = __floats2half2_rn(sre[s], sim[s]);
    }
}

__global__ __launch_bounds__(256)
void fo_mid(const __half2* __restrict__ Dh, __half2* __restrict__ D2h)
{
    __shared__ float sre[16 * RSTR];
    __shared__ float sim[16 * RSTR];
    const int t = threadIdx.x;
    const int r = blockIdx.x >> 4;
    const int k20 = (blockIdx.x & 15) << 4;
#pragma unroll
    for (int it = 0; it < 16; ++it) {
        float2 v = __half22float2(Dh[(size_t)r * NN + ((size_t)(k20 + it) << 8) + t]);
        sre[it * RSTR + SWZI(t, it)] = v.x;
        sim[it * RSTR + SWZI(t, it)] = v.y;
    }
    __syncthreads();
    const int g = t >> 4, u = t & 15;
    float* rr = sre + g * RSTR; float* ri = sim + g * RSTR;
    fft256_soa<1, false, 1, false, 0, 0>(rr, ri, u, 0, 0.f, 16.0f / (float)NN, g & 12, 15);
    fft256_soa<-1, true, 0, true, 0, 0>(rr, ri, u, k20 + g, TWO_PI / (float)NN, 1.f, g & 12, 15);
    __syncthreads();
#pragma unroll
    for (int it = 0; it < 16; ++it) {
        int flat = it * 256 + t;
        int i = flat & 15, k2 = flat >> 4;
        int s = i * RSTR + SWZI(k2, i);
        D2h[(size_t)r * NN + (k2 << 8) + (k20 + i)] = __floats2half2_rn(sre[s], sim[s]);
    }
}

__global__ __launch_bounds__(256)
void fo_stage2(const __half2* __restrict__ D2h, __half2* __restrict__ Cw, int qbase)
{
    __shared__ float sre[16 * RSTR];
    __shared__ float sim[16 * RSTR];
    const int t = threadIdx.x;
    const int r = blockIdx.x >> 4;
    const int k20 = (blockIdx.x & 15) << 4;
    const int q = qbase + r;
    const int j1 = q >> 6, ql = q & 63;
#pragma unroll
    for (int it = 0; it < 16; ++it) {
        float2 v = __half22float2(D2h[(size_t)r * NN + ((size_t)(k20 + it) << 8) + t]);
        sre[it * RSTR + SWZI(t, it)] = v.x;
        sim[it * RSTR + SWZI(t, it)] = v.y;
    }
    __syncthreads();
    const int g = t >> 4, u = t & 15;
    fft256_soa<-1, false, 0, false, 0, 0>(sre + g * RSTR, sim + g * RSTR, u, 0, 0.f, 1.f, g & 12, 15);
    __syncthreads();
    const size_t base = COFF[j1] + (size_t)ql * CWW[j1];
    const int lo = CLO[j1], Wd = CWW[j1];
#pragma unroll
    for (int it = 0; it < 16; ++it) {
        int flat = it * 256 + t;
        int fi = flat & 15, k1 = flat >> 4;
        int k = (k20 + fi) + (k1 << 8);
        int ksg = (k < NN / 2) ? k : k - NN;
        int idx = ksg - lo;
        if (idx >= 0 && idx < Wd) {
            int s = fi * RSTR + SWZI(k1, fi);
            Cw[base + idx] = __floats2half2_rn(sre[s], sim[s]);
        }
    }
}

// ============== S0 + S1 fold (8 + 512 blocks) ==============
__global__ __launch_bounds__(256)
void sfold_all(const float2* __restrict__ XF, const __half2* __restrict__ Cw,
               float* __restrict__ out)
{
    __shared__ float Gr[256];
    __shared__ float Gi[256];
    const int blk = blockIdx.x;
    const int t = threadIdx.x;
    const float invsigphi = 731.428571f;
    float ar = 0.f, ai = 0.f;
    if (blk < 8) {
#pragma unroll
        for (int qq = -4; qq <= 4; ++qq) {
            int ks = t + (qq << 8);
            int k = ks & (NN - 1);
            float a = ((float)ks * (1.0f / (float)NN)) * invsigphi;
            float wg = __expf(-0.5f * a * a);
            float2 v = XF[(size_t)blk * NN + k];
            ar = fmaf(v.x, wg, ar); ai = fmaf(v.y, wg, ai);
        }
    } else {
        int q = blk - 8;
        int j1 = q >> 6, ql = q & 63;
        size_t base = COFF[j1] + (size_t)ql * CWW[j1];
        int lo = CLO[j1], Wd = CWW[j1], ring = CRING[j1];
#pragma unroll
        for (int qq = -4; qq <= 4; ++qq) {
            int ks = t + (qq << 8);
            float a = ((float)ks * (1.0f / (float)NN)) * invsigphi;
            float wg = __expf(-0.5f * a * a);
            int idx = ring ? ((ks - lo) & (Wd - 1)) : (ks - lo);
            float2 v = __half22float2(Cw[base + idx]);
            ar = fmaf(v.x, wg, ar); ai = fmaf(v.y, wg, ai);
        }
    }
    Gr[t] = ar; Gi[t] = ai;
    __syncthreads();
    float sb, cb;
    __sincosf((TWO_PI / 256.0f) * (float)t, &sb, &cb);
    float wr = 1.f, wi = 0.f, s = 0.f;
    for (int kk = 0; kk < 256; ++kk) {
        s = fmaf(Gr[kk], wr, s);
        s = fmaf(-Gi[kk], wi, s);
        float nr = wr * cb - wi * sb; wi = wr * sb + wi * cb; wr = nr;
    }
    s *= (1.0f / (float)NN);
    float mag = sqrtf(fmaf(s, s, 1e-8f));
    float val = logf(mag + 1e-8f);
    int b, chan;
    if (blk < 8) { b = blk; chan = 0; }
    else { int q = blk - 8; int j1 = q >> 6, ql = q & 63; b = ql >> 3; chan = 1 + j1 * 8 + (ql & 7); }
    out[((size_t)b * 289 + chan) * 256 + t] = val;
}

// ============== FULL second order (j2 <= 2: 192 rows) ==============
__device__ __forceinline__ void so_decode_full(int q, int& j1, int& j2, int& rb)
{
    int pp = q >> 6;
    rb = q & 63;
    j2 = (pp == 0) ? 1 : 2;
    j1 = (pp == 0) ? 0 : pp - 1;
}
__device__ __forceinline__ void so_decode_dec16(int q, int& j1, int& j2, int& rb)
{
    int pp = q >> 6;
    rb = q & 63;
    j2 = (pp < 3) ? 3 : 4;
    j1 = (pp < 3) ? pp : pp - 3;
}

__global__ __launch_bounds__(256)
void so_stage1(const __half2* __restrict__ Cw, __half2* __restrict__ Dh, int qbase)
{
    __shared__ float sre[16 * RSTR];
    __shared__ float sim[16 * RSTR];
    const int t = threadIdx.x;
    const int r = blockIdx.x >> 4;
    const int n10 = (blockIdx.x & 15) << 4;
    int j1, j2, rb;
    so_decode_full(qbase + r, j1, j2, rb);
    const float xi2 = 0.35f * exp2f(-(float)j2);
    const float invsig = 1.0f / (0.6f * xi2);
    const float kc = xi2 * (float)NN;
    const float Hh = 5.0f * (0.6f * xi2) * (float)NN;
    const int klo = (int)(kc - Hh), khi = (int)(kc + Hh) + 1;
    const int qm = (klo >= 0 && khi >= NN) ? 15 : quarter_mask(klo, khi);
    const size_t base = COFF[j1] + (size_t)rb * CWW[j1];
    const int lo = CLO[j1], Wd = CWW[j1];
#pragma unroll
    for (int it = 0; it < 16; ++it) {
        int i = t & 15, n2 = (it << 4) + (t >> 4);
        if (!(qm & (1 << (it >> 2)))) {
            sre[i * RSTR + SWZI(n2, i)] = 0.f;
            sim[i * RSTR + SWZI(n2, i)] = 0.f;
            continue;
        }
        int n = (n10 + i) + (n2 << 8);
        int ksg = (n < NN / 2) ? n : n - NN;
        float nsf = (float)ksg;
        float vr = 0.f, vi = 0.f;
        int idx = ksg - lo;
        if (fabsf(nsf - kc) <= Hh && idx >= 0 && idx < Wd) {
            float2 v = __half22float2(Cw[base + idx]);
            float a = (nsf * (1.0f / (float)NN) - xi2) * invsig;
            float wg = __expf(-0.5f * a * a) * (1.0f / 256.0f);
            vr = v.x * wg; vi = v.y * wg;
        }
        sre[i * RSTR + SWZI(n2, i)] = vr;
        sim[i * RSTR + SWZI(n2, i)] = vi;
    }
    __syncthreads();
    const int g = t >> 4, u = t & 15;
    fft256_soa<1, true, 0, false, 0, 0>(sre + g * RSTR, sim + g * RSTR, u, n10 + g,
                                        TWO_PI / (float)NN, 1.f, g & 12, qm);
    __syncthreads();
#pragma unroll
    for (int it = 0; it < 16; ++it) {
        int flat = it * 256 + t;
        int i = flat & 15, k2 = flat >> 4;
        int s = i * RSTR + SWZI(k2, i);
        Dh[(size_t)r * NN + (k2 << 8) + (n10 + i)] = __floats2half2_rn(sre[s], sim[s]);
    }
}

__global__ __launch_bounds__(256)
void so_stage2(const __half2* __restrict__ Dh, float* __restrict__ S2acc, int qbase)
{
    __shared__ float sre[16 * RSTR];
    __shared__ float sim[16 * RSTR];
    __shared__ float wtab[16][8];
    const int t = threadIdx.x;
    const int r = blockIdx.x >> 4;
    const int k20 = (blockIdx.x & 15) << 4;
#pragma unroll
    for (int it = 0; it < 16; ++it) {
        float2 v = __half22float2(Dh[(size_t)r * NN + ((size_t)(k20 + it) << 8) + t]);
        sre[it * RSTR + SWZI(t, it)] = v.x;
        sim[it * RSTR + SWZI(t, it)] = v.y;
    }
    if (t < 128) {
        int fi = t >> 3, dd = (t & 7) - 4;
        int w = k20 + fi + (dd << 8) + 768;
        float val = 0.f;
        if (w >= 0 && w <= 1536) {
            float m = (float)(w - 768);
            val = 0.003426963f * __expf(-3.690276e-5f * m * m);
        }
        wtab[fi][t & 7] = val;
    }
    __syncthreads();
    const int g = t >> 4, u = t & 15;
    fft256_soa<1, false, 2, false, 4, 3>(sre + g * RSTR, sim + g * RSTR, u, 0, 0.f, 1.f, g & 12, 15);
    __syncthreads();
    float acc = 0.f;
#pragma unroll
    for (int fi = 0; fi < 16; ++fi) {
        const float* row = sim + fi * RSTR;
#pragma unroll
        for (int dd = 0; dd < 8; ++dd)
            acc = fmaf(row[t + dd], wtab[fi][dd], acc);
    }
    atomicAdd(&S2acc[(size_t)(qbase + r) * 256 + t], acc * (1.0f / 256.0f));
}

// ============== decimated M=16384 (s=4, L=64) ==============
// MODE 1 = fo (XF*psi1, j1=2,3,4), MODE 2 = so (Cw*psi2, j2=3,4)
template<int MODE>
__global__ __launch_bounds__(256)
void dec16_s1(const float2* __restrict__ XF, const __half2* __restrict__ Cw,
              __half2* __restrict__ Dh16, int qbase)
{
    __shared__ float sre[64 * 64];
    __shared__ float sim[64 * 64];
    __shared__ float twt[96];
    const int t = threadIdx.x;
    const int r = blockIdx.x >> 2;
    const int c0 = (blockIdx.x & 3) << 6;
    const int q = qbase + r;
    float xi, invsig, kc, Hh; int srow = 0; size_t cbase = 0; int lo = 0, Wd = 0, ring = 0;
    if (MODE == 1) {
        int j1 = 2 + (q >> 6); int ql = q & 63; srow = ql >> 3;
        int lam = j1 * 8 + (ql & 7);
        xi = 0.35f * exp2f(-(float)lam * 0.125f);
        invsig = 8.0f / xi; kc = xi * (float)NN; Hh = 6.10f * (xi * 0.125f) * (float)NN;
    } else {
        int j1, j2, rb;
        so_decode_dec16(q, j1, j2, rb);
        xi = 0.35f * exp2f(-(float)j2);
        invsig = 1.0f / (0.6f * xi); kc = xi * (float)NN;
        Hh = fminf(6.10f * (0.6f * xi) * (float)NN, 7967.0f);
        cbase = COFF[j1] + (size_t)rb * CWW[j1]; lo = CLO[j1]; Wd = CWW[j1]; ring = CRING[j1];
    }
    build_tw6(twt, t);
    const int klo = (int)ceilf(kc - Hh);
#pragma unroll
    for (int it = 0; it < 16; ++it) {
        int flat = it * 256 + t;
        int c = flat & 63, n2 = flat >> 6;
        int kap = (c0 + c) + (n2 << 8);
        int kk = klo + (int)(((unsigned)(kap - klo)) & 16383u);
        float vr = 0.f, vi = 0.f;
        if (fabsf((float)kk - kc) <= Hh) {
            float2 v;
            bool ok = true;
            if (MODE == 1) v = XF[(size_t)srow * NN + (kk & (NN - 1))];
            else {
                int idx;
                if (ring) idx = (kk - lo) & (Wd - 1);
                else { idx = kk - lo; ok = (idx >= 0 && idx < Wd); }
                v = ok ? __half22float2(Cw[cbase + idx]) : make_float2(0.f, 0.f);
            }
            float a = ((float)kk * (1.0f / (float)NN) - xi) * invsig;
            float wg = __expf(-0.5f * a * a) * 0.015625f;
            vr = v.x * wg; vi = v.y * wg;
        }
        int p = rev64(n2);
        sre[(p << 6) + c] = vr;
        sim[(p << 6) + c] = vi;
    }
    lds_dit<64, 6, 64, 1, false>(sre, sim, twt, t, 256);
    // M-twiddle via per-thread rotation recurrence: angle = 2pi/16384 * row*(c0+c)
    {
        const int c = t & 63, r0 = t >> 6;
        float sA, cA, sD, cD;
        __sincosf((TWO_PI / 16384.0f) * (float)(r0 * (c0 + c)), &sA, &cA);
        __sincosf((TWO_PI / 16384.0f) * (float)(4 * (c0 + c)), &sD, &cD);
#pragma unroll
        for (int it = 0; it < 16; ++it) {
            int row = (it << 2) + r0;
            int a = (row << 6) + c;
            float rr = sre[a] * cA - sim[a] * sA;
            sim[a] = sre[a] * sA + sim[a] * cA; sre[a] = rr;
            float nc = cA * cD - sA * sD; sA = cA * sD + sA * cD; cA = nc;
        }
    }
    __syncthreads();
#pragma unroll
    for (int it = 0; it < 16; ++it) {
        int flat = it * 256 + t;
        int c = flat & 63, row = flat >> 6;
        Dh16[(size_t)r * 16384 + (row << 8) + (c0 + c)] =
            __floats2half2_rn(sre[(row << 6) + c], sim[(row << 6) + c]);
    }
}

__global__ __launch_bounds__(256)
void dec16_s2so(const __half2* __restrict__ Dh16, float* __restrict__ S2acc, int qbase)
{
    __shared__ float sre[16 * RSTR];
    __shared__ float sim[16 * RSTR];
    __shared__ float wtab[16][6];
    const int t = threadIdx.x;
    const int r = blockIdx.x >> 2;
    const int k2base = (blockIdx.x & 3) << 4;
#pragma unroll
    for (int it = 0; it < 16; ++it) {
        float2 v = __half22float2(Dh16[(size_t)r * 16384 + ((k2base + it) << 8) + t]);
        sre[it * RSTR + SWZI(t, it)] = v.x;
        sim[it * RSTR + SWZI(t, it)] = v.y;
    }
    if (t < 96) {
        int p = t / 6, dl = t % 6;
        float w = (float)(256 * (dl - 2) - 4 * (k2base + p));
        wtab[p][dl] = 0.003426963f * __expf(-3.690276e-5f * w * w);
    }
    __syncthreads();
    const int g = t >> 4, u = t & 15;
    fft256_soa<1, false, 2, false, 3, 2>(sre + g * RSTR, sim + g * RSTR, u, 0, 0.f,
                                         64.0f / (float)NN, g & 12, 15);
    __syncthreads();
    float acc = 0.f;
#pragma unroll
    for (int p = 0; p < 16; ++p) {
        const float* row = sim + p * RSTR;
#pragma unroll
        for (int dl = 0; dl < 6; ++dl)
            acc = fmaf(row[t + 5 - dl], wtab[p][dl], acc);
    }
    atomicAdd(&S2acc[(size_t)(192 + qbase + r) * 256 + t], acc * 4.0f);
}

__global__ __launch_bounds__(256)
void dec16_s2fo(const __half2* __restrict__ Dh16, __half2* __restrict__ D2h16)
{
    __shared__ float sre[16 * RSTR];
    __shared__ float sim[16 * RSTR];
    const int t = threadIdx.x;
    const int r = blockIdx.x >> 2;
    const int k2base = (blockIdx.x & 3) << 4;
#pragma unroll
    for (int it = 0; it < 16; ++it) {
        float2 v = __half22float2(Dh16[(size_t)r * 16384 + ((k2base + it) << 8) + t]);
        sre[it * RSTR + SWZI(t, it)] = v.x;
        sim[it * RSTR + SWZI(t, it)] = v.y;
    }
    __syncthreads();
    const int g = t >> 4, u = t & 15;
    float* rr = sre + g * RSTR; float* ri = sim + g * RSTR;
    fft256_soa<1, false, 1, false, 0, 0>(rr, ri, u, 0, 0.f, 256.0f / (float)NN, g & 12, 15);
    fft256_soa<-1, true, 0, true, 0, 0>(rr, ri, u, k2base + g, TWO_PI / 16384.0f, 1.f, g & 12, 15);
    __syncthreads();
#pragma unroll
    for (int it = 0; it < 16; ++it) {
        int a = it * RSTR + SWZI(t, it);
        D2h16[(size_t)r * 16384 + ((k2base + it) << 8) + t] = __floats2half2_rn(sre[a], sim[a]);
    }
}

__global__ __launch_bounds__(256)
void dec16_s3fo(const __half2* __restrict__ D2h16, __half2* __restrict__ Cw, int qbase)
{
    __shared__ float sre[64 * 64];
    __shared__ float sim[64 * 64];
    __shared__ float twt[96];
    const int t = threadIdx.x;
    const int r = blockIdx.x >> 2;
    const int c0 = (blockIdx.x & 3) << 6;
    const int q = qbase + r;
    const int j1 = 2 + (q >> 6), ql = q & 63;
    build_tw6(twt, t);
#pragma unroll
    for (int it = 0; it < 16; ++it) {
        int flat = it * 256 + t;
        int c = flat & 63, m2 = flat >> 6;
        float2 v = __half22float2(D2h16[(size_t)r * 16384 + (m2 << 8) + (c0 + c)]);
        sre[(m2 << 6) + c] = v.x;
        sim[(m2 << 6) + c] = v.y;
    }
    lds_dif<64, 6, 64, -1, false>(sre, sim, twt, t, 256);
    const int lo = CLO[j1];
    const size_t rbase = COFF[j1] + (size_t)ql * 16384;
#pragma unroll
    for (int it = 0; it < 16; ++it) {
        int flat = it * 256 + t;
        int c = flat & 63, p = flat >> 6;
        int kap = (c0 + c) + (rev64(p) << 8);
        int ks = (kap < 8192) ? kap : kap - 16384;
        int idx = (ks - lo) & 16383;
        int a = (p << 6) + c;
        Cw[rbase + idx] = __floats2half2_rn(sre[a], sim[a]);
    }
}

// ============== decimated M=4096 (s=16, L=16) — single-kernel ==============
__global__ __launch_bounds__(256)
void m4k_fo(const float2* __restrict__ XF, __half2* __restrict__ Cw)
{
    __shared__ float sre[16 * RSTR];
    __shared__ float sim[16 * RSTR];
    __shared__ float twt[96];
    const int t = threadIdx.x;
    const int q = blockIdx.x;
    const int j1 = 5 + (q >> 6), ql = q & 63;
    const int srow = ql >> 3;
    const int lam = j1 * 8 + (ql & 7);
    const float xi = 0.35f * exp2f(-(float)lam * 0.125f);
    const float invsig = 8.0f / xi;
    const float kc = xi * (float)NN;
    const float Hh = 6.10f * (xi * 0.125f) * (float)NN;
    const int klo = (int)ceilf(kc - Hh);
    build_tw6(twt, t);
#pragma unroll
    for (int it = 0; it < 16; ++it) {
        int kap = t + (it << 8);
        int kk = klo + (int)(((unsigned)(kap - klo)) & 4095u);
        float vr = 0.f, vi = 0.f;
        if (fabsf((float)kk - kc) <= Hh) {
            float2 v = XF[(size_t)srow * NN + (kk & (NN - 1))];
            float a = ((float)kk * (1.0f / (float)NN) - xi) * invsig;
            float wg = __expf(-0.5f * a * a);
            vr = v.x * wg; vi = v.y * wg;
        }
        int p = rev16(it);
        sre[p * RSTR + SWZI(t, p)] = vr;
        sim[p * RSTR + SWZI(t, p)] = vi;
    }
    lds_dit<16, 8, RSTR, 1, true>(sre, sim, twt, t, 256);
    {   // twiddle: angle = 2pi/4096 * it * t, recurrence over it
        float sD, cD; __sincosf((TWO_PI / 4096.0f) * (float)t, &sD, &cD);
        float cA = 1.f, sA = 0.f;
#pragma unroll
        for (int it = 0; it < 16; ++it) {
            int a = it * RSTR + SWZI(t, it);
            float rr = sre[a] * cA - sim[a] * sA;
            sim[a] = sre[a] * sA + sim[a] * cA; sre[a] = rr;
            float nc = cA * cD - sA * sD; sA = cA * sD + sA * cD; cA = nc;
        }
    }
    __syncthreads();
    const int g = t >> 4, u = t & 15;
    float* rr = sre + g * RSTR; float* ri = sim + g * RSTR;
    fft256_soa<1, false, 1, false, 0, 0>(rr, ri, u, 0, 0.f, 16.0f / (float)NN, g & 12, 15);
    fft256_soa<-1, true, 0, true, 0, 0>(rr, ri, u, g, TWO_PI / 4096.0f, 1.f, g & 12, 15);
    lds_dif<16, 8, RSTR, -1, true>(sre, sim, twt, t, 256);
    const int lo = CLO[j1];
    const size_t rbase = COFF[j1] + (size_t)ql * 4096;
#pragma unroll
    for (int it = 0; it < 16; ++it) {
        int kap = t + (rev16(it) << 8);
        int ks = (kap < 2048) ? kap : kap - 4096;
        int idx = (ks - lo) & 4095;
        int a = it * RSTR + SWZI(t, it);
        Cw[rbase + idx] = __floats2half2_rn(sre[a], sim[a]);
    }
}

// m4k second order: j2 = 5,6,7 (1152 rows), direct output
__global__ __launch_bounds__(256)
void m4k_so(const __half2* __restrict__ Cw, float* __restrict__ out)
{
    __shared__ float sre[16 * RSTR];
    __shared__ float sim[16 * RSTR];
    __shared__ float wtab[16][6];
    __shared__ float twt[96];
    const int t = threadIdx.x;
    const int q = blockIdx.x;
    const int pp = q >> 6, rb = q & 63;
    int j1, j2;
    if (pp < 5)       { j2 = 5; j1 = pp; }
    else if (pp < 11) { j2 = 6; j1 = pp - 5; }
    else              { j2 = 7; j1 = pp - 11; }
    const float xi2 = 0.35f * exp2f(-(float)j2);
    const float invsig = 1.0f / (0.6f * xi2);
    const float kc = xi2 * (float)NN;
    const float Hh = fminf(6.10f * (0.6f * xi2) * (float)NN, 1823.0f);
    const int klo = (int)ceilf(kc - Hh);
    const size_t cbase = COFF[j1] + (size_t)rb * CWW[j1];
    const int lo = CLO[j1], Wd = CWW[j1], ring = CRING[j1];
    build_tw6(twt, t);
#pragma unroll
    for (int it = 0; it < 16; ++it) {
        int kap = t + (it << 8);
        int kk = klo + (int)(((unsigned)(kap - klo)) & 4095u);
        float vr = 0.f, vi = 0.f;
        if (fabsf((float)kk - kc) <= Hh) {
            int idx; bool ok = true;
            if (ring) idx = (kk - lo) & (Wd - 1);
            else { idx = kk - lo; ok = (idx >= 0 && idx < Wd); }
            if (ok) {
                float2 v = __half22float2(Cw[cbase + idx]);
                float a = ((float)kk * (1.0f / (float)NN) - xi2) * invsig;
                float wg = __expf(-0.5f * a * a);
                vr = v.x * wg; vi = v.y * wg;
            }
        }
        int p = rev16(it);
        sre[p * RSTR + SWZI(t, p)] = vr;
        sim[p * RSTR + SWZI(t, p)] = vi;
    }
    if (t < 96) {
        int p = t / 6, dl = t % 6;
        float w = (float)(256 * (dl - 2) - 16 * p);
        wtab[p][dl] = 0.003426963f * __expf(-3.690276e-5f * w * w);
    }
    lds_dit<16, 8, RSTR, 1, true>(sre, sim, twt, t, 256);
    {
        float sD, cD; __sincosf((TWO_PI / 4096.0f) * (float)t, &sD, &cD);
        float cA = 1.f, sA = 0.f;
#pragma unroll
        for (int it = 0; it < 16; ++it) {
            int a = it * RSTR + SWZI(t, it);
            float rr = sre[a] * cA - sim[a] * sA;
            sim[a] = sre[a] * sA + sim[a] * cA; sre[a] = rr;
            float nc = cA * cD - sA * sD; sA = cA * sD + sA * cD; cA = nc;
        }
    }
    __syncthreads();
    const int g = t >> 4, u = t & 15;
    fft256_soa<1, false, 2, false, 3, 2>(sre + g * RSTR, sim + g * RSTR, u, 0, 0.f,
                                         1.0f / (float)NN, g & 12, 15);
    __syncthreads();
    float acc = 0.f;
#pragma unroll
    for (int p = 0; p < 16; ++p) {
        const float* row = sim + p * RSTR;
#pragma unroll
        for (int dl = 0; dl < 6; ++dl)
            acc = fmaf(row[t + 5 - dl], wtab[p][dl], acc);
    }
    acc *= 16.0f;
    const int b = rb >> 3;
    const int chan = 65 + 4 * j2 * (j2 - 1) + j1 * 8 + (rb & 7);
    float mag = sqrtf(fmaf(acc, acc, 1e-8f));
    out[((size_t)b * 289 + chan) * 256 + t] = logf(mag + 1e-8f);
}

__global__ __launch_bounds__(256)
void s2final(const float* __restrict__ S2acc, float* __restrict__ out)
{
    const int q = blockIdx.x, n = threadIdx.x;
    int j1, j2, rb;
    if (q < 192) so_decode_full(q, j1, j2, rb);
    else         so_decode_dec16(q - 192, j1, j2, rb);
    const int b = rb >> 3;
    const int chan = 65 + 4 * j2 * (j2 - 1) + j1 * 8 + (rb & 7);
    float s = S2acc[(size_t)q * 256 + n];
    float mag = sqrtf(fmaf(s, s, 1e-8f));
    out[((size_t)b * 289 + chan) * 256 + n] = logf(mag + 1e-8f);
}

__global__ void zero2_kernel(float* a, int na, float* b, int nb)
{
    int i = blockIdx.x * 256 + threadIdx.x;
    if (i < na) a[i] = 0.f;
    else if (i < na + nb) b[i - na] = 0.f;
}

extern "C" void kernel_launch(void* const* d_in, const int* in_sizes, int n_in,
                              void* d_out, int out_size, void* d_ws, size_t ws_size,
                              hipStream_t stream)
{
    const float* x = (const float*)d_in[0];
    float* out = (float*)d_out;
    char* ws = (char*)d_ws;

    size_t off = 0;
    float2*  XF    = (float2*)ws;                 off += 8ul * NN * 8;
    __half2* Cw    = (__half2*)(ws + off);        off += CTOT * 4ul;
    float*   S2acc = (float*)(ws + off);          off += 640ul * 256 * 4;
    off = (off + 255) & ~255ul;
    char* reg0 = ws + off;
    size_t avail = (ws_size > off) ? (ws_size - off) : 0;

    int CHB = (int)(avail / (512ul * 1024));  if (CHB > 128) CHB = 128;  if (CHB < 1) CHB = 1;
    int CHD = (int)(avail / (256ul * 1024));  if (CHD > 192) CHD = 192;  if (CHD < 1) CHD = 1;
    int CHE = (int)(avail / (128ul * 1024));  if (CHE > 192) CHE = 192;  if (CHE < 1) CHE = 1;
    int CHF = (int)(avail / (64ul * 1024));   if (CHF > 448) CHF = 448;  if (CHF < 1) CHF = 1;

    {
        int nz = 8 * 289 * 256;
        int na = 640 * 256;
        zero2_kernel<<<(nz + na + 255) / 256, 256, 0, stream>>>(out + nz, nz, S2acc, na);
    }

    // XF = fft(x)
    {
        float2* Df = (float2*)reg0;
        xf_stage1<<<8 * 16, 256, 0, stream>>>(x, Df);
        xf_stage2<<<8 * 16, 256, 0, stream>>>(Df, XF);
    }

    // first order FULL (j1 = 0,1 : 128 rows)
    for (int cs = 0; cs < 128; cs += CHB) {
        int m = (128 - cs < CHB) ? (128 - cs) : CHB;
        __half2* DhB = (__half2*)reg0;
        __half2* D2h = DhB + (size_t)CHB * NN;
        fo_stage1<<<m * 16, 256, 0, stream>>>(XF, DhB, cs);
        fo_mid<<<m * 16, 256, 0, stream>>>(DhB, D2h);
        fo_stage2<<<m * 16, 256, 0, stream>>>(D2h, Cw, cs);
    }
    // first order M=16384 (j1 = 2,3,4 : 192 rows)
    for (int cs = 0; cs < 192; cs += CHE) {
        int m = (192 - cs < CHE) ? (192 - cs) : CHE;
        __half2* Dh16  = (__half2*)reg0;
        __half2* D2h16 = Dh16 + (size_t)CHE * 16384;
        dec16_s1<1><<<m * 4, 256, 0, stream>>>(XF, Cw, Dh16, cs);
        dec16_s2fo<<<m * 4, 256, 0, stream>>>(Dh16, D2h16);
        dec16_s3fo<<<m * 4, 256, 0, stream>>>(D2h16, Cw, cs);
    }
    // first order M=4096 (j1 = 5..7)
    m4k_fo<<<192, 256, 0, stream>>>(XF, Cw);

    // S0 + S1
    sfold_all<<<8 + 512, 256, 0, stream>>>(XF, Cw, out);

    // second order FULL (j2 = 1,2 : 192 rows)
    for (int qs = 0; qs < 192; qs += CHD) {
        int m = (192 - qs < CHD) ? (192 - qs) : CHD;
        __half2* DhS = (__half2*)reg0;
        so_stage1<<<m * 16, 256, 0, stream>>>(Cw, DhS, qs);
        so_stage2<<<m * 16, 256, 0, stream>>>(DhS, S2acc, qs);
    }
    // second order M=16384 (j2 = 3,4 : 448 rows)
    for (int qs = 0; qs < 448; qs += CHF) {
        int m = (448 - qs < CHF) ? (448 - qs) : CHF;
        __half2* Dh16 = (__half2*)reg0;
        dec16_s1<2><<<m * 4, 256, 0, stream>>>(XF, Cw, Dh16, qs);
        dec16_s2so<<<m * 4, 256, 0, stream>>>(Dh16, S2acc, qs);
    }
    // second order M=4096 (j2 = 5,6,7 : 1152 rows)
    m4k_so<<<1152, 256, 0, stream>>>(Cw, out);

    s2final<<<640, 256, 0, stream>>>(S2acc, out);
}

// Round 9
// 257.842 us; speedup vs baseline: 10.9592x; 1.1948x over previous
//
#include <hip/hip_runtime.h>
#include <hip/hip_fp16.h>
#include <math.h>

#define NN 65536
#define TWO_PI 6.283185307179586f
#define RSTR 264
#define SWZ(m) ((m) ^ (((m) >> 4) & 15))
#define SWZI(m, r) (SWZ(m) ^ ((r) & 12))
#define CTOT 10829824ul

__constant__ int CLO[8]  = {-32768, -15360, -5376, -8192, -8192, -2048, -2048, -2048};
__constant__ int CWW[8]  = {65536, 42240, 16384, 16384, 16384, 4096, 4096, 4096};
__constant__ int CRING[8] = {0, 0, 1, 1, 1, 1, 1, 1};
__constant__ unsigned long COFF[8] = {0ul, 4194304ul, 6897664ul, 7946240ul,
                                      8994816ul, 10043392ul, 10305536ul, 10567680ul};

__device__ __forceinline__ void lds_fence() {
    asm volatile("s_waitcnt lgkmcnt(0)" ::: "memory");
}
__device__ __forceinline__ int rev16(int p) { return ((p & 3) << 2) | (p >> 2); }
__device__ __forceinline__ int rev64(int p) { return ((p & 3) << 4) | (p & 12) | (p >> 4); }

__device__ __forceinline__ int quarter_mask(int klo, int khi)
{
    int qm = 0;
#pragma unroll
    for (int qq = 0; qq < 4; ++qq) {
        int lo_q = 16384 * qq - 255;
        int hi_q = 16384 * qq + 16639;
        bool act;
        if (klo >= 0) act = (hi_q >= klo) && (lo_q <= khi);
        else          act = (lo_q <= khi) || (hi_q >= klo + NN);
        if (act) qm |= (1 << qq);
    }
    return qm;
}

__device__ __forceinline__ void build_tw6(float* twt, int t)
{
    if (t < 16) {
        float s1, c1; __sincosf((TWO_PI / 64.0f) * (float)t, &s1, &c1);
        float c2 = c1 * c1 - s1 * s1, s2 = 2.f * c1 * s1;
        float c3 = c2 * c1 - s2 * s1, s3 = c2 * s1 + s2 * c1;
        float* e = twt + 6 * t;
        e[0] = c1; e[1] = s1; e[2] = c2; e[3] = s2; e[4] = c3; e[5] = s3;
    }
}

template<int SIGN>
__device__ __forceinline__ void fft16(float* xr, float* xi, float* yr, float* yi)
{
    const float S = (SIGN > 0) ? 1.0f : -1.0f;
    const float C8 = 0.92387953251f, S8 = 0.38268343236f, R2 = 0.70710678119f;
#pragma unroll
    for (int n0 = 0; n0 < 4; ++n0) {
        float z0r=xr[n0],    z0i=xi[n0];
        float z1r=xr[n0+4],  z1i=xi[n0+4];
        float z2r=xr[n0+8],  z2i=xi[n0+8];
        float z3r=xr[n0+12], z3i=xi[n0+12];
        float t0r=z0r+z2r, t0i=z0i+z2i;
        float t1r=z0r-z2r, t1i=z0i-z2i;
        float t2r=z1r+z3r, t2i=z1i+z3i;
        float t3r=S*(z1r-z3r), t3i=S*(z1i-z3i);
        xr[n0]=t0r+t2r;      xi[n0]=t0i+t2i;
        xr[n0+4]=t1r-t3i;    xi[n0+4]=t1i+t3r;
        xr[n0+8]=t0r-t2r;    xi[n0+8]=t0i-t2i;
        xr[n0+12]=t1r+t3i;   xi[n0+12]=t1i-t3r;
    }
    {
        const float W1r=C8,  W1i=S*S8;
        const float W2r=R2,  W2i=S*R2;
        const float W3r=S8,  W3i=S*C8;
        const float W6r=-R2, W6i=S*R2;
        const float W9r=-C8, W9i=-S*S8;
#define TWID(idx, wr, wi) { float ar=xr[idx], ai=xi[idx]; xr[idx]=ar*(wr)-ai*(wi); xi[idx]=ar*(wi)+ai*(wr); }
        TWID(5,W1r,W1i)  TWID(9,W2r,W2i)   TWID(13,W3r,W3i)
        TWID(6,W2r,W2i)  { float ar=xr[10], ai=xi[10]; xr[10]=-S*ai; xi[10]=S*ar; } TWID(14,W6r,W6i)
        TWID(7,W3r,W3i)  TWID(11,W6r,W6i)  TWID(15,W9r,W9i)
#undef TWID
    }
#pragma unroll
    for (int p = 0; p < 4; ++p) {
        float z0r=xr[4*p],   z0i=xi[4*p];
        float z1r=xr[4*p+1], z1i=xi[4*p+1];
        float z2r=xr[4*p+2], z2i=xi[4*p+2];
        float z3r=xr[4*p+3], z3i=xi[4*p+3];
        float t0r=z0r+z2r, t0i=z0i+z2i;
        float t1r=z0r-z2r, t1i=z0i-z2i;
        float t2r=z1r+z3r, t2i=z1i+z3i;
        float t3r=S*(z1r-z3r), t3i=S*(z1i-z3i);
        yr[p]=t0r+t2r;     yi[p]=t0i+t2i;
        yr[p+4]=t1r-t3i;   yi[p+4]=t1i+t3r;
        yr[p+8]=t0r-t2r;   yi[p+8]=t0i-t2i;
        yr[p+12]=t1r+t3i;  yi[p+12]=t1i-t3r;
    }
}

template<int SIGN, bool BIGTW, int OUT, bool INREAL, int PADL, int PADR>
__device__ __forceinline__ void fft256_soa(float* rr, float* ri, int u, int n1,
                                           float twrate, float mscale, int cxor, int qmask)
{
    float xr[16], xi[16], yr[16], yi[16];
#pragma unroll
    for (int qq = 0; qq < 4; ++qq) {
        if (qmask & (1 << qq)) {
#pragma unroll
            for (int j = 0; j < 4; ++j) {
                int b = qq * 4 + j;
                int s = SWZ(u + (b << 4)) ^ cxor;
                xr[b] = rr[s];
                xi[b] = INREAL ? 0.f : ri[s];
            }
        } else {
#pragma unroll
            for (int j = 0; j < 4; ++j) { xr[qq * 4 + j] = 0.f; xi[qq * 4 + j] = 0.f; }
        }
    }
    fft16<SIGN>(xr, xi, yr, yi);
    float sa, ca;
    __sincosf((float)SIGN * (TWO_PI / 256.0f) * (float)u, &sa, &ca);
    float twr = 1.f, twi = 0.f;
#pragma unroll
    for (int c = 0; c < 16; ++c) {
        int s = SWZ((c << 4) + u) ^ cxor;
        rr[s] = yr[c] * twr - yi[c] * twi;
        ri[s] = yr[c] * twi + yi[c] * twr;
        float nr = twr * ca - twi * sa; twi = twr * sa + twi * ca; twr = nr;
    }
    lds_fence();
#pragma unroll
    for (int a = 0; a < 16; ++a) {
        int s = SWZ((u << 4) + a) ^ cxor;
        xr[a] = rr[s]; xi[a] = ri[s];
    }
    fft16<SIGN>(xr, xi, yr, yi);
    float tbr = 1.f, tbi = 0.f, str = 1.f, sti = 0.f;
    if (BIGTW) {
        float s0, c0, s1, c1;
        __sincosf((float)SIGN * twrate * (float)(n1 * u), &s0, &c0);
        __sincosf((float)SIGN * twrate * (float)(n1 << 4), &s1, &c1);
        tbr = c0; tbi = s0; str = c1; sti = s1;
    }
#pragma unroll
    for (int d = 0; d < 16; ++d) {
        float vr = yr[d], vi = yi[d];
        if (BIGTW) {
            float pr = vr * tbr - vi * tbi, pi = vr * tbi + vi * tbr;
            vr = pr; vi = pi;
            float nr = tbr * str - tbi * sti; tbi = tbr * sti + tbi * str; tbr = nr;
        }
        int k = u + (d << 4);
        if (OUT == 1) {
            rr[SWZ(k) ^ cxor] = sqrtf(fmaf(vr, vr, vi * vi)) * mscale;
        } else if (OUT == 2) {
            float mag = sqrtf(fmaf(vr, vr, vi * vi)) * mscale;
            ri[PADL + k] = mag;
            if (k >= 256 - PADL) ri[k - (256 - PADL)] = mag;
            if (k < PADR) ri[PADL + 256 + k] = mag;
        } else {
            int s = SWZ(k) ^ cxor;
            rr[s] = vr; ri[s] = vi;
        }
    }
    lds_fence();
}

template<int L, int CLOG, int RST, int SIGN, bool SWZC>
__device__ __forceinline__ void lds_dit(float* re, float* im, const float* twt, int t, int T)
{
    const float S = (float)SIGN;
    const int NC = 1 << CLOG;
    const int nbf = NC * (L >> 2);
    for (int h = 1; h < L; h <<= 2) {
        __syncthreads();
        for (int i = t; i < nbf; i += T) {
            int c = i & (NC - 1);
            int bf = i >> CLOG;
            int j = bf & (h - 1);
            int q0 = ((bf - j) << 2) + j;
            int r0 = q0, r1 = q0 + h, r2 = q0 + 2 * h, r3 = q0 + 3 * h;
            int a0, a1, a2, a3;
            if (SWZC) {
                a0 = r0 * RST + SWZI(c, r0); a1 = r1 * RST + SWZI(c, r1);
                a2 = r2 * RST + SWZI(c, r2); a3 = r3 * RST + SWZI(c, r3);
            } else {
                a0 = r0 * RST + c; a1 = r1 * RST + c; a2 = r2 * RST + c; a3 = r3 * RST + c;
            }
            float x0r = re[a0], x0i = im[a0];
            float x1r = re[a1], x1i = im[a1];
            float x2r = re[a2], x2i = im[a2];
            float x3r = re[a3], x3i = im[a3];
            if (h > 1) {
                const float* e = twt + 6 * (j * (16 / h));
                float cj = e[0], sj = S * e[1];
                float c2 = e[2], s2 = S * e[3];
                float c3 = e[4], s3 = S * e[5];
                float r;
                r = x1r * cj - x1i * sj; x1i = x1r * sj + x1i * cj; x1r = r;
                r = x2r * c2 - x2i * s2; x2i = x2r * s2 + x2i * c2; x2r = r;
                r = x3r * c3 - x3i * s3; x3i = x3r * s3 + x3i * c3; x3r = r;
            }
            float t0r = x0r + x2r, t0i = x0i + x2i;
            float t1r = x0r - x2r, t1i = x0i - x2i;
            float t2r = x1r + x3r, t2i = x1i + x3i;
            float t3r = -S * (x1i - x3i), t3i = S * (x1r - x3r);
            re[a0] = t0r + t2r; im[a0] = t0i + t2i;
            re[a1] = t1r + t3r; im[a1] = t1i + t3i;
            re[a2] = t0r - t2r; im[a2] = t0i - t2i;
            re[a3] = t1r - t3r; im[a3] = t1i - t3i;
        }
    }
    __syncthreads();
}

template<int L, int CLOG, int RST, int SIGN, bool SWZC>
__device__ __forceinline__ void lds_dif(float* re, float* im, const float* twt, int t, int T)
{
    const float S = (float)SIGN;
    const int NC = 1 << CLOG;
    const int nbf = NC * (L >> 2);
    for (int h = L >> 2; h >= 1; h >>= 2) {
        __syncthreads();
        for (int i = t; i < nbf; i += T) {
            int c = i & (NC - 1);
            int bf = i >> CLOG;
            int j = bf & (h - 1);
            int q0 = ((bf - j) << 2) + j;
            int r0 = q0, r1 = q0 + h, r2 = q0 + 2 * h, r3 = q0 + 3 * h;
            int a0, a1, a2, a3;
            if (SWZC) {
                a0 = r0 * RST + SWZI(c, r0); a1 = r1 * RST + SWZI(c, r1);
                a2 = r2 * RST + SWZI(c, r2); a3 = r3 * RST + SWZI(c, r3);
            } else {
                a0 = r0 * RST + c; a1 = r1 * RST + c; a2 = r2 * RST + c; a3 = r3 * RST + c;
            }
            float x0r = re[a0], x0i = im[a0];
            float x1r = re[a1], x1i = im[a1];
            float x2r = re[a2], x2i = im[a2];
            float x3r = re[a3], x3i = im[a3];
            float t0r = x0r + x2r, t0i = x0i + x2i;
            float t1r = x0r - x2r, t1i = x0i - x2i;
            float t2r = x1r + x3r, t2i = x1i + x3i;
            float t3r = -S * (x1i - x3i), t3i = S * (x1r - x3r);
            float y1r = t1r + t3r, y1i = t1i + t3i;
            float y2r = t0r - t2r, y2i = t0i - t2i;
            float y3r = t1r - t3r, y3i = t1i - t3i;
            re[a0] = t0r + t2r; im[a0] = t0i + t2i;
            if (h > 1) {
                const float* e = twt + 6 * (j * (16 / h));
                float cj = e[0], sj = S * e[1];
                float c2 = e[2], s2 = S * e[3];
                float c3 = e[4], s3 = S * e[5];
                re[a1] = y1r * cj - y1i * sj; im[a1] = y1r * sj + y1i * cj;
                re[a2] = y2r * c2 - y2i * s2; im[a2] = y2r * s2 + y2i * c2;
                re[a3] = y3r * c3 - y3i * s3; im[a3] = y3r * s3 + y3i * c3;
            } else {
                re[a1] = y1r; im[a1] = y1i;
                re[a2] = y2r; im[a2] = y2i;
                re[a3] = y3r; im[a3] = y3i;
            }
        }
    }
    __syncthreads();
}

// ================= XF chain =================
__global__ __launch_bounds__(256)
void xf_stage1(const float* __restrict__ x, float2* __restrict__ D)
{
    __shared__ float sre[16 * RSTR];
    __shared__ float sim[16 * RSTR];
    const int t = threadIdx.x;
    const int r = blockIdx.x >> 4;
    const int n10 = (blockIdx.x & 15) << 4;
#pragma unroll
    for (int it = 0; it < 16; ++it) {
        int flat = it * 256 + t;
        int i = flat & 15, n2 = flat >> 4;
        int n = (n10 + i) + (n2 << 8);
        sre[i * RSTR + SWZI(n2, i)] = x[(size_t)r * NN + n];
        sim[i * RSTR + SWZI(n2, i)] = 0.f;
    }
    __syncthreads();
    const int g = t >> 4, u = t & 15;
    fft256_soa<-1, true, 0, false, 0, 0>(sre + g * RSTR, sim + g * RSTR, u, n10 + g,
                                         TWO_PI / (float)NN, 1.f, g & 12, 15);
    __syncthreads();
#pragma unroll
    for (int it = 0; it < 16; ++it) {
        int flat = it * 256 + t;
        int i = flat & 15, k2 = flat >> 4;
        int s = i * RSTR + SWZI(k2, i);
        D[(size_t)r * NN + (k2 << 8) + (n10 + i)] = make_float2(sre[s], sim[s]);
    }
}

__global__ __launch_bounds__(256)
void xf_stage2(const float2* __restrict__ D, float2* __restrict__ XF)
{
    __shared__ float sre[16 * RSTR];
    __shared__ float sim[16 * RSTR];
    const int t = threadIdx.x;
    const int r = blockIdx.x >> 4;
    const int k20 = (blockIdx.x & 15) << 4;
#pragma unroll
    for (int it = 0; it < 16; ++it) {
        float2 v = D[(size_t)r * NN + ((size_t)(k20 + it) << 8) + t];
        sre[it * RSTR + SWZI(t, it)] = v.x;
        sim[it * RSTR + SWZI(t, it)] = v.y;
    }
    __syncthreads();
    const int g = t >> 4, u = t & 15;
    fft256_soa<-1, false, 0, false, 0, 0>(sre + g * RSTR, sim + g * RSTR, u, 0, 0.f, 1.f, g & 12, 15);
    __syncthreads();
#pragma unroll
    for (int it = 0; it < 16; ++it) {
        int flat = it * 256 + t;
        int fi = flat & 15, k1 = flat >> 4;
        int s = fi * RSTR + SWZI(k1, fi);
        XF[(size_t)r * NN + (size_t)(k20 + fi) + ((size_t)k1 << 8)] = make_float2(sre[s], sim[s]);
    }
}

// ================= device bodies (shared-mem carved from sm) =================
__device__ void d_fo_stage1(float* sm, int t, int blk, const float2* __restrict__ XF,
                            __half2* __restrict__ Dh)
{
    float* sre = sm; float* sim = sm + 4224;
    const int r = blk >> 4;
    const int n10 = (blk & 15) << 4;
    const int q = r;
    const int j1 = q >> 6, ql = q & 63;
    const int srow = ql >> 3, w = ql & 7;
    const int lam = j1 * 8 + w;
    const float xi = 0.35f * exp2f(-(float)lam * 0.125f);
    const float invsig = 8.0f / xi;
    const float kc = xi * (float)NN;
    const float Hh = 5.0f * (xi * 0.125f) * (float)NN;
    const int klo = (int)(kc - Hh), khi = (int)(kc + Hh) + 1;
    const int qm = (khi >= NN) ? 15 : quarter_mask(klo, khi);
#pragma unroll
    for (int it = 0; it < 16; ++it) {
        int i = t & 15, n2 = (it << 4) + (t >> 4);
        if (!(qm & (1 << (it >> 2)))) {
            sre[i * RSTR + SWZI(n2, i)] = 0.f;
            sim[i * RSTR + SWZI(n2, i)] = 0.f;
            continue;
        }
        int n = (n10 + i) + (n2 << 8);
        float nsf = (float)((n < NN / 2) ? n : n - NN);
        float vr = 0.f, vi = 0.f;
        if (fabsf(nsf - kc) <= Hh) {
            float2 v = XF[(size_t)srow * NN + n];
            float a = (nsf * (1.0f / (float)NN) - xi) * invsig;
            float wg = __expf(-0.5f * a * a) * 0.0625f;
            vr = v.x * wg; vi = v.y * wg;
        }
        sre[i * RSTR + SWZI(n2, i)] = vr;
        sim[i * RSTR + SWZI(n2, i)] = vi;
    }
    __syncthreads();
    const int g = t >> 4, u = t & 15;
    fft256_soa<1, true, 0, false, 0, 0>(sre + g * RSTR, sim + g * RSTR, u, n10 + g,
                                        TWO_PI / (float)NN, 1.f, g & 12, qm);
    __syncthreads();
#pragma unroll
    for (int it = 0; it < 16; ++it) {
        int flat = it * 256 + t;
        int i = flat & 15, k2 = flat >> 4;
        int s = i * RSTR + SWZI(k2, i);
        Dh[(size_t)r * NN + (k2 << 8) + (n10 + i)] = __floats2half2_rn(sre[s], sim[s]);
    }
}

__device__ void d_fo_mid(float* sm, int t, int blk, const __half2* __restrict__ Dh,
                         __half2* __restrict__ D2h)
{
    float* sre = sm; float* sim = sm + 4224;
    const int r = blk >> 4;
    const int k20 = (blk & 15) << 4;
#pragma unroll
    for (int it = 0; it < 16; ++it) {
        float2 v = __half22float2(Dh[(size_t)r * NN + ((size_t)(k20 + it) << 8) + t]);
        sre[it * RSTR + SWZI(t, it)] = v.x;
        sim[it * RSTR + SWZI(t, it)] = v.y;
    }
    __syncthreads();
    const int g = t >> 4, u = t & 15;
    float* rr = sre + g * RSTR; float* ri = sim + g * RSTR;
    fft256_soa<1, false, 1, false, 0, 0>(rr, ri, u, 0, 0.f, 16.0f / (float)NN, g & 12, 15);
    fft256_soa<-1, true, 0, true, 0, 0>(rr, ri, u, k20 + g, TWO_PI / (float)NN, 1.f, g & 12, 15);
    __syncthreads();
#pragma unroll
    for (int it = 0; it < 16; ++it) {
        int flat = it * 256 + t;
        int i = flat & 15, k2 = flat >> 4;
        int s = i * RSTR + SWZI(k2, i);
        D2h[(size_t)r * NN + (k2 << 8) + (k20 + i)] = __floats2half2_rn(sre[s], sim[s]);
    }
}

__device__ void d_fo_stage2(float* sm, int t, int blk, const __half2* __restrict__ D2h,
                            __half2* __restrict__ Cw)
{
    float* sre = sm; float* sim = sm + 4224;
    const int r = blk >> 4;
    const int k20 = (blk & 15) << 4;
    const int j1 = r >> 6, ql = r & 63;
#pragma unroll
    for (int it = 0; it < 16; ++it) {
        float2 v = __half22float2(D2h[(size_t)r * NN + ((size_t)(k20 + it) << 8) + t]);
        sre[it * RSTR + SWZI(t, it)] = v.x;
        sim[it * RSTR + SWZI(t, it)] = v.y;
    }
    __syncthreads();
    const int g = t >> 4, u = t & 15;
    fft256_soa<-1, false, 0, false, 0, 0>(sre + g * RSTR, sim + g * RSTR, u, 0, 0.f, 1.f, g & 12, 15);
    __syncthreads();
    const size_t base = COFF[j1] + (size_t)ql * CWW[j1];
    const int lo = CLO[j1], Wd = CWW[j1];
#pragma unroll
    for (int it = 0; it < 16; ++it) {
        int flat = it * 256 + t;
        int fi = flat & 15, k1 = flat >> 4;
        int k = (k20 + fi) + (k1 << 8);
        int ksg = (k < NN / 2) ? k : k - NN;
        int idx = ksg - lo;
        if (idx >= 0 && idx < Wd) {
            int s = fi * RSTR + SWZI(k1, fi);
            Cw[base + idx] = __floats2half2_rn(sre[s], sim[s]);
        }
    }
}

__device__ void d_sfold(float* sm, int t, int blk, const float2* __restrict__ XF,
                        const __half2* __restrict__ Cw, float* __restrict__ out)
{
    float* Gr = sm; float* Gi = sm + 256;
    const float invsigphi = 731.428571f;
    float ar = 0.f, ai = 0.f;
    if (blk < 8) {
#pragma unroll
        for (int qq = -4; qq <= 4; ++qq) {
            int ks = t + (qq << 8);
            int k = ks & (NN - 1);
            float a = ((float)ks * (1.0f / (float)NN)) * invsigphi;
            float wg = __expf(-0.5f * a * a);
            float2 v = XF[(size_t)blk * NN + k];
            ar = fmaf(v.x, wg, ar); ai = fmaf(v.y, wg, ai);
        }
    } else {
        int q = blk - 8;
        int j1 = q >> 6, ql = q & 63;
        size_t base = COFF[j1] + (size_t)ql * CWW[j1];
        int lo = CLO[j1], Wd = CWW[j1], ring = CRING[j1];
#pragma unroll
        for (int qq = -4; qq <= 4; ++qq) {
            int ks = t + (qq << 8);
            float a = ((float)ks * (1.0f / (float)NN)) * invsigphi;
            float wg = __expf(-0.5f * a * a);
            int idx = ring ? ((ks - lo) & (Wd - 1)) : (ks - lo);
            float2 v = __half22float2(Cw[base + idx]);
            ar = fmaf(v.x, wg, ar); ai = fmaf(v.y, wg, ai);
        }
    }
    Gr[t] = ar; Gi[t] = ai;
    __syncthreads();
    float sb, cb;
    __sincosf((TWO_PI / 256.0f) * (float)t, &sb, &cb);
    float wr = 1.f, wi = 0.f, s = 0.f;
    for (int kk = 0; kk < 256; ++kk) {
        s = fmaf(Gr[kk], wr, s);
        s = fmaf(-Gi[kk], wi, s);
        float nr = wr * cb - wi * sb; wi = wr * sb + wi * cb; wr = nr;
    }
    s *= (1.0f / (float)NN);
    float mag = sqrtf(fmaf(s, s, 1e-8f));
    float val = logf(mag + 1e-8f);
    int b, chan;
    if (blk < 8) { b = blk; chan = 0; }
    else { int q = blk - 8; int j1 = q >> 6, ql = q & 63; b = ql >> 3; chan = 1 + j1 * 8 + (ql & 7); }
    out[((size_t)b * 289 + chan) * 256 + t] = val;
}

__device__ __forceinline__ void so_decode_full(int q, int& j1, int& j2, int& rb)
{
    int pp = q >> 6;
    rb = q & 63;
    j2 = (pp == 0) ? 1 : 2;
    j1 = (pp == 0) ? 0 : pp - 1;
}
__device__ __forceinline__ void so_decode_dec16(int q, int& j1, int& j2, int& rb)
{
    int pp = q >> 6;
    rb = q & 63;
    j2 = (pp < 3) ? 3 : 4;
    j1 = (pp < 3) ? pp : pp - 3;
}

__device__ void d_so_stage1(float* sm, int t, int blk, const __half2* __restrict__ Cw,
                            __half2* __restrict__ Dh)
{
    float* sre = sm; float* sim = sm + 4224;
    const int r = blk >> 4;
    const int n10 = (blk & 15) << 4;
    int j1, j2, rb;
    so_decode_full(r, j1, j2, rb);
    const float xi2 = 0.35f * exp2f(-(float)j2);
    const float invsig = 1.0f / (0.6f * xi2);
    const float kc = xi2 * (float)NN;
    const float Hh = 5.0f * (0.6f * xi2) * (float)NN;
    const int klo = (int)(kc - Hh), khi = (int)(kc + Hh) + 1;
    const int qm = (klo >= 0 && khi >= NN) ? 15 : quarter_mask(klo, khi);
    const size_t base = COFF[j1] + (size_t)rb * CWW[j1];
    const int lo = CLO[j1], Wd = CWW[j1];
#pragma unroll
    for (int it = 0; it < 16; ++it) {
        int i = t & 15, n2 = (it << 4) + (t >> 4);
        if (!(qm & (1 << (it >> 2)))) {
            sre[i * RSTR + SWZI(n2, i)] = 0.f;
            sim[i * RSTR + SWZI(n2, i)] = 0.f;
            continue;
        }
        int n = (n10 + i) + (n2 << 8);
        int ksg = (n < NN / 2) ? n : n - NN;
        float nsf = (float)ksg;
        float vr = 0.f, vi = 0.f;
        int idx = ksg - lo;
        if (fabsf(nsf - kc) <= Hh && idx >= 0 && idx < Wd) {
            float2 v = __half22float2(Cw[base + idx]);
            float a = (nsf * (1.0f / (float)NN) - xi2) * invsig;
            float wg = __expf(-0.5f * a * a) * (1.0f / 256.0f);
            vr = v.x * wg; vi = v.y * wg;
        }
        sre[i * RSTR + SWZI(n2, i)] = vr;
        sim[i * RSTR + SWZI(n2, i)] = vi;
    }
    __syncthreads();
    const int g = t >> 4, u = t & 15;
    fft256_soa<1, true, 0, false, 0, 0>(sre + g * RSTR, sim + g * RSTR, u, n10 + g,
                                        TWO_PI / (float)NN, 1.f, g & 12, qm);
    __syncthreads();
#pragma unroll
    for (int it = 0; it < 16; ++it) {
        int flat = it * 256 + t;
        int i = flat & 15, k2 = flat >> 4;
        int s = i * RSTR + SWZI(k2, i);
        Dh[(size_t)r * NN + (k2 << 8) + (n10 + i)] = __floats2half2_rn(sre[s], sim[s]);
    }
}

__device__ void d_so_stage2(float* sm, int t, int blk, const __half2* __restrict__ Dh,
                            float* __restrict__ S2acc)
{
    float* sre = sm; float* sim = sm + 4224;
    float* wtab = sm + 8448;   // [16][8]
    const int r = blk >> 4;
    const int k20 = (blk & 15) << 4;
#pragma unroll
    for (int it = 0; it < 16; ++it) {
        float2 v = __half22float2(Dh[(size_t)r * NN + ((size_t)(k20 + it) << 8) + t]);
        sre[it * RSTR + SWZI(t, it)] = v.x;
        sim[it * RSTR + SWZI(t, it)] = v.y;
    }
    if (t < 128) {
        int fi = t >> 3, dd = (t & 7) - 4;
        int w = k20 + fi + (dd << 8) + 768;
        float val = 0.f;
        if (w >= 0 && w <= 1536) {
            float m = (float)(w - 768);
            val = 0.003426963f * __expf(-3.690276e-5f * m * m);
        }
        wtab[fi * 8 + (t & 7)] = val;
    }
    __syncthreads();
    const int g = t >> 4, u = t & 15;
    fft256_soa<1, false, 2, false, 4, 3>(sre + g * RSTR, sim + g * RSTR, u, 0, 0.f, 1.f, g & 12, 15);
    __syncthreads();
    float acc = 0.f;
#pragma unroll
    for (int fi = 0; fi < 16; ++fi) {
        const float* row = sim + fi * RSTR;
#pragma unroll
        for (int dd = 0; dd < 8; ++dd)
            acc = fmaf(row[t + dd], wtab[fi * 8 + dd], acc);
    }
    atomicAdd(&S2acc[(size_t)r * 256 + t], acc * (1.0f / 256.0f));
}

template<int MODE>
__device__ void d_dec16_s1(float* sm, int t, int blk, const float2* __restrict__ XF,
                           const __half2* __restrict__ Cw, __half2* __restrict__ Dh16)
{
    float* sre = sm; float* sim = sm + 4096; float* twt = sm + 8192;
    const int r = blk >> 2;
    const int c0 = (blk & 3) << 6;
    const int q = r;
    float xi, invsig, kc, Hh; int srow = 0; size_t cbase = 0; int lo = 0, Wd = 0, ring = 0;
    if (MODE == 1) {
        int j1 = 2 + (q >> 6); int ql = q & 63; srow = ql >> 3;
        int lam = j1 * 8 + (ql & 7);
        xi = 0.35f * exp2f(-(float)lam * 0.125f);
        invsig = 8.0f / xi; kc = xi * (float)NN; Hh = 6.10f * (xi * 0.125f) * (float)NN;
    } else {
        int j1, j2, rb;
        so_decode_dec16(q, j1, j2, rb);
        xi = 0.35f * exp2f(-(float)j2);
        invsig = 1.0f / (0.6f * xi); kc = xi * (float)NN;
        Hh = fminf(6.10f * (0.6f * xi) * (float)NN, 7967.0f);
        cbase = COFF[j1] + (size_t)rb * CWW[j1]; lo = CLO[j1]; Wd = CWW[j1]; ring = CRING[j1];
    }
    build_tw6(twt, t);
    const int klo = (int)ceilf(kc - Hh);
#pragma unroll
    for (int it = 0; it < 16; ++it) {
        int flat = it * 256 + t;
        int c = flat & 63, n2 = flat >> 6;
        int kap = (c0 + c) + (n2 << 8);
        int kk = klo + (int)(((unsigned)(kap - klo)) & 16383u);
        float vr = 0.f, vi = 0.f;
        if (fabsf((float)kk - kc) <= Hh) {
            float2 v;
            bool ok = true;
            if (MODE == 1) v = XF[(size_t)srow * NN + (kk & (NN - 1))];
            else {
                int idx;
                if (ring) idx = (kk - lo) & (Wd - 1);
                else { idx = kk - lo; ok = (idx >= 0 && idx < Wd); }
                v = ok ? __half22float2(Cw[cbase + idx]) : make_float2(0.f, 0.f);
            }
            float a = ((float)kk * (1.0f / (float)NN) - xi) * invsig;
            float wg = __expf(-0.5f * a * a) * 0.015625f;
            vr = v.x * wg; vi = v.y * wg;
        }
        int p = rev64(n2);
        sre[(p << 6) + c] = vr;
        sim[(p << 6) + c] = vi;
    }
    lds_dit<64, 6, 64, 1, false>(sre, sim, twt, t, 256);
    {
        const int c = t & 63, r0 = t >> 6;
        float sA, cA, sD, cD;
        __sincosf((TWO_PI / 16384.0f) * (float)(r0 * (c0 + c)), &sA, &cA);
        __sincosf((TWO_PI / 16384.0f) * (float)(4 * (c0 + c)), &sD, &cD);
#pragma unroll
        for (int it = 0; it < 16; ++it) {
            int row = (it << 2) + r0;
            int a = (row << 6) + c;
            float rr = sre[a] * cA - sim[a] * sA;
            sim[a] = sre[a] * sA + sim[a] * cA; sre[a] = rr;
            float nc = cA * cD - sA * sD; sA = cA * sD + sA * cD; cA = nc;
        }
    }
    __syncthreads();
#pragma unroll
    for (int it = 0; it < 16; ++it) {
        int flat = it * 256 + t;
        int c = flat & 63, row = flat >> 6;
        Dh16[(size_t)r * 16384 + (row << 8) + (c0 + c)] =
            __floats2half2_rn(sre[(row << 6) + c], sim[(row << 6) + c]);
    }
}

__device__ void d_dec16_s2so(float* sm, int t, int blk, const __half2* __restrict__ Dh16,
                             float* __restrict__ S2acc)
{
    float* sre = sm; float* sim = sm + 4224;
    float* wtab = sm + 8448;   // [16][6]
    const int r = blk >> 2;
    const int k2base = (blk & 3) << 4;
#pragma unroll
    for (int it = 0; it < 16; ++it) {
        float2 v = __half22float2(Dh16[(size_t)r * 16384 + ((k2base + it) << 8) + t]);
        sre[it * RSTR + SWZI(t, it)] = v.x;
        sim[it * RSTR + SWZI(t, it)] = v.y;
    }
    if (t < 96) {
        int p = t / 6, dl = t % 6;
        float w = (float)(256 * (dl - 2) - 4 * (k2base + p));
        wtab[p * 6 + dl] = 0.003426963f * __expf(-3.690276e-5f * w * w);
    }
    __syncthreads();
    const int g = t >> 4, u = t & 15;
    fft256_soa<1, false, 2, false, 3, 2>(sre + g * RSTR, sim + g * RSTR, u, 0, 0.f,
                                         64.0f / (float)NN, g & 12, 15);
    __syncthreads();
    float acc = 0.f;
#pragma unroll
    for (int p = 0; p < 16; ++p) {
        const float* row = sim + p * RSTR;
#pragma unroll
        for (int dl = 0; dl < 6; ++dl)
            acc = fmaf(row[t + 5 - dl], wtab[p * 6 + dl], acc);
    }
    atomicAdd(&S2acc[(size_t)(192 + r) * 256 + t], acc * 4.0f);
}

__device__ void d_dec16_s2fo(float* sm, int t, int blk, const __half2* __restrict__ Dh16,
                             __half2* __restrict__ D2h16)
{
    float* sre = sm; float* sim = sm + 4224;
    const int r = blk >> 2;
    const int k2base = (blk & 3) << 4;
#pragma unroll
    for (int it = 0; it < 16; ++it) {
        float2 v = __half22float2(Dh16[(size_t)r * 16384 + ((k2base + it) << 8) + t]);
        sre[it * RSTR + SWZI(t, it)] = v.x;
        sim[it * RSTR + SWZI(t, it)] = v.y;
    }
    __syncthreads();
    const int g = t >> 4, u = t & 15;
    float* rr = sre + g * RSTR; float* ri = sim + g * RSTR;
    fft256_soa<1, false, 1, false, 0, 0>(rr, ri, u, 0, 0.f, 256.0f / (float)NN, g & 12, 15);
    fft256_soa<-1, true, 0, true, 0, 0>(rr, ri, u, k2base + g, TWO_PI / 16384.0f, 1.f, g & 12, 15);
    __syncthreads();
#pragma unroll
    for (int it = 0; it < 16; ++it) {
        int a = it * RSTR + SWZI(t, it);
        D2h16[(size_t)r * 16384 + ((k2base + it) << 8) + t] = __floats2half2_rn(sre[a], sim[a]);
    }
}

__device__ void d_dec16_s3fo(float* sm, int t, int blk, const __half2* __restrict__ D2h16,
                             __half2* __restrict__ Cw)
{
    float* sre = sm; float* sim = sm + 4096; float* twt = sm + 8192;
    const int r = blk >> 2;
    const int c0 = (blk & 3) << 6;
    const int j1 = 2 + (r >> 6), ql = r & 63;
    build_tw6(twt, t);
#pragma unroll
    for (int it = 0; it < 16; ++it) {
        int flat = it * 256 + t;
        int c = flat & 63, m2 = flat >> 6;
        float2 v = __half22float2(D2h16[(size_t)r * 16384 + (m2 << 8) + (c0 + c)]);
        sre[(m2 << 6) + c] = v.x;
        sim[(m2 << 6) + c] = v.y;
    }
    lds_dif<64, 6, 64, -1, false>(sre, sim, twt, t, 256);
    const int lo = CLO[j1];
    const size_t rbase = COFF[j1] + (size_t)ql * 16384;
#pragma unroll
    for (int it = 0; it < 16; ++it) {
        int flat = it * 256 + t;
        int c = flat & 63, p = flat >> 6;
        int kap = (c0 + c) + (rev64(p) << 8);
        int ks = (kap < 8192) ? kap : kap - 16384;
        int idx = (ks - lo) & 16383;
        int a = (p << 6) + c;
        Cw[rbase + idx] = __floats2half2_rn(sre[a], sim[a]);
    }
}

__device__ void d_m4k_fo(float* sm, int t, int blk, const float2* __restrict__ XF,
                         __half2* __restrict__ Cw)
{
    float* sre = sm; float* sim = sm + 4224; float* twt = sm + 8448;
    const int q = blk;
    const int j1 = 5 + (q >> 6), ql = q & 63;
    const int srow = ql >> 3;
    const int lam = j1 * 8 + (ql & 7);
    const float xi = 0.35f * exp2f(-(float)lam * 0.125f);
    const float invsig = 8.0f / xi;
    const float kc = xi * (float)NN;
    const float Hh = 6.10f * (xi * 0.125f) * (float)NN;
    const int klo = (int)ceilf(kc - Hh);
    build_tw6(twt, t);
#pragma unroll
    for (int it = 0; it < 16; ++it) {
        int kap = t + (it << 8);
        int kk = klo + (int)(((unsigned)(kap - klo)) & 4095u);
        float vr = 0.f, vi = 0.f;
        if (fabsf((float)kk - kc) <= Hh) {
            float2 v = XF[(size_t)srow * NN + (kk & (NN - 1))];
            float a = ((float)kk * (1.0f / (float)NN) - xi) * invsig;
            float wg = __expf(-0.5f * a * a);
            vr = v.x * wg; vi = v.y * wg;
        }
        int p = rev16(it);
        sre[p * RSTR + SWZI(t, p)] = vr;
        sim[p * RSTR + SWZI(t, p)] = vi;
    }
    lds_dit<16, 8, RSTR, 1, true>(sre, sim, twt, t, 256);
    {
        float sD, cD; __sincosf((TWO_PI / 4096.0f) * (float)t, &sD, &cD);
        float cA = 1.f, sA = 0.f;
#pragma unroll
        for (int it = 0; it < 16; ++it) {
            int a = it * RSTR + SWZI(t, it);
            float rr = sre[a] * cA - sim[a] * sA;
            sim[a] = sre[a] * sA + sim[a] * cA; sre[a] = rr;
            float nc = cA * cD - sA * sD; sA = cA * sD + sA * cD; cA = nc;
        }
    }
    __syncthreads();
    const int g = t >> 4, u = t & 15;
    float* rr = sre + g * RSTR; float* ri = sim + g * RSTR;
    fft256_soa<1, false, 1, false, 0, 0>(rr, ri, u, 0, 0.f, 16.0f / (float)NN, g & 12, 15);
    fft256_soa<-1, true, 0, true, 0, 0>(rr, ri, u, g, TWO_PI / 4096.0f, 1.f, g & 12, 15);
    lds_dif<16, 8, RSTR, -1, true>(sre, sim, twt, t, 256);
    const int lo = CLO[j1];
    const size_t rbase = COFF[j1] + (size_t)ql * 4096;
#pragma unroll
    for (int it = 0; it < 16; ++it) {
        int kap = t + (rev16(it) << 8);
        int ks = (kap < 2048) ? kap : kap - 4096;
        int idx = (ks - lo) & 4095;
        int a = it * RSTR + SWZI(t, it);
        Cw[rbase + idx] = __floats2half2_rn(sre[a], sim[a]);
    }
}

__device__ void d_m4k_so(float* sm, int t, int blk, const __half2* __restrict__ Cw,
                         float* __restrict__ out)
{
    float* sre = sm; float* sim = sm + 4224;
    float* twt = sm + 8448; float* wtab = sm + 8544;   // [16][6]
    const int q = blk;
    const int pp = q >> 6, rb = q & 63;
    int j1, j2;
    if (pp < 5)       { j2 = 5; j1 = pp; }
    else if (pp < 11) { j2 = 6; j1 = pp - 5; }
    else              { j2 = 7; j1 = pp - 11; }
    const float xi2 = 0.35f * exp2f(-(float)j2);
    const float invsig = 1.0f / (0.6f * xi2);
    const float kc = xi2 * (float)NN;
    const float Hh = fminf(6.10f * (0.6f * xi2) * (float)NN, 1823.0f);
    const int klo = (int)ceilf(kc - Hh);
    const size_t cbase = COFF[j1] + (size_t)rb * CWW[j1];
    const int lo = CLO[j1], Wd = CWW[j1], ring = CRING[j1];
    build_tw6(twt, t);
#pragma unroll
    for (int it = 0; it < 16; ++it) {
        int kap = t + (it << 8);
        int kk = klo + (int)(((unsigned)(kap - klo)) & 4095u);
        float vr = 0.f, vi = 0.f;
        if (fabsf((float)kk - kc) <= Hh) {
            int idx; bool ok = true;
            if (ring) idx = (kk - lo) & (Wd - 1);
            else { idx = kk - lo; ok = (idx >= 0 && idx < Wd); }
            if (ok) {
                float2 v = __half22float2(Cw[cbase + idx]);
                float a = ((float)kk * (1.0f / (float)NN) - xi2) * invsig;
                float wg = __expf(-0.5f * a * a);
                vr = v.x * wg; vi = v.y * wg;
            }
        }
        int p = rev16(it);
        sre[p * RSTR + SWZI(t, p)] = vr;
        sim[p * RSTR + SWZI(t, p)] = vi;
    }
    if (t < 96) {
        int p = t / 6, dl = t % 6;
        float w = (float)(256 * (dl - 2) - 16 * p);
        wtab[p * 6 + dl] = 0.003426963f * __expf(-3.690276e-5f * w * w);
    }
    lds_dit<16, 8, RSTR, 1, true>(sre, sim, twt, t, 256);
    {
        float sD, cD; __sincosf((TWO_PI / 4096.0f) * (float)t, &sD, &cD);
        float cA = 1.f, sA = 0.f;
#pragma unroll
        for (int it = 0; it < 16; ++it) {
            int a = it * RSTR + SWZI(t, it);
            float rr = sre[a] * cA - sim[a] * sA;
            sim[a] = sre[a] * sA + sim[a] * cA; sre[a] = rr;
            float nc = cA * cD - sA * sD; sA = cA * sD + sA * cD; cA = nc;
        }
    }
    __syncthreads();
    const int g = t >> 4, u = t & 15;
    fft256_soa<1, false, 2, false, 3, 2>(sre + g * RSTR, sim + g * RSTR, u, 0, 0.f,
                                         1.0f / (float)NN, g & 12, 15);
    __syncthreads();
    float acc = 0.f;
#pragma unroll
    for (int p = 0; p < 16; ++p) {
        const float* row = sim + p * RSTR;
#pragma unroll
        for (int dl = 0; dl < 6; ++dl)
            acc = fmaf(row[t + 5 - dl], wtab[p * 6 + dl], acc);
    }
    acc *= 16.0f;
    const int b = rb >> 3;
    const int chan = 65 + 4 * j2 * (j2 - 1) + j1 * 8 + (rb & 7);
    float mag = sqrtf(fmaf(acc, acc, 1e-8f));
    out[((size_t)b * 289 + chan) * 256 + t] = logf(mag + 1e-8f);
}

// ================= dispatchers =================
__global__ __launch_bounds__(256)
void fo_s1_kernel(const float2* __restrict__ XF, __half2* __restrict__ Cw,
                  __half2* __restrict__ DhB, __half2* __restrict__ Dh16)
{
    __shared__ float sm[8704];
    const int t = threadIdx.x;
    const int b = blockIdx.x;
    if (b < 192) d_m4k_fo(sm, t, b, XF, Cw);
    else if (b < 960) d_dec16_s1<1>(sm, t, b - 192, XF, nullptr, Dh16);
    else d_fo_stage1(sm, t, b - 960, XF, DhB);
}

__global__ __launch_bounds__(256)
void fo_s2_kernel(const __half2* __restrict__ DhB, const __half2* __restrict__ Dh16,
                  __half2* __restrict__ D2h, __half2* __restrict__ D2h16)
{
    __shared__ float sm[8704];
    const int t = threadIdx.x;
    const int b = blockIdx.x;
    if (b < 768) d_dec16_s2fo(sm, t, b, Dh16, D2h16);
    else d_fo_mid(sm, t, b - 768, DhB, D2h);
}

__global__ __launch_bounds__(256)
void fo_s3_kernel(const __half2* __restrict__ D2h, const __half2* __restrict__ D2h16,
                  __half2* __restrict__ Cw)
{
    __shared__ float sm[8704];
    const int t = threadIdx.x;
    const int b = blockIdx.x;
    if (b < 768) d_dec16_s3fo(sm, t, b, D2h16, Cw);
    else d_fo_stage2(sm, t, b - 768, D2h, Cw);
}

__global__ __launch_bounds__(256)
void so_1_kernel(const float2* __restrict__ XF, const __half2* __restrict__ Cw,
                 __half2* __restrict__ DhS, __half2* __restrict__ Dh16so,
                 float* __restrict__ out)
{
    __shared__ float sm[8704];
    const int t = threadIdx.x;
    const int b = blockIdx.x;
    if (b < 1152) d_m4k_so(sm, t, b, Cw, out);
    else if (b < 2944) d_dec16_s1<2>(sm, t, b - 1152, nullptr, Cw, Dh16so);
    else if (b < 6016) d_so_stage1(sm, t, b - 2944, Cw, DhS);
    else d_sfold(sm, t, b - 6016, XF, Cw, out);
}

__global__ __launch_bounds__(256)
void so_2_kernel(const __half2* __restrict__ DhS, const __half2* __restrict__ Dh16so,
                 float* __restrict__ S2acc)
{
    __shared__ float sm[8704];
    const int t = threadIdx.x;
    const int b = blockIdx.x;
    if (b < 1792) d_dec16_s2so(sm, t, b, Dh16so, S2acc);
    else d_so_stage2(sm, t, b - 1792, DhS, S2acc);
}

__global__ __launch_bounds__(256)
void s2final(const float* __restrict__ S2acc, float* __restrict__ out)
{
    const int q = blockIdx.x, n = threadIdx.x;
    int j1, j2, rb;
    if (q < 192) so_decode_full(q, j1, j2, rb);
    else         so_decode_dec16(q - 192, j1, j2, rb);
    const int b = rb >> 3;
    const int chan = 65 + 4 * j2 * (j2 - 1) + j1 * 8 + (rb & 7);
    float s = S2acc[(size_t)q * 256 + n];
    float mag = sqrtf(fmaf(s, s, 1e-8f));
    out[((size_t)b * 289 + chan) * 256 + n] = logf(mag + 1e-8f);
}

__global__ void zero2_kernel(float* a, int na, float* b, int nb)
{
    int i = blockIdx.x * 256 + threadIdx.x;
    if (i < na) a[i] = 0.f;
    else if (i < na + nb) b[i - na] = 0.f;
}

extern "C" void kernel_launch(void* const* d_in, const int* in_sizes, int n_in,
                              void* d_out, int out_size, void* d_ws, size_t ws_size,
                              hipStream_t stream)
{
    const float* x = (const float*)d_in[0];
    float* out = (float*)d_out;
    char* ws = (char*)d_ws;

    size_t off = 0;
    float2*  XF    = (float2*)ws;                 off += 8ul * NN * 8;
    __half2* Cw    = (__half2*)(ws + off);        off += CTOT * 4ul;
    float*   S2acc = (float*)(ws + off);          off += 640ul * 256 * 4;
    off = (off + 255) & ~255ul;
    char* sc = ws + off;

    // fo-phase scratch (92.3 MB)
    __half2* DhB   = (__half2*)sc;                        // 128 rows x 64K = 32 MB
    __half2* D2h   = (__half2*)(sc + 33554432ul);         // 32 MB
    __half2* Dh16  = (__half2*)(sc + 67108864ul);         // 192 x 16K = 12 MB
    __half2* D2h16 = (__half2*)(sc + 79691776ul);         // 12 MB
    // so-phase scratch reuses the same region (79.7 MB)
    __half2* DhS    = (__half2*)sc;                       // 192 rows x 64K = 48 MB
    __half2* Dh16so = (__half2*)(sc + 50331648ul);        // 448 x 16K = 28 MB
    float2*  Df     = (float2*)sc;                        // 4 MB (XF stage scratch)

    {
        int nz = 8 * 289 * 256;
        int na = 640 * 256;
        zero2_kernel<<<(nz + na + 255) / 256, 256, 0, stream>>>(out + nz, nz, S2acc, na);
    }

    // XF = fft(x)
    xf_stage1<<<8 * 16, 256, 0, stream>>>(x, Df);
    xf_stage2<<<8 * 16, 256, 0, stream>>>(Df, XF);

    // first order, all resolutions, stage-wise fused
    fo_s1_kernel<<<3008, 256, 0, stream>>>(XF, Cw, DhB, Dh16);
    fo_s2_kernel<<<2816, 256, 0, stream>>>(DhB, Dh16, D2h, D2h16);
    fo_s3_kernel<<<2816, 256, 0, stream>>>(D2h, D2h16, Cw);

    // second order + S0/S1, fused
    so_1_kernel<<<6536, 256, 0, stream>>>(XF, Cw, DhS, Dh16so, out);
    so_2_kernel<<<4864, 256, 0, stream>>>(DhS, Dh16so, S2acc);
    s2final<<<640, 256, 0, stream>>>(S2acc, out);
}